// Round 9
// baseline (442.997 us; speedup 1.0000x reference)
//
#include <hip/hip_runtime.h>
#include <math.h>

// ---------------------------------------------------------------------------
// VQ-VAE forward (round 20 = round 19 with the k_sp128 staging-offset bug
// fixed: chunk offset is c<<11 (64 rows x 32 elems), not c<<12 which
// overwrote the second double-buffer -> absmax 3.94 failure).
//  - Round-18 base (gload_lds 2-phase, d3 = 256x256 k_m256).
//  - k_sp128: split-bf16 128x128 tile for e1 (192 blk) / e2 (64 blk).
//  - d2 -> k_mfma_g 128x128 (192 blk).
//  - Per-output MFMA chains unchanged -> bit-identical outputs.
// ---------------------------------------------------------------------------

typedef __attribute__((ext_vector_type(8))) short bf16x8;
typedef __attribute__((ext_vector_type(4))) float f32x4;

__device__ __forceinline__ unsigned pk_bf16(float a, float b) {
    unsigned ua = __float_as_uint(a), ub = __float_as_uint(b);
    ua += 0x7fffu + ((ua >> 16) & 1u);          // RNE
    ub += 0x7fffu + ((ub >> 16) & 1u);
    return (ua >> 16) | (ub & 0xffff0000u);
}
__device__ __forceinline__ unsigned short bfh(float x) {
    unsigned u = __float_as_uint(x);
    u += 0x7fffu + ((u >> 16) & 1u);
    return (unsigned short)(u >> 16);
}
__device__ __forceinline__ float bf2f(unsigned short h) {
    return __uint_as_float(((unsigned)h) << 16);
}

// async global->LDS DMA, 16 B per lane (global_load_lds_dwordx4)
__device__ __forceinline__ void gload16(const unsigned short* g, unsigned short* l) {
    __builtin_amdgcn_global_load_lds(
        (const __attribute__((address_space(1))) unsigned int*)g,
        (__attribute__((address_space(3))) unsigned int*)l, 16, 0, 0);
}

__device__ __forceinline__ void bn4(float4& a, const float* __restrict__ s,
                                    const float* __restrict__ c) {
    float4 sv = *(const float4*)s;
    float4 cv = *(const float4*)c;
    a.x = fmaxf(fmaf(a.x, sv.x, cv.x), 0.f);
    a.y = fmaxf(fmaf(a.y, sv.y, cv.y), 0.f);
    a.z = fmaxf(fmaf(a.z, sv.z, cv.z), 0.f);
    a.w = fmaxf(fmaf(a.w, sv.w, cv.w), 0.f);
}

// ======================= fp32 GEMM (weff + VQ dist) ========================
#define FBK  32
#define FSTR 36

__global__ __launch_bounds__(256)
void k_gemm(const float* __restrict__ Abase,
            const float* __restrict__ Wt,
            float* __restrict__ Cout,
            const float* __restrict__ bnS, const float* __restrict__ bnB,
            unsigned long long* __restrict__ amin,
            const float* __restrict__ codesq,
            int Mslice, int K, int N, int decK)
{
    __shared__ __align__(16) float As[FBK][FSTR];
    __shared__ __align__(16) float Bs[FBK][FSTR];

    const int tid = threadIdx.x;
    const int z  = blockIdx.z;
    const int n0 = blockIdx.x << 5;
    const int m0 = blockIdx.y << 5;
    const int ty = tid >> 4;          // 0..15  (m pairs)
    const int tx = tid & 15;          // 0..15  (n pairs)

    const int a_slice = z / decK, wk = z - a_slice * decK;
    const float* Ap = Abase + (size_t)a_slice * (size_t)Mslice * (size_t)K;
    const float* Wp = Wt    + (size_t)wk * (size_t)K * (size_t)N;

    const int sr  = tid >> 3;         // 0..31
    const int sc4 = (tid & 7) << 2;   // 0..28

    int mrow = m0 + sr;
    if (mrow > Mslice - 1) mrow = Mslice - 1;
    const float* Arow_p = Ap + (size_t)mrow * K;

    float acc[2][2];
    acc[0][0] = 0.f; acc[0][1] = 0.f; acc[1][0] = 0.f; acc[1][1] = 0.f;

    // ---- prefetch chunk 0 ----
    float4 pa = *(const float4*)(Arow_p + sc4);
    if (bnS != nullptr) bn4(pa, bnS + sc4, bnB + sc4);
    float4 pb = *(const float4*)(Wp + (size_t)sr * N + n0 + sc4);

    for (int k0 = 0; k0 < K; k0 += FBK) {
        __syncthreads();
        As[sc4 + 0][sr] = pa.x;
        As[sc4 + 1][sr] = pa.y;
        As[sc4 + 2][sr] = pa.z;
        As[sc4 + 3][sr] = pa.w;
        *(float4*)&Bs[sr][sc4] = pb;
        const int k0n = k0 + FBK;
        if (k0n < K) {
            pa = *(const float4*)(Arow_p + k0n + sc4);
            if (bnS != nullptr) bn4(pa, bnS + k0n + sc4, bnB + k0n + sc4);
            pb = *(const float4*)(Wp + (size_t)(k0n + sr) * N + n0 + sc4);
        }
        __syncthreads();
#pragma unroll
        for (int kk = 0; kk < FBK; ++kk) {
            float2 av = *(const float2*)&As[kk][ty << 1];
            float2 bv = *(const float2*)&Bs[kk][tx << 1];
            acc[0][0] = fmaf(av.x, bv.x, acc[0][0]);
            acc[0][1] = fmaf(av.x, bv.y, acc[0][1]);
            acc[1][0] = fmaf(av.y, bv.x, acc[1][0]);
            acc[1][1] = fmaf(av.y, bv.y, acc[1][1]);
        }
    }

    if (amin != nullptr) {
        float2 cq = *(const float2*)(codesq + n0 + (tx << 1));
#pragma unroll
        for (int i = 0; i < 2; ++i) {
            const int m = m0 + (ty << 1) + i;
            float d0 = cq.x - 2.f * acc[i][0];
            float d1 = cq.y - 2.f * acc[i][1];
            int bj = (d1 < d0) ? 1 : 0;
            float best = (d1 < d0) ? d1 : d0;
            unsigned u = __float_as_uint(best);
            u = (u & 0x80000000u) ? ~u : (u | 0x80000000u);
            unsigned long long key =
                ((unsigned long long)u << 32) | (unsigned)(n0 + (tx << 1) + bj);
#pragma unroll
            for (int off = 1; off < 16; off <<= 1) {
                unsigned long long o = __shfl_xor(key, off, 64);
                if (o < key) key = o;
            }
            if (tx == 0 && m < Mslice) atomicMin(&amin[m], key);
        }
        return;
    }

#pragma unroll
    for (int i = 0; i < 2; ++i) {
        const int m = m0 + (ty << 1) + i;
        if (m < Mslice) {
            float2 v = make_float2(acc[i][0], acc[i][1]);
            *(float2*)&Cout[((size_t)z * Mslice + m) * N + n0 + (tx << 1)] = v;
        }
    }
}

// ===== bf16 MFMA GEMM, 128x128 tile, gload_lds + 2-phase pipeline ==========
// (d2 and out-proj). Linear LDS [2][128][64] bf16; XOR-swizzle: 16B unit u at
// row r holds global unit u^(r&7). B rows clamped to N-1 for padded cols.
__global__ __launch_bounds__(256)
void k_mfma_g(const unsigned short* __restrict__ Abase,
              const unsigned short* __restrict__ Bt,
              unsigned short* __restrict__ Cb,
              float* __restrict__ operm,
              const float* __restrict__ bias,
              float* __restrict__ stats,
              int Mslice, int K, int N, int decK)
{
    __shared__ __align__(16) unsigned short As[2][128 * 64];
    __shared__ __align__(16) unsigned short Bs[2][128 * 64];
    __shared__ float colsum[128], colsq[128];

    const int tid  = threadIdx.x;
    const int lane = tid & 63;
    const int wave = tid >> 6;
    const int wm = (wave >> 1) << 6;
    const int wn = (wave & 1) << 6;
    const int z  = blockIdx.z;
    const int n0 = blockIdx.x << 7;
    const int m0 = blockIdx.y << 7;

    if (stats != nullptr && tid < 128) { colsum[tid] = 0.f; colsq[tid] = 0.f; }

    const int a_slice = z / decK, wk = z - a_slice * decK;
    const unsigned short* Ap = Abase + (size_t)a_slice * (size_t)Mslice * (size_t)K;
    const unsigned short* Bp = Bt + (size_t)wk * (size_t)N * (size_t)K;

    const int srow  = tid >> 3;                       // 0..31 (row within chunk)
    const int selem = ((tid & 7) ^ (srow & 7)) << 3;  // swizzled elem offset
    const unsigned short* Asrc = Ap + (size_t)(m0 + srow) * K + selem;

    size_t boff[4];
#pragma unroll
    for (int c = 0; c < 4; ++c) {
        int brow = n0 + srow + (c << 5);
        if (brow > N - 1) brow = N - 1;
        boff[c] = (size_t)brow * K + selem;
    }

    f32x4 acc[4][4];
#pragma unroll
    for (int i = 0; i < 4; ++i)
#pragma unroll
        for (int j = 0; j < 4; ++j) acc[i][j] = (f32x4){0.f, 0.f, 0.f, 0.f};

    const int lidx = lane & 15;
    const int lq   = lane >> 4;

    // ---- prologue: stage chunk 0 into buffer 0 ----
#pragma unroll
    for (int c = 0; c < 4; ++c) {
        gload16(Asrc + (size_t)(c << 5) * K, &As[0][tid * 8 + (c << 11)]);
        gload16(Bp + boff[c],                &Bs[0][tid * 8 + (c << 11)]);
    }
    __syncthreads();   // vmcnt(0) drain: chunk 0 visible

    const int nsteps = K >> 6;
    int cur = 0;
    for (int t = 0; t < nsteps; ++t) {
        if (t + 1 < nsteps) {
            const int k0n = (t + 1) << 6;
#pragma unroll
            for (int c = 0; c < 4; ++c) {
                gload16(Asrc + (size_t)(c << 5) * K + k0n,
                        &As[cur ^ 1][tid * 8 + (c << 11)]);
                gload16(Bp + boff[c] + k0n,
                        &Bs[cur ^ 1][tid * 8 + (c << 11)]);
            }
        }
#pragma unroll
        for (int ks = 0; ks < 2; ++ks) {
            const int ub = (ks << 2) + lq;                        // 16B unit idx
            const int uo = (ub ^ (lidx & 7)) << 3;                // swizzled elems
            bf16x8 af[4], bfv[4];
#pragma unroll
            for (int t4 = 0; t4 < 4; ++t4)
                af[t4] = *(const bf16x8*)&As[cur][((wm + (t4 << 4) + lidx) << 6) + uo];
#pragma unroll
            for (int t4 = 0; t4 < 4; ++t4)
                bfv[t4] = *(const bf16x8*)&Bs[cur][((wn + (t4 << 4) + lidx) << 6) + uo];
#pragma unroll
            for (int mt = 0; mt < 4; ++mt)
#pragma unroll
                for (int nt = 0; nt < 4; ++nt)
                    acc[mt][nt] = __builtin_amdgcn_mfma_f32_16x16x32_bf16(
                        af[mt], bfv[nt], acc[mt][nt], 0, 0, 0);
        }
        __syncthreads();   // prefetch landed + all waves done reading buf cur
        cur ^= 1;
    }

    const int rbase = lq << 2;
#pragma unroll
    for (int nt = 0; nt < 4; ++nt) {
        const int col = n0 + wn + (nt << 4) + lidx;
        const float badd = (bias != nullptr && col < N) ? bias[col] : 0.f;
        float s = 0.f, q = 0.f;
#pragma unroll
        for (int mt = 0; mt < 4; ++mt) {
#pragma unroll
            for (int r = 0; r < 4; ++r) {
                float x = acc[mt][nt][r];
                s += x; q += x * x;
                const int row = m0 + wm + (mt << 4) + rbase + r;
                if (operm != nullptr) {
                    if (col < N) {
                        const int t = row >> 10, b = row & 1023;
                        operm[(size_t)b * 4050 + t * 135 + col] = x + badd;
                    }
                } else {
                    Cb[((size_t)z * Mslice + row) * (size_t)N + col] = bfh(x + badd);
                }
            }
        }
        if (stats != nullptr) {
            s += __shfl_xor(s, 16, 64); s += __shfl_xor(s, 32, 64);
            q += __shfl_xor(q, 16, 64); q += __shfl_xor(q, 32, 64);
            if (lq == 0) {
                atomicAdd(&colsum[wn + (nt << 4) + lidx], s);
                atomicAdd(&colsq [wn + (nt << 4) + lidx], q);
            }
        }
    }
    if (stats != nullptr) {
        __syncthreads();
        if (tid < 128) {
            atomicAdd(&stats[n0 + tid],       colsum[tid]);
            atomicAdd(&stats[512 + n0 + tid], colsq[tid]);
        }
    }
}

// ===== bf16 MFMA GEMM, 256x256 tile, gload_lds + 2-phase (d3) ==============
__global__ __launch_bounds__(512)
void k_m256(const unsigned short* __restrict__ Abase,
            const unsigned short* __restrict__ Bt,
            unsigned short* __restrict__ Cb,
            float* __restrict__ stats,
            int Mslice, int K, int N, int decK)
{
    __shared__ __align__(16) unsigned short As[2][256 * 64];
    __shared__ __align__(16) unsigned short Bs[2][256 * 64];
    __shared__ float colsum[256], colsq[256];

    const int tid  = threadIdx.x;
    const int lane = tid & 63;
    const int wave = tid >> 6;          // 0..7
    const int wm = (wave >> 2) << 7;    // 0,128
    const int wn = (wave & 3) << 6;     // 0,64,128,192
    const int z  = blockIdx.z;
    const int n0 = blockIdx.x << 8;
    const int m0 = blockIdx.y << 8;

    if (stats != nullptr && tid < 256) { colsum[tid] = 0.f; colsq[tid] = 0.f; }

    const int a_slice = z / decK, wk = z - a_slice * decK;
    const unsigned short* Ap = Abase + (size_t)a_slice * (size_t)Mslice * (size_t)K;
    const unsigned short* Bp = Bt + (size_t)wk * (size_t)N * (size_t)K;

    const int srow  = tid >> 3;                       // 0..63 (row within chunk)
    const int selem = ((tid & 7) ^ (srow & 7)) << 3;  // swizzled elem offset
    const unsigned short* Asrc = Ap + (size_t)(m0 + srow) * K + selem;

    size_t boff[4];
#pragma unroll
    for (int c = 0; c < 4; ++c) {
        int brow = n0 + srow + (c << 6);
        if (brow > N - 1) brow = N - 1;
        boff[c] = (size_t)brow * K + selem;
    }

    f32x4 acc[8][4];
#pragma unroll
    for (int i = 0; i < 8; ++i)
#pragma unroll
        for (int j = 0; j < 4; ++j) acc[i][j] = (f32x4){0.f, 0.f, 0.f, 0.f};

    const int lidx = lane & 15;
    const int lq   = lane >> 4;

    // ---- prologue: stage chunk 0 into buffer 0 ----
#pragma unroll
    for (int c = 0; c < 4; ++c) {
        gload16(Asrc + (size_t)(c << 6) * K, &As[0][tid * 8 + (c << 12)]);
        gload16(Bp + boff[c],                &Bs[0][tid * 8 + (c << 12)]);
    }
    __syncthreads();

    const int nsteps = K >> 6;
    int cur = 0;
    for (int t = 0; t < nsteps; ++t) {
        if (t + 1 < nsteps) {
            const int k0n = (t + 1) << 6;
#pragma unroll
            for (int c = 0; c < 4; ++c) {
                gload16(Asrc + (size_t)(c << 6) * K + k0n,
                        &As[cur ^ 1][tid * 8 + (c << 12)]);
                gload16(Bp + boff[c] + k0n,
                        &Bs[cur ^ 1][tid * 8 + (c << 12)]);
            }
        }
#pragma unroll
        for (int ks = 0; ks < 2; ++ks) {
            const int ub = (ks << 2) + lq;                        // 16B unit idx
            const int uo = (ub ^ (lidx & 7)) << 3;                // swizzled elems
            bf16x8 af[8], bfv[4];
#pragma unroll
            for (int i = 0; i < 8; ++i)
                af[i] = *(const bf16x8*)&As[cur][((wm + (i << 4) + lidx) << 6) + uo];
#pragma unroll
            for (int j = 0; j < 4; ++j)
                bfv[j] = *(const bf16x8*)&Bs[cur][((wn + (j << 4) + lidx) << 6) + uo];
#pragma unroll
            for (int mt = 0; mt < 8; ++mt)
#pragma unroll
                for (int nt = 0; nt < 4; ++nt)
                    acc[mt][nt] = __builtin_amdgcn_mfma_f32_16x16x32_bf16(
                        af[mt], bfv[nt], acc[mt][nt], 0, 0, 0);
        }
        __syncthreads();
        cur ^= 1;
    }

    const int rbase = lq << 2;
#pragma unroll
    for (int nt = 0; nt < 4; ++nt) {
        const int col = n0 + wn + (nt << 4) + lidx;
        float s = 0.f, q = 0.f;
#pragma unroll
        for (int mt = 0; mt < 8; ++mt) {
#pragma unroll
            for (int r = 0; r < 4; ++r) {
                float x = acc[mt][nt][r];
                s += x; q += x * x;
                const int row = m0 + wm + (mt << 4) + rbase + r;
                Cb[((size_t)z * Mslice + row) * (size_t)N + col] = bfh(x);
            }
        }
        if (stats != nullptr) {
            s += __shfl_xor(s, 16, 64); s += __shfl_xor(s, 32, 64);
            q += __shfl_xor(q, 16, 64); q += __shfl_xor(q, 32, 64);
            if (lq == 0) {
                atomicAdd(&colsum[wn + (nt << 4) + lidx], s);
                atomicAdd(&colsq [wn + (nt << 4) + lidx], q);
            }
        }
    }
    if (stats != nullptr) {
        __syncthreads();
        if (tid < 256) {
            atomicAdd(&stats[n0 + tid],       colsum[tid]);
            atomicAdd(&stats[512 + n0 + tid], colsq[tid]);
        }
    }
}

// ===== bf16 MFMA GEMM, 64x64 tile, gload_lds + 2-phase (d0,d1) =============
__global__ __launch_bounds__(256)
void k_b64g(const unsigned short* __restrict__ Abase,
            const unsigned short* __restrict__ Bt,
            unsigned short* __restrict__ Cb,
            const float* __restrict__ bias,
            float* __restrict__ stats,
            int Mslice, int K, int N, int decK)
{
    __shared__ __align__(16) unsigned short As[2][64 * 64];
    __shared__ __align__(16) unsigned short Bs[2][64 * 64];
    __shared__ float colsum[64], colsq[64];

    const int tid  = threadIdx.x;
    const int lane = tid & 63;
    const int wave = tid >> 6;
    const int wm = (wave >> 1) << 5;
    const int wn = (wave & 1) << 5;
    const int z  = blockIdx.z;
    const int n0 = blockIdx.x << 6;
    const int m0 = blockIdx.y << 6;

    if (stats != nullptr && tid < 64) { colsum[tid] = 0.f; colsq[tid] = 0.f; }

    const int a_slice = z / decK, wk = z - a_slice * decK;
    const unsigned short* Ap = Abase + (size_t)a_slice * (size_t)Mslice * (size_t)K;
    const unsigned short* Bp = Bt + (size_t)wk * (size_t)N * (size_t)K;

    const int srow  = tid >> 3;                       // 0..31
    const int selem = ((tid & 7) ^ (srow & 7)) << 3;
    const unsigned short* Asrc = Ap + (size_t)(m0 + srow) * K + selem;
    const unsigned short* Bsrc = Bp + (size_t)(n0 + srow) * K + selem;

    f32x4 acc[2][2];
#pragma unroll
    for (int i = 0; i < 2; ++i)
#pragma unroll
        for (int j = 0; j < 2; ++j) acc[i][j] = (f32x4){0.f, 0.f, 0.f, 0.f};

    const int lidx = lane & 15;
    const int lq   = lane >> 4;

    // ---- prologue: stage chunk 0 into buffer 0 ----
#pragma unroll
    for (int c = 0; c < 2; ++c) {
        gload16(Asrc + (size_t)(c << 5) * K, &As[0][tid * 8 + (c << 11)]);
        gload16(Bsrc + (size_t)(c << 5) * K, &Bs[0][tid * 8 + (c << 11)]);
    }
    __syncthreads();

    const int nsteps = K >> 6;
    int cur = 0;
    for (int t = 0; t < nsteps; ++t) {
        if (t + 1 < nsteps) {
            const int k0n = (t + 1) << 6;
#pragma unroll
            for (int c = 0; c < 2; ++c) {
                gload16(Asrc + (size_t)(c << 5) * K + k0n,
                        &As[cur ^ 1][tid * 8 + (c << 11)]);
                gload16(Bsrc + (size_t)(c << 5) * K + k0n,
                        &Bs[cur ^ 1][tid * 8 + (c << 11)]);
            }
        }
#pragma unroll
        for (int ks = 0; ks < 2; ++ks) {
            const int ub = (ks << 2) + lq;
            const int uo = (ub ^ (lidx & 7)) << 3;
            bf16x8 af[2], bfv[2];
#pragma unroll
            for (int t2 = 0; t2 < 2; ++t2)
                af[t2] = *(const bf16x8*)&As[cur][((wm + (t2 << 4) + lidx) << 6) + uo];
#pragma unroll
            for (int t2 = 0; t2 < 2; ++t2)
                bfv[t2] = *(const bf16x8*)&Bs[cur][((wn + (t2 << 4) + lidx) << 6) + uo];
#pragma unroll
            for (int mt = 0; mt < 2; ++mt)
#pragma unroll
                for (int nt = 0; nt < 2; ++nt)
                    acc[mt][nt] = __builtin_amdgcn_mfma_f32_16x16x32_bf16(
                        af[mt], bfv[nt], acc[mt][nt], 0, 0, 0);
        }
        __syncthreads();
        cur ^= 1;
    }

    const int rbase = lq << 2;
#pragma unroll
    for (int nt = 0; nt < 2; ++nt) {
        const int col = n0 + wn + (nt << 4) + lidx;
        const float badd = (bias != nullptr) ? bias[col] : 0.f;
        float s = 0.f, q = 0.f;
#pragma unroll
        for (int mt = 0; mt < 2; ++mt) {
#pragma unroll
            for (int r = 0; r < 4; ++r) {
                float x = acc[mt][nt][r];
                s += x; q += x * x;
                const int row = m0 + wm + (mt << 4) + rbase + r;
                Cb[((size_t)z * Mslice + row) * (size_t)N + col] = bfh(x + badd);
            }
        }
        if (stats != nullptr) {
            s += __shfl_xor(s, 16, 64); s += __shfl_xor(s, 32, 64);
            q += __shfl_xor(q, 16, 64); q += __shfl_xor(q, 32, 64);
            if (lq == 0) {
                atomicAdd(&colsum[wn + (nt << 4) + lidx], s);
                atomicAdd(&colsq [wn + (nt << 4) + lidx], q);
            }
        }
    }
    if (stats != nullptr) {
        __syncthreads();
        if (tid < 64) {
            atomicAdd(&stats[n0 + tid],       colsum[tid]);
            atomicAdd(&stats[512 + n0 + tid], colsq[tid]);
        }
    }
}

// ===== split-bf16 MFMA GEMM, 128x128 tile, gload_lds + 2-phase (e1,e2) =====
// 256 threads, 4 waves (2m x 2n), per-wave 64x64, acc[4][4]. Linear LDS
// [2][128][32] bf16 per buffer (64 KB total); XOR-swizzle unit^(row&3).
// Chunk c (rows 64c..64c+63) lands at elem offset c<<11 (64 rows x 32).
__global__ __launch_bounds__(256)
void k_sp128(const unsigned short* __restrict__ Ahg,
             const unsigned short* __restrict__ Alg,
             const unsigned short* __restrict__ Whi,
             const unsigned short* __restrict__ Wlo,
             float* __restrict__ Cout, float* __restrict__ stats,
             int Mslice, int Kp, int N, int n_terms)
{
    __shared__ __align__(16) unsigned short Ah[2][128 * 32];
    __shared__ __align__(16) unsigned short Al[2][128 * 32];
    __shared__ __align__(16) unsigned short Bh[2][128 * 32];
    __shared__ __align__(16) unsigned short Bl[2][128 * 32];
    __shared__ float colsum[128], colsq[128];

    const int tid  = threadIdx.x;
    const int lane = tid & 63;
    const int wave = tid >> 6;          // 0..3
    const int wm = (wave >> 1) << 6;    // 0,64
    const int wn = (wave & 1) << 6;     // 0,64
    const int z  = blockIdx.z;
    const int n0 = blockIdx.x << 7;
    const int m0 = blockIdx.y << 7;

    if (stats != nullptr && tid < 128) { colsum[tid] = 0.f; colsq[tid] = 0.f; }

    // staging: chunk c covers rows c*64..c*64+63; thread handles one 16B unit
    const int srow  = tid >> 2;                       // 0..63 (row in sub-chunk)
    const int selem = ((tid & 3) ^ (srow & 3)) << 3;  // swizzled elem in 32-row

    f32x4 acc[4][4];
#pragma unroll
    for (int i = 0; i < 4; ++i)
#pragma unroll
        for (int j = 0; j < 4; ++j) acc[i][j] = (f32x4){0.f, 0.f, 0.f, 0.f};

    const int lidx = lane & 15;
    const int lq   = lane >> 4;
    const int uo   = (lq ^ (lidx & 3)) << 3;          // swizzled read offset

    const int cpk = Kp >> 5;
    const int tot = n_terms * cpk;

    // ---- prologue: stage chunk 0 (term 0, k 0) into buffer 0 ----
    {
#pragma unroll
        for (int c = 0; c < 2; ++c) {
            const int row = (c << 6) + srow;
            const size_t ab = ((size_t)(z * n_terms) * Mslice + m0 + row)
                              * (size_t)Kp + selem;
            const size_t bb = ((size_t)(n0 + row)) * (size_t)Kp + selem;
            gload16(Ahg + ab, &Ah[0][tid * 8 + (c << 11)]);
            gload16(Alg + ab, &Al[0][tid * 8 + (c << 11)]);
            gload16(Whi + bb, &Bh[0][tid * 8 + (c << 11)]);
            gload16(Wlo + bb, &Bl[0][tid * 8 + (c << 11)]);
        }
    }
    __syncthreads();

    int cur = 0;
    int lt = 0, lk = 32;
    if (lk >= Kp) { lk = 0; lt = 1; }
    for (int cc = 0; cc < tot; ++cc) {
        if (cc + 1 < tot) {
#pragma unroll
            for (int c = 0; c < 2; ++c) {
                const int row = (c << 6) + srow;
                const size_t ab = ((size_t)(z * n_terms + lt) * Mslice + m0 + row)
                                  * (size_t)Kp + lk + selem;
                const size_t bb = ((size_t)lt * N + n0 + row) * (size_t)Kp + lk + selem;
                gload16(Ahg + ab, &Ah[cur ^ 1][tid * 8 + (c << 11)]);
                gload16(Alg + ab, &Al[cur ^ 1][tid * 8 + (c << 11)]);
                gload16(Whi + bb, &Bh[cur ^ 1][tid * 8 + (c << 11)]);
                gload16(Wlo + bb, &Bl[cur ^ 1][tid * 8 + (c << 11)]);
            }
            lk += 32; if (lk >= Kp) { lk = 0; ++lt; }
        }
        bf16x8 ah[4], al[4], bh[4], bl[4];
#pragma unroll
        for (int t = 0; t < 4; ++t) {
            const int ra = ((wm + (t << 4) + lidx) << 5) + uo;
            ah[t] = *(const bf16x8*)&Ah[cur][ra];
            al[t] = *(const bf16x8*)&Al[cur][ra];
        }
#pragma unroll
        for (int t = 0; t < 4; ++t) {
            const int rb = ((wn + (t << 4) + lidx) << 5) + uo;
            bh[t] = *(const bf16x8*)&Bh[cur][rb];
            bl[t] = *(const bf16x8*)&Bl[cur][rb];
        }
#pragma unroll
        for (int mt = 0; mt < 4; ++mt)
#pragma unroll
            for (int nt = 0; nt < 4; ++nt) {
                acc[mt][nt] = __builtin_amdgcn_mfma_f32_16x16x32_bf16(
                    ah[mt], bh[nt], acc[mt][nt], 0, 0, 0);
                acc[mt][nt] = __builtin_amdgcn_mfma_f32_16x16x32_bf16(
                    al[mt], bh[nt], acc[mt][nt], 0, 0, 0);
                acc[mt][nt] = __builtin_amdgcn_mfma_f32_16x16x32_bf16(
                    ah[mt], bl[nt], acc[mt][nt], 0, 0, 0);
            }
        __syncthreads();
        cur ^= 1;
    }

    const int rbase = lq << 2;
#pragma unroll
    for (int nt = 0; nt < 4; ++nt) {
        const int col = n0 + wn + (nt << 4) + lidx;
        float s = 0.f, q = 0.f;
#pragma unroll
        for (int mt = 0; mt < 4; ++mt) {
#pragma unroll
            for (int r = 0; r < 4; ++r) {
                float x = acc[mt][nt][r];
                s += x; q += x * x;
                const int row = m0 + wm + (mt << 4) + rbase + r;
                Cout[((size_t)z * Mslice + row) * (size_t)N + col] = x;
            }
        }
        if (stats != nullptr) {
            s += __shfl_xor(s, 16, 64); s += __shfl_xor(s, 32, 64);
            q += __shfl_xor(q, 16, 64); q += __shfl_xor(q, 32, 64);
            if (lq == 0) {
                atomicAdd(&colsum[wn + (nt << 4) + lidx], s);
                atomicAdd(&colsq [wn + (nt << 4) + lidx], q);
            }
        }
    }
    if (stats != nullptr) {
        __syncthreads();
        if (tid < 128) {
            atomicAdd(&stats[n0 + tid],       colsum[tid]);
            atomicAdd(&stats[512 + n0 + tid], colsq[tid]);
        }
    }
}

// ===== split-bf16 MFMA GEMM, 64x64 tile, gload_lds + 2-phase (e3) ==========
__global__ __launch_bounds__(256)
void k_sp64g(const unsigned short* __restrict__ Ahg,
             const unsigned short* __restrict__ Alg,
             const unsigned short* __restrict__ Whi,
             const unsigned short* __restrict__ Wlo,
             float* __restrict__ Cout, float* __restrict__ stats,
             int Mslice, int Kp, int N, int n_terms)
{
    __shared__ __align__(16) unsigned short Ah[2][64 * 32];
    __shared__ __align__(16) unsigned short Al[2][64 * 32];
    __shared__ __align__(16) unsigned short Bh[2][64 * 32];
    __shared__ __align__(16) unsigned short Bl[2][64 * 32];
    __shared__ float colsum[64], colsq[64];

    const int tid  = threadIdx.x;
    const int lane = tid & 63;
    const int wave = tid >> 6;
    const int wm = (wave >> 1) << 5;
    const int wn = (wave & 1) << 5;
    const int z  = blockIdx.z;
    const int n0 = blockIdx.x << 6;
    const int m0 = blockIdx.y << 6;

    if (stats != nullptr && tid < 64) { colsum[tid] = 0.f; colsq[tid] = 0.f; }

    const int srow  = tid >> 2;                       // 0..63
    const int selem = ((tid & 3) ^ (srow & 3)) << 3;  // swizzled elem in 32-row

    f32x4 acc[2][2];
#pragma unroll
    for (int i = 0; i < 2; ++i)
#pragma unroll
        for (int j = 0; j < 2; ++j) acc[i][j] = (f32x4){0.f, 0.f, 0.f, 0.f};

    const int lidx = lane & 15;
    const int lq   = lane >> 4;
    const int uo   = (lq ^ (lidx & 3)) << 3;          // swizzled read offset

    const int cpk = Kp >> 5;
    const int tot = n_terms * cpk;

    // ---- prologue: stage chunk 0 (term 0, k 0) into buffer 0 ----
    {
        const size_t ab = ((size_t)(z * n_terms) * Mslice + m0 + srow)
                          * (size_t)Kp + selem;
        const size_t bb = ((size_t)(n0 + srow)) * (size_t)Kp + selem;
        gload16(Ahg + ab, &Ah[0][tid * 8]);
        gload16(Alg + ab, &Al[0][tid * 8]);
        gload16(Whi + bb, &Bh[0][tid * 8]);
        gload16(Wlo + bb, &Bl[0][tid * 8]);
    }
    __syncthreads();

    int cur = 0;
    int lt = 0, lk = 32;
    if (lk >= Kp) { lk = 0; lt = 1; }
    for (int c = 0; c < tot; ++c) {
        if (c + 1 < tot) {
            const size_t ab = ((size_t)(z * n_terms + lt) * Mslice + m0 + srow)
                              * (size_t)Kp + lk + selem;
            const size_t bb = ((size_t)lt * N + n0 + srow) * (size_t)Kp + lk + selem;
            gload16(Ahg + ab, &Ah[cur ^ 1][tid * 8]);
            gload16(Alg + ab, &Al[cur ^ 1][tid * 8]);
            gload16(Whi + bb, &Bh[cur ^ 1][tid * 8]);
            gload16(Wlo + bb, &Bl[cur ^ 1][tid * 8]);
            lk += 32; if (lk >= Kp) { lk = 0; ++lt; }
        }
        bf16x8 ah[2], al[2], bh[2], bl[2];
#pragma unroll
        for (int t = 0; t < 2; ++t) {
            const int ra = ((wm + (t << 4) + lidx) << 5) + uo;
            ah[t] = *(const bf16x8*)&Ah[cur][ra];
            al[t] = *(const bf16x8*)&Al[cur][ra];
        }
#pragma unroll
        for (int t = 0; t < 2; ++t) {
            const int rb = ((wn + (t << 4) + lidx) << 5) + uo;
            bh[t] = *(const bf16x8*)&Bh[cur][rb];
            bl[t] = *(const bf16x8*)&Bl[cur][rb];
        }
#pragma unroll
        for (int mt = 0; mt < 2; ++mt)
#pragma unroll
            for (int nt = 0; nt < 2; ++nt) {
                acc[mt][nt] = __builtin_amdgcn_mfma_f32_16x16x32_bf16(
                    ah[mt], bh[nt], acc[mt][nt], 0, 0, 0);
                acc[mt][nt] = __builtin_amdgcn_mfma_f32_16x16x32_bf16(
                    al[mt], bh[nt], acc[mt][nt], 0, 0, 0);
                acc[mt][nt] = __builtin_amdgcn_mfma_f32_16x16x32_bf16(
                    ah[mt], bl[nt], acc[mt][nt], 0, 0, 0);
            }
        __syncthreads();
        cur ^= 1;
    }

    const int rbase = lq << 2;
#pragma unroll
    for (int nt = 0; nt < 2; ++nt) {
        const int col = n0 + wn + (nt << 4) + lidx;
        float s = 0.f, q = 0.f;
#pragma unroll
        for (int mt = 0; mt < 2; ++mt) {
#pragma unroll
            for (int r = 0; r < 4; ++r) {
                float x = acc[mt][nt][r];
                s += x; q += x * x;
                const int row = m0 + wm + (mt << 4) + rbase + r;
                Cout[((size_t)z * Mslice + row) * (size_t)N + col] = x;
            }
        }
        if (stats != nullptr) {
            s += __shfl_xor(s, 16, 64); s += __shfl_xor(s, 32, 64);
            q += __shfl_xor(q, 16, 64); q += __shfl_xor(q, 32, 64);
            if (lq == 0) {
                atomicAdd(&colsum[wn + (nt << 4) + lidx], s);
                atomicAdd(&colsq [wn + (nt << 4) + lidx], q);
            }
        }
    }
    if (stats != nullptr) {
        __syncthreads();
        if (tid < 64) {
            atomicAdd(&stats[n0 + tid],       colsum[tid]);
            atomicAdd(&stats[512 + n0 + tid], colsq[tid]);
        }
    }
}

// ================= merged prep kernel (9 independent preps) ================
__global__ void k_prep(float* __restrict__ zbase, unsigned long long* __restrict__ amin,
                       const float* __restrict__ codebook, float* __restrict__ codeT,
                       float* __restrict__ codesq,
                       const float* __restrict__ w_e2, unsigned short* __restrict__ whi_e2,
                       unsigned short* __restrict__ wlo_e2,
                       const float* __restrict__ w_e3, unsigned short* __restrict__ whi_e3,
                       unsigned short* __restrict__ wlo_e3,
                       const float* __restrict__ W_q,  unsigned short* __restrict__ wqb,
                       const float* __restrict__ w_d1, unsigned short* __restrict__ wd1b,
                       const float* __restrict__ w_d2, unsigned short* __restrict__ wd2b,
                       const float* __restrict__ w_d3, unsigned short* __restrict__ wd3b,
                       const float* __restrict__ W_out, unsigned short* __restrict__ woutb,
                       const float* __restrict__ in_seqs,
                       unsigned short* __restrict__ in_h, unsigned short* __restrict__ in_l)
{
    __shared__ float red[4];
    const int bid = blockIdx.x;
    const int tid = threadIdx.x;

    if (bid < 32) {                                    // s0: init
        int t = bid * 256 + tid;
        if (t < 6720) zbase[t] = 0.f;
        if (t < 1024) amin[t] = ~0ULL;
        return;
    }
    if (bid < 1056) {                                  // s1: codeT repack (Kc=1)
        int idx = (bid - 32) * 256 + tid;
        int i = (idx >> 9) & 511, o = idx & 511;
        codeT[idx] = codebook[(o << 9) + i];
        return;
    }
    if (bid < 1568) {                                  // s2: codesq
        int c = bid - 1056;
        float s = 0.f;
        for (int i = tid; i < 512; i += 256) { float v = codebook[c * 512 + i]; s += v * v; }
        for (int off = 32; off; off >>= 1) s += __shfl_down(s, off, 64);
        if ((tid & 63) == 0) red[tid >> 6] = s;
        __syncthreads();
        if (tid == 0) codesq[c] = red[0] + red[1] + red[2] + red[3];
        return;
    }
    if (bid < 4640) {                                  // s3: split e2 (Kc=3)
        int idx = (bid - 1568) * 256 + tid;
        int i = idx & 511, o = (idx >> 9) & 511, k = idx >> 18;
        float v = w_e2[(((o << 9) + i) * 3) + k];
        unsigned short h = bfh(v);
        whi_e2[idx] = h; wlo_e2[idx] = bfh(v - bf2f(h));
        return;
    }
    if (bid < 6688) {                                  // s4: split e3 (Kc=2)
        int idx = (bid - 4640) * 256 + tid;
        int i = idx & 511, o = (idx >> 9) & 511, k = idx >> 18;
        float v = w_e3[(((o << 9) + i) * 2) + k];
        unsigned short h = bfh(v);
        whi_e3[idx] = h; wlo_e3[idx] = bfh(v - bf2f(h));
        return;
    }
    if (bid < 7712) {                                  // s5: W_q bf (Kc=1,I=O=512)
        int idx = (bid - 6688) * 256 + tid;
        int i = idx & 511, o = (idx >> 9) & 511;
        wqb[idx] = bfh(W_q[((size_t)i << 9) + o]);
        return;
    }
    if (bid < 9760) {                                  // s6: w_d1 bf (Kc=2)
        int idx = (bid - 7712) * 256 + tid;
        int i = idx & 511, o = (idx >> 9) & 511, k = idx >> 18;
        wd1b[idx] = bfh(w_d1[(((size_t)i << 9) + o) * 2 + k]);
        return;
    }
    if (bid < 12832) {                                 // s7: w_d2 bf (Kc=3)
        int idx = (bid - 9760) * 256 + tid;
        int i = idx & 511, o = (idx >> 9) & 511, k = idx >> 18;
        wd2b[idx] = bfh(w_d2[(((size_t)i << 9) + o) * 3 + k]);
        return;
    }
    if (bid < 17952) {                                 // s8: w_d3 bf (Kc=5)
        int idx = (bid - 12832) * 256 + tid;
        int i = idx & 511, o = (idx >> 9) & 511, k = idx >> 18;
        wd3b[idx] = bfh(w_d3[(((size_t)i << 9) + o) * 5 + k]);
        return;
    }
    if (bid < 18222) {                                 // s9: W_out bf (Kc=1,I=512,O=135)
        int idx = (bid - 17952) * 256 + tid;
        if (idx >= 69120) return;
        int i = idx % 512, o = idx / 512;              // [o][i], o<135
        woutb[idx] = bfh(W_out[((size_t)i * 135) + o]);
        return;
    }
    {                                                  // s10: split_in
        int idx = (bid - 18222) * 256 + tid;
        if (idx >= 4915200) return;
        int i = idx % 160, r = idx / 160;
        float v = (i < 135) ? in_seqs[(size_t)r * 135 + i] : 0.f;
        unsigned short h = bfh(v);
        in_h[idx] = h; in_l[idx] = bfh(v - bf2f(h));
    }
}

// ============================ small kernels ================================
__global__ void k_repack(const float* __restrict__ w, float* __restrict__ wt,
                         int Kc, int total)
{
    int idx = blockIdx.x * 256 + threadIdx.x;
    if (idx >= total) return;
    int k = idx >> 18;
    int rem = idx & 262143;
    int i = rem >> 9, o = rem & 511;
    wt[idx] = w[(((o << 9) + i) * Kc + k)];
}

__global__ void k_repack_sp_weff(const float* __restrict__ weff,
                                 unsigned short* __restrict__ whi,
                                 unsigned short* __restrict__ wlo,
                                 int total)
{
    int idx = blockIdx.x * 256 + threadIdx.x;
    if (idx >= total) return;
    int i = idx % 160;
    int o = (idx / 160) & 511;
    int t = idx / 81920;
    float v = (i < 135) ? weff[((size_t)t * 135 + i) * 512 + o] : 0.f;
    unsigned short h = bfh(v);
    whi[idx] = h;
    wlo[idx] = bfh(v - bf2f(h));
}

__global__ void k_bnsplit(const float* __restrict__ x,
                          const float* __restrict__ sc, const float* __restrict__ sh,
                          unsigned short* __restrict__ hq, unsigned short* __restrict__ lq_,
                          int total4)
{
    int idx = blockIdx.x * 256 + threadIdx.x;
    if (idx >= total4) return;
    const int base = idx << 2;
    float4 f = *(const float4*)(x + base);
    const int k = base & 511;
    float4 s = *(const float4*)(sc + k);
    float4 c = *(const float4*)(sh + k);
    float y0 = fmaxf(fmaf(f.x, s.x, c.x), 0.f);
    float y1 = fmaxf(fmaf(f.y, s.y, c.y), 0.f);
    float y2 = fmaxf(fmaf(f.z, s.z, c.z), 0.f);
    float y3 = fmaxf(fmaf(f.w, s.w, c.w), 0.f);
    unsigned short h0 = bfh(y0), h1 = bfh(y1), h2 = bfh(y2), h3 = bfh(y3);
    unsigned short l0 = bfh(y0 - bf2f(h0)), l1 = bfh(y1 - bf2f(h1));
    unsigned short l2 = bfh(y2 - bf2f(h2)), l3 = bfh(y3 - bf2f(h3));
    *(uint2*)&hq[base]  = make_uint2((unsigned)h0 | ((unsigned)h1 << 16),
                                     (unsigned)h2 | ((unsigned)h3 << 16));
    *(uint2*)&lq_[base] = make_uint2((unsigned)l0 | ((unsigned)l1 << 16),
                                     (unsigned)l2 | ((unsigned)l3 << 16));
}

__global__ void k_bnapply(const unsigned short* __restrict__ x,
                          const float* __restrict__ sc, const float* __restrict__ sh,
                          unsigned short* __restrict__ y, int total8)
{
    int idx = blockIdx.x * 256 + threadIdx.x;
    if (idx >= total8) return;
    const int base = idx << 3;
    uint4 raw = *(const uint4*)(x + base);
    const int k = base & 511;
    float4 s0 = *(const float4*)(sc + k);
    float4 c0 = *(const float4*)(sh + k);
    float4 s1 = *(const float4*)(sc + k + 4);
    float4 c1 = *(const float4*)(sh + k + 4);
    unsigned* u = (unsigned*)&raw;
    float x0 = __uint_as_float(u[0] << 16),        x1 = __uint_as_float(u[0] & 0xffff0000u);
    float x2 = __uint_as_float(u[1] << 16),        x3 = __uint_as_float(u[1] & 0xffff0000u);
    float x4 = __uint_as_float(u[2] << 16),        x5 = __uint_as_float(u[2] & 0xffff0000u);
    float x6 = __uint_as_float(u[3] << 16),        x7 = __uint_as_float(u[3] & 0xffff0000u);
    x0 = fmaxf(fmaf(x0, s0.x, c0.x), 0.f); x1 = fmaxf(fmaf(x1, s0.y, c0.y), 0.f);
    x2 = fmaxf(fmaf(x2, s0.z, c0.z), 0.f); x3 = fmaxf(fmaf(x3, s0.w, c0.w), 0.f);
    x4 = fmaxf(fmaf(x4, s1.x, c1.x), 0.f); x5 = fmaxf(fmaf(x5, s1.y, c1.y), 0.f);
    x6 = fmaxf(fmaf(x6, s1.z, c1.z), 0.f); x7 = fmaxf(fmaf(x7, s1.w, c1.w), 0.f);
    *(uint4*)&y[base] = make_uint4(pk_bf16(x0, x1), pk_bf16(x2, x3),
                                   pk_bf16(x4, x5), pk_bf16(x6, x7));
}

__global__ void k_bn_fin(const float* __restrict__ stats,
                         const float* __restrict__ g, const float* __restrict__ b,
                         float* __restrict__ sc, float* __restrict__ sh, float inv_n)
{
    int c = blockIdx.x * blockDim.x + threadIdx.x;
    if (c >= 512) return;
    float m = stats[c] * inv_n;
    float v = stats[512 + c] * inv_n - m * m;
    float a = (float)((double)g[c] / sqrt((double)v + 1e-5));
    sc[c] = a;
    sh[c] = b[c] - m * a;
}

__global__ void k_vq_gather(const unsigned long long* __restrict__ amin,
                            const float* __restrict__ codebook,
                            const float* __restrict__ e3pre,
                            const float* __restrict__ sc, const float* __restrict__ sh,
                            unsigned short* __restrict__ quant_bf,
                            float* __restrict__ loss,
                            unsigned int* __restrict__ hist)
{
    int b = blockIdx.x; int t = threadIdx.x;   // 256 threads
    unsigned int idx = (unsigned int)(amin[b] & 0xFFFFFFFFull) & 511u;
    float part = 0.f;
    for (int i = t; i < 512; i += 256) {
        float q = codebook[(size_t)idx * 512 + i];
        quant_bf[(size_t)b * 512 + i] = bfh(q);
        float x = e3pre[(size_t)b * 512 + i];
        float f = fmaxf(fmaf(x, sc[i], sh[i]), 0.f);
        float d = q - f;
        part += d * d;
    }
    for (int off = 32; off; off >>= 1) part += __shfl_down(part, off, 64);
    __shared__ float red[4];
    if ((t & 63) == 0) red[t >> 6] = part;
    __syncthreads();
    if (t == 0) {
        atomicAdd(loss, red[0] + red[1] + red[2] + red[3]);
        atomicAdd(&hist[idx], 1u);
    }
}

__global__ void k_scalars(const unsigned int* __restrict__ hist,
                          const float* __restrict__ loss, float* __restrict__ out)
{
    int t = threadIdx.x;   // 512
    float p = (float)hist[t] * (1.0f / 1024.0f);
    float e = p * logf(p + 1e-10f);
    for (int off = 32; off; off >>= 1) e += __shfl_down(e, off, 64);
    __shared__ float red[8];
    if ((t & 63) == 0) red[t >> 6] = e;
    __syncthreads();
    if (t == 0) {
        float s = 0.f;
        for (int i = 0; i < 8; ++i) s += red[i];
        out[4147200] = 1.25f * loss[0] * (1.0f / 524288.0f);
        out[4147201] = expf(-s);
    }
}

extern "C" void kernel_launch(void* const* d_in, const int* in_sizes, int n_in,
                              void* d_out, int out_size, void* d_ws, size_t ws_size,
                              hipStream_t stream)
{
    const float* in_seqs = (const float*)d_in[0];
    const float* W_in  = (const float*)d_in[1];
    const float* w_e1  = (const float*)d_in[3];
    const float* g_e1  = (const float*)d_in[4];
    const float* be1   = (const float*)d_in[5];
    const float* w_e2  = (const float*)d_in[6];
    const float* g_e2  = (const float*)d_in[7];
    const float* be2   = (const float*)d_in[8];
    const float* w_e3  = (const float*)d_in[9];
    const float* g_e3  = (const float*)d_in[10];
    const float* be3   = (const float*)d_in[11];
    const float* codebook = (const float*)d_in[12];
    const float* W_q   = (const float*)d_in[13];
    const float* b_q   = (const float*)d_in[14];
    const float* w_d1  = (const float*)d_in[15];
    const float* g_d1  = (const float*)d_in[16];
    const float* bd1   = (const float*)d_in[17];
    const float* w_d2  = (const float*)d_in[18];
    const float* g_d2  = (const float*)d_in[19];
    const float* bd2   = (const float*)d_in[20];
    const float* w_d3  = (const float*)d_in[21];
    const float* g_d3  = (const float*)d_in[22];
    const float* bd3   = (const float*)d_in[23];
    const float* W_out = (const float*)d_in[24];
    const float* b_out = (const float*)d_in[25];
    float* out = (float*)d_out;

    // ---- workspace layout (float offsets) ----
    float* W = (float*)d_ws;
    unsigned long long* amin = (unsigned long long*)W;            // 2048 f
    float* stats  = W + 2048;                                     // 6144
    float* lossp  = W + 8192;                                     // 64
    unsigned int* hist = (unsigned int*)(W + 8256);               // 512
    float* scsh   = W + 8768;                                     // 6144
    float* codesq = W + 14912;                                    // 512
    float* wt_e1  = W + 15424;                                    // 1310720 f
    float* weff   = W + 1326144;                                  // 345600 f
    float* codeT  = W + 1671744;                                  // 262144 f
    unsigned short* esw = (unsigned short*)(W + 1933888);         // 3440640 ush
    unsigned short* whi_e1 = esw;
    unsigned short* wlo_e1 = esw + 409600;
    unsigned short* whi_e2 = esw + 819200;
    unsigned short* wlo_e2 = esw + 1605632;
    unsigned short* whi_e3 = esw + 2392064;
    unsigned short* wlo_e3 = esw + 2916352;
    unsigned short* in_h  = (unsigned short*)(W + 3654208);       // 4915200 ush
    unsigned short* in_l  = in_h + 4915200;
    unsigned short* d3pre = (unsigned short*)(W + 3654208);       // 15728640 ush
    float* e1f = W + 11518528;                                    // 3145728 f
    unsigned short* e1h = (unsigned short*)(W + 14664256);        // 3145728 ush
    unsigned short* e1l = e1h + 3145728;
    float* e2f = W + 17809984;                                    // 1048576 f
    unsigned short* e2h = (unsigned short*)(W + 18858560);        // 1048576 ush
    unsigned short* e2l = e2h + 1048576;
    unsigned short* d2pre = (unsigned short*)(W + 17809984);      // 3145728 ush
    unsigned short* d2bf  = d2pre + 3145728;                      // 3145728 ush
    float* e3f = W + 20955712;                                    // 524288 f
    unsigned short* quant_bf = (unsigned short*)(W + 21480000);   // 524288 ush
    unsigned short* d0bf     = (unsigned short*)(W + 21742144);   // 524288 ush
    unsigned short* d1pre    = (unsigned short*)(W + 22004288);   // 1048576 ush
    unsigned short* d1bf     = (unsigned short*)(W + 22528640);   // 1048576 ush
    unsigned short* d3bf     = (unsigned short*)(W + 23052928);   // 15728640 ush
    // d3bf ends at f-offset 30917248 (~124 MB) < 256 MiB ws.

    unsigned short* db    = (unsigned short*)wt_e1;
    unsigned short* wqb   = db;
    unsigned short* wd1b  = db + 262144;
    unsigned short* wd2b  = db + 786432;
    unsigned short* wd3b  = db + 1572864;
    unsigned short* woutb = db + 2883584;

    float* st_e1 = stats + 0 * 1024; float* sc_e1 = scsh + 0 * 1024; float* sh_e1 = sc_e1 + 512;
    float* st_e2 = stats + 1 * 1024; float* sc_e2 = scsh + 1 * 1024; float* sh_e2 = sc_e2 + 512;
    float* st_e3 = stats + 2 * 1024; float* sc_e3 = scsh + 2 * 1024; float* sh_e3 = sc_e3 + 512;
    float* st_d1 = stats + 3 * 1024; float* sc_d1 = scsh + 3 * 1024; float* sh_d1 = sc_d1 + 512;
    float* st_d2 = stats + 4 * 1024; float* sc_d2 = scsh + 4 * 1024; float* sh_d2 = sc_d2 + 512;
    float* st_d3 = stats + 5 * 1024; float* sc_d3 = scsh + 5 * 1024; float* sh_d3 = sc_d3 + 512;

    dim3 blk(256);

    // order: wt_e1 fp32 repack -> weff gemm -> sp_weff, THEN k_prep (which
    // fills decoder bf16 weights over the then-dead wt_e1 region).
    k_repack<<<dim3(5 * 1024), blk, 0, stream>>>(w_e1, wt_e1, 5, 5 * 262144);
    k_gemm<<<dim3(16, 5, 5), blk, 0, stream>>>(W_in, wt_e1, weff,
        nullptr, nullptr, nullptr, nullptr, 135, 512, 512, 5);
    k_repack_sp_weff<<<dim3(1600), blk, 0, stream>>>(weff, whi_e1, wlo_e1, 409600);

    k_prep<<<dim3(37422), blk, 0, stream>>>(stats, amin,
        codebook, codeT, codesq,
        w_e2, whi_e2, wlo_e2, w_e3, whi_e3, wlo_e3,
        W_q, wqb, w_d1, wd1b, w_d2, wd2b, w_d3, wd3b, W_out, woutb,
        in_seqs, in_h, in_l);

    // ---- encoder: split-bf16 MFMA (gload_lds, 2-phase) ----
    // e1/e2: 128x128 tiles (k_sp128); e3: 64x64 (k_sp64g, keeps 128 blocks)
    k_sp128<<<dim3(4, 8, 6), blk, 0, stream>>>(in_h, in_l, whi_e1, wlo_e1,
        e1f, st_e1, 1024, 160, 512, 5);
    k_bn_fin<<<dim3(2), blk, 0, stream>>>(st_e1, g_e1, be1, sc_e1, sh_e1, 1.f / 6144.f);
    k_bnsplit<<<dim3(3072), blk, 0, stream>>>(e1f, sc_e1, sh_e1, e1h, e1l, 786432);

    k_sp128<<<dim3(4, 8, 2), blk, 0, stream>>>(e1h, e1l, whi_e2, wlo_e2,
        e2f, st_e2, 1024, 512, 512, 3);
    k_bn_fin<<<dim3(2), blk, 0, stream>>>(st_e2, g_e2, be2, sc_e2, sh_e2, 1.f / 2048.f);
    k_bnsplit<<<dim3(1024), blk, 0, stream>>>(e2f, sc_e2, sh_e2, e2h, e2l, 262144);

    k_sp64g<<<dim3(8, 16, 1), blk, 0, stream>>>(e2h, e2l, whi_e3, wlo_e3,
        e3f, st_e3, 1024, 512, 512, 2);
    k_bn_fin<<<dim3(2), blk, 0, stream>>>(st_e3, g_e3, be3, sc_e3, sh_e3, 1.f / 1024.f);

    // ---- VQ: fp32 dist GEMM + argmin (32x32 tiles, 512 blocks) ----
    k_gemm<<<dim3(16, 32, 1), blk, 0, stream>>>(e3f, codeT, nullptr,
        sc_e3, sh_e3, amin, codesq, 1024, 512, 512, 1);
    k_vq_gather<<<dim3(1024), blk, 0, stream>>>(amin, codebook, e3f, sc_e3, sh_e3,
                                                quant_bf, lossp, hist);

    // ---- decoder: all gload_lds 2-phase; BN as separate passes ----
    k_b64g<<<dim3(8, 16, 1), blk, 0, stream>>>(quant_bf, wqb, d0bf,
        b_q, nullptr, 1024, 512, 512, 1);

    k_b64g<<<dim3(8, 16, 2), blk, 0, stream>>>(d0bf, wd1b, d1pre,
        nullptr, st_d1, 1024, 512, 512, 2);
    k_bn_fin<<<dim3(2), blk, 0, stream>>>(st_d1, g_d1, bd1, sc_d1, sh_d1, 1.f / 2048.f);
    k_bnapply<<<dim3(512), blk, 0, stream>>>(d1pre, sc_d1, sh_d1, d1bf, 131072);

    // d2: 128x128 gload_lds 2-phase (192 blocks, staged 98->49 MB)
    k_mfma_g<<<dim3(4, 8, 6), blk, 0, stream>>>(d1bf, wd2b, d2pre,
        nullptr, nullptr, st_d2, 1024, 512, 512, 3);
    k_bn_fin<<<dim3(2), blk, 0, stream>>>(st_d2, g_d2, bd2, sc_d2, sh_d2, 1.f / 6144.f);
    k_bnapply<<<dim3(1536), blk, 0, stream>>>(d2pre, sc_d2, sh_d2, d2bf, 393216);

    // d3: 256x256 tiles, gload_lds 2-phase, 512 threads (240 blocks)
    k_m256<<<dim3(2, 4, 30), dim3(512), 0, stream>>>(d2bf, wd3b, d3pre,
        st_d3, 1024, 512, 512, 5);
    k_bn_fin<<<dim3(2), blk, 0, stream>>>(st_d3, g_d3, bd3, sc_d3, sh_d3, 1.f / 30720.f);
    k_bnapply<<<dim3(7680), blk, 0, stream>>>(d3pre, sc_d3, sh_d3, d3bf, 1966080);

    // out-proj: 128x128 gload_lds 2-phase, operm store, N=135 (B rows clamped)
    k_mfma_g<<<dim3(2, 240, 1), blk, 0, stream>>>(d3bf, woutb, nullptr,
        out, b_out, nullptr, 30720, 512, 135, 1);

    k_scalars<<<dim3(1), dim3(512), 0, stream>>>(hist, lossp, out);
}

// Round 10
// 423.809 us; speedup vs baseline: 1.0453x; 1.0453x over previous
//
#include <hip/hip_runtime.h>
#include <math.h>

// ---------------------------------------------------------------------------
// VQ-VAE forward (round 21).
//  - POST-MORTEM round 20: k_sp128 (128^2 split tile, 66KB LDS) collapsed
//    occupancy (2.5%, 1 wave/SIMD at 192/64-block grids) -> e1/e2 regressed
//    ~+35us total. Staged-traffic lever only pays with >=2 blocks-worth/CU.
//  - REVERT e1/e2 to k_sp64g (768/256 blocks, verified 415.6us config).
//  - KEEP d2 on 128x128 k_mfma_g (192 blk; inferred neutral-to-positive).
//  - k_sp128 deleted. All remaining paths previously correctness-verified.
// ---------------------------------------------------------------------------

typedef __attribute__((ext_vector_type(8))) short bf16x8;
typedef __attribute__((ext_vector_type(4))) float f32x4;

__device__ __forceinline__ unsigned pk_bf16(float a, float b) {
    unsigned ua = __float_as_uint(a), ub = __float_as_uint(b);
    ua += 0x7fffu + ((ua >> 16) & 1u);          // RNE
    ub += 0x7fffu + ((ub >> 16) & 1u);
    return (ua >> 16) | (ub & 0xffff0000u);
}
__device__ __forceinline__ unsigned short bfh(float x) {
    unsigned u = __float_as_uint(x);
    u += 0x7fffu + ((u >> 16) & 1u);
    return (unsigned short)(u >> 16);
}
__device__ __forceinline__ float bf2f(unsigned short h) {
    return __uint_as_float(((unsigned)h) << 16);
}

// async global->LDS DMA, 16 B per lane (global_load_lds_dwordx4)
__device__ __forceinline__ void gload16(const unsigned short* g, unsigned short* l) {
    __builtin_amdgcn_global_load_lds(
        (const __attribute__((address_space(1))) unsigned int*)g,
        (__attribute__((address_space(3))) unsigned int*)l, 16, 0, 0);
}

__device__ __forceinline__ void bn4(float4& a, const float* __restrict__ s,
                                    const float* __restrict__ c) {
    float4 sv = *(const float4*)s;
    float4 cv = *(const float4*)c;
    a.x = fmaxf(fmaf(a.x, sv.x, cv.x), 0.f);
    a.y = fmaxf(fmaf(a.y, sv.y, cv.y), 0.f);
    a.z = fmaxf(fmaf(a.z, sv.z, cv.z), 0.f);
    a.w = fmaxf(fmaf(a.w, sv.w, cv.w), 0.f);
}

// ======================= fp32 GEMM (weff + VQ dist) ========================
#define FBK  32
#define FSTR 36

__global__ __launch_bounds__(256)
void k_gemm(const float* __restrict__ Abase,
            const float* __restrict__ Wt,
            float* __restrict__ Cout,
            const float* __restrict__ bnS, const float* __restrict__ bnB,
            unsigned long long* __restrict__ amin,
            const float* __restrict__ codesq,
            int Mslice, int K, int N, int decK)
{
    __shared__ __align__(16) float As[FBK][FSTR];
    __shared__ __align__(16) float Bs[FBK][FSTR];

    const int tid = threadIdx.x;
    const int z  = blockIdx.z;
    const int n0 = blockIdx.x << 5;
    const int m0 = blockIdx.y << 5;
    const int ty = tid >> 4;          // 0..15  (m pairs)
    const int tx = tid & 15;          // 0..15  (n pairs)

    const int a_slice = z / decK, wk = z - a_slice * decK;
    const float* Ap = Abase + (size_t)a_slice * (size_t)Mslice * (size_t)K;
    const float* Wp = Wt    + (size_t)wk * (size_t)K * (size_t)N;

    const int sr  = tid >> 3;         // 0..31
    const int sc4 = (tid & 7) << 2;   // 0..28

    int mrow = m0 + sr;
    if (mrow > Mslice - 1) mrow = Mslice - 1;
    const float* Arow_p = Ap + (size_t)mrow * K;

    float acc[2][2];
    acc[0][0] = 0.f; acc[0][1] = 0.f; acc[1][0] = 0.f; acc[1][1] = 0.f;

    // ---- prefetch chunk 0 ----
    float4 pa = *(const float4*)(Arow_p + sc4);
    if (bnS != nullptr) bn4(pa, bnS + sc4, bnB + sc4);
    float4 pb = *(const float4*)(Wp + (size_t)sr * N + n0 + sc4);

    for (int k0 = 0; k0 < K; k0 += FBK) {
        __syncthreads();
        As[sc4 + 0][sr] = pa.x;
        As[sc4 + 1][sr] = pa.y;
        As[sc4 + 2][sr] = pa.z;
        As[sc4 + 3][sr] = pa.w;
        *(float4*)&Bs[sr][sc4] = pb;
        const int k0n = k0 + FBK;
        if (k0n < K) {
            pa = *(const float4*)(Arow_p + k0n + sc4);
            if (bnS != nullptr) bn4(pa, bnS + k0n + sc4, bnB + k0n + sc4);
            pb = *(const float4*)(Wp + (size_t)(k0n + sr) * N + n0 + sc4);
        }
        __syncthreads();
#pragma unroll
        for (int kk = 0; kk < FBK; ++kk) {
            float2 av = *(const float2*)&As[kk][ty << 1];
            float2 bv = *(const float2*)&Bs[kk][tx << 1];
            acc[0][0] = fmaf(av.x, bv.x, acc[0][0]);
            acc[0][1] = fmaf(av.x, bv.y, acc[0][1]);
            acc[1][0] = fmaf(av.y, bv.x, acc[1][0]);
            acc[1][1] = fmaf(av.y, bv.y, acc[1][1]);
        }
    }

    if (amin != nullptr) {
        float2 cq = *(const float2*)(codesq + n0 + (tx << 1));
#pragma unroll
        for (int i = 0; i < 2; ++i) {
            const int m = m0 + (ty << 1) + i;
            float d0 = cq.x - 2.f * acc[i][0];
            float d1 = cq.y - 2.f * acc[i][1];
            int bj = (d1 < d0) ? 1 : 0;
            float best = (d1 < d0) ? d1 : d0;
            unsigned u = __float_as_uint(best);
            u = (u & 0x80000000u) ? ~u : (u | 0x80000000u);
            unsigned long long key =
                ((unsigned long long)u << 32) | (unsigned)(n0 + (tx << 1) + bj);
#pragma unroll
            for (int off = 1; off < 16; off <<= 1) {
                unsigned long long o = __shfl_xor(key, off, 64);
                if (o < key) key = o;
            }
            if (tx == 0 && m < Mslice) atomicMin(&amin[m], key);
        }
        return;
    }

#pragma unroll
    for (int i = 0; i < 2; ++i) {
        const int m = m0 + (ty << 1) + i;
        if (m < Mslice) {
            float2 v = make_float2(acc[i][0], acc[i][1]);
            *(float2*)&Cout[((size_t)z * Mslice + m) * N + n0 + (tx << 1)] = v;
        }
    }
}

// ===== bf16 MFMA GEMM, 128x128 tile, gload_lds + 2-phase pipeline ==========
// (d2 and out-proj). Linear LDS [2][128][64] bf16; XOR-swizzle: 16B unit u at
// row r holds global unit u^(r&7). B rows clamped to N-1 for padded cols.
__global__ __launch_bounds__(256)
void k_mfma_g(const unsigned short* __restrict__ Abase,
              const unsigned short* __restrict__ Bt,
              unsigned short* __restrict__ Cb,
              float* __restrict__ operm,
              const float* __restrict__ bias,
              float* __restrict__ stats,
              int Mslice, int K, int N, int decK)
{
    __shared__ __align__(16) unsigned short As[2][128 * 64];
    __shared__ __align__(16) unsigned short Bs[2][128 * 64];
    __shared__ float colsum[128], colsq[128];

    const int tid  = threadIdx.x;
    const int lane = tid & 63;
    const int wave = tid >> 6;
    const int wm = (wave >> 1) << 6;
    const int wn = (wave & 1) << 6;
    const int z  = blockIdx.z;
    const int n0 = blockIdx.x << 7;
    const int m0 = blockIdx.y << 7;

    if (stats != nullptr && tid < 128) { colsum[tid] = 0.f; colsq[tid] = 0.f; }

    const int a_slice = z / decK, wk = z - a_slice * decK;
    const unsigned short* Ap = Abase + (size_t)a_slice * (size_t)Mslice * (size_t)K;
    const unsigned short* Bp = Bt + (size_t)wk * (size_t)N * (size_t)K;

    const int srow  = tid >> 3;                       // 0..31 (row within chunk)
    const int selem = ((tid & 7) ^ (srow & 7)) << 3;  // swizzled elem offset
    const unsigned short* Asrc = Ap + (size_t)(m0 + srow) * K + selem;

    size_t boff[4];
#pragma unroll
    for (int c = 0; c < 4; ++c) {
        int brow = n0 + srow + (c << 5);
        if (brow > N - 1) brow = N - 1;
        boff[c] = (size_t)brow * K + selem;
    }

    f32x4 acc[4][4];
#pragma unroll
    for (int i = 0; i < 4; ++i)
#pragma unroll
        for (int j = 0; j < 4; ++j) acc[i][j] = (f32x4){0.f, 0.f, 0.f, 0.f};

    const int lidx = lane & 15;
    const int lq   = lane >> 4;

    // ---- prologue: stage chunk 0 into buffer 0 ----
#pragma unroll
    for (int c = 0; c < 4; ++c) {
        gload16(Asrc + (size_t)(c << 5) * K, &As[0][tid * 8 + (c << 11)]);
        gload16(Bp + boff[c],                &Bs[0][tid * 8 + (c << 11)]);
    }
    __syncthreads();   // vmcnt(0) drain: chunk 0 visible

    const int nsteps = K >> 6;
    int cur = 0;
    for (int t = 0; t < nsteps; ++t) {
        if (t + 1 < nsteps) {
            const int k0n = (t + 1) << 6;
#pragma unroll
            for (int c = 0; c < 4; ++c) {
                gload16(Asrc + (size_t)(c << 5) * K + k0n,
                        &As[cur ^ 1][tid * 8 + (c << 11)]);
                gload16(Bp + boff[c] + k0n,
                        &Bs[cur ^ 1][tid * 8 + (c << 11)]);
            }
        }
#pragma unroll
        for (int ks = 0; ks < 2; ++ks) {
            const int ub = (ks << 2) + lq;                        // 16B unit idx
            const int uo = (ub ^ (lidx & 7)) << 3;                // swizzled elems
            bf16x8 af[4], bfv[4];
#pragma unroll
            for (int t4 = 0; t4 < 4; ++t4)
                af[t4] = *(const bf16x8*)&As[cur][((wm + (t4 << 4) + lidx) << 6) + uo];
#pragma unroll
            for (int t4 = 0; t4 < 4; ++t4)
                bfv[t4] = *(const bf16x8*)&Bs[cur][((wn + (t4 << 4) + lidx) << 6) + uo];
#pragma unroll
            for (int mt = 0; mt < 4; ++mt)
#pragma unroll
                for (int nt = 0; nt < 4; ++nt)
                    acc[mt][nt] = __builtin_amdgcn_mfma_f32_16x16x32_bf16(
                        af[mt], bfv[nt], acc[mt][nt], 0, 0, 0);
        }
        __syncthreads();   // prefetch landed + all waves done reading buf cur
        cur ^= 1;
    }

    const int rbase = lq << 2;
#pragma unroll
    for (int nt = 0; nt < 4; ++nt) {
        const int col = n0 + wn + (nt << 4) + lidx;
        const float badd = (bias != nullptr && col < N) ? bias[col] : 0.f;
        float s = 0.f, q = 0.f;
#pragma unroll
        for (int mt = 0; mt < 4; ++mt) {
#pragma unroll
            for (int r = 0; r < 4; ++r) {
                float x = acc[mt][nt][r];
                s += x; q += x * x;
                const int row = m0 + wm + (mt << 4) + rbase + r;
                if (operm != nullptr) {
                    if (col < N) {
                        const int t = row >> 10, b = row & 1023;
                        operm[(size_t)b * 4050 + t * 135 + col] = x + badd;
                    }
                } else {
                    Cb[((size_t)z * Mslice + row) * (size_t)N + col] = bfh(x + badd);
                }
            }
        }
        if (stats != nullptr) {
            s += __shfl_xor(s, 16, 64); s += __shfl_xor(s, 32, 64);
            q += __shfl_xor(q, 16, 64); q += __shfl_xor(q, 32, 64);
            if (lq == 0) {
                atomicAdd(&colsum[wn + (nt << 4) + lidx], s);
                atomicAdd(&colsq [wn + (nt << 4) + lidx], q);
            }
        }
    }
    if (stats != nullptr) {
        __syncthreads();
        if (tid < 128) {
            atomicAdd(&stats[n0 + tid],       colsum[tid]);
            atomicAdd(&stats[512 + n0 + tid], colsq[tid]);
        }
    }
}

// ===== bf16 MFMA GEMM, 256x256 tile, gload_lds + 2-phase (d3) ==============
__global__ __launch_bounds__(512)
void k_m256(const unsigned short* __restrict__ Abase,
            const unsigned short* __restrict__ Bt,
            unsigned short* __restrict__ Cb,
            float* __restrict__ stats,
            int Mslice, int K, int N, int decK)
{
    __shared__ __align__(16) unsigned short As[2][256 * 64];
    __shared__ __align__(16) unsigned short Bs[2][256 * 64];
    __shared__ float colsum[256], colsq[256];

    const int tid  = threadIdx.x;
    const int lane = tid & 63;
    const int wave = tid >> 6;          // 0..7
    const int wm = (wave >> 2) << 7;    // 0,128
    const int wn = (wave & 3) << 6;     // 0,64,128,192
    const int z  = blockIdx.z;
    const int n0 = blockIdx.x << 8;
    const int m0 = blockIdx.y << 8;

    if (stats != nullptr && tid < 256) { colsum[tid] = 0.f; colsq[tid] = 0.f; }

    const int a_slice = z / decK, wk = z - a_slice * decK;
    const unsigned short* Ap = Abase + (size_t)a_slice * (size_t)Mslice * (size_t)K;
    const unsigned short* Bp = Bt + (size_t)wk * (size_t)N * (size_t)K;

    const int srow  = tid >> 3;                       // 0..63 (row within chunk)
    const int selem = ((tid & 7) ^ (srow & 7)) << 3;  // swizzled elem offset
    const unsigned short* Asrc = Ap + (size_t)(m0 + srow) * K + selem;

    size_t boff[4];
#pragma unroll
    for (int c = 0; c < 4; ++c) {
        int brow = n0 + srow + (c << 6);
        if (brow > N - 1) brow = N - 1;
        boff[c] = (size_t)brow * K + selem;
    }

    f32x4 acc[8][4];
#pragma unroll
    for (int i = 0; i < 8; ++i)
#pragma unroll
        for (int j = 0; j < 4; ++j) acc[i][j] = (f32x4){0.f, 0.f, 0.f, 0.f};

    const int lidx = lane & 15;
    const int lq   = lane >> 4;

    // ---- prologue: stage chunk 0 into buffer 0 ----
#pragma unroll
    for (int c = 0; c < 4; ++c) {
        gload16(Asrc + (size_t)(c << 6) * K, &As[0][tid * 8 + (c << 12)]);
        gload16(Bp + boff[c],                &Bs[0][tid * 8 + (c << 12)]);
    }
    __syncthreads();

    const int nsteps = K >> 6;
    int cur = 0;
    for (int t = 0; t < nsteps; ++t) {
        if (t + 1 < nsteps) {
            const int k0n = (t + 1) << 6;
#pragma unroll
            for (int c = 0; c < 4; ++c) {
                gload16(Asrc + (size_t)(c << 6) * K + k0n,
                        &As[cur ^ 1][tid * 8 + (c << 12)]);
                gload16(Bp + boff[c] + k0n,
                        &Bs[cur ^ 1][tid * 8 + (c << 12)]);
            }
        }
#pragma unroll
        for (int ks = 0; ks < 2; ++ks) {
            const int ub = (ks << 2) + lq;                        // 16B unit idx
            const int uo = (ub ^ (lidx & 7)) << 3;                // swizzled elems
            bf16x8 af[8], bfv[4];
#pragma unroll
            for (int i = 0; i < 8; ++i)
                af[i] = *(const bf16x8*)&As[cur][((wm + (i << 4) + lidx) << 6) + uo];
#pragma unroll
            for (int j = 0; j < 4; ++j)
                bfv[j] = *(const bf16x8*)&Bs[cur][((wn + (j << 4) + lidx) << 6) + uo];
#pragma unroll
            for (int mt = 0; mt < 8; ++mt)
#pragma unroll
                for (int nt = 0; nt < 4; ++nt)
                    acc[mt][nt] = __builtin_amdgcn_mfma_f32_16x16x32_bf16(
                        af[mt], bfv[nt], acc[mt][nt], 0, 0, 0);
        }
        __syncthreads();
        cur ^= 1;
    }

    const int rbase = lq << 2;
#pragma unroll
    for (int nt = 0; nt < 4; ++nt) {
        const int col = n0 + wn + (nt << 4) + lidx;
        float s = 0.f, q = 0.f;
#pragma unroll
        for (int mt = 0; mt < 8; ++mt) {
#pragma unroll
            for (int r = 0; r < 4; ++r) {
                float x = acc[mt][nt][r];
                s += x; q += x * x;
                const int row = m0 + wm + (mt << 4) + rbase + r;
                Cb[((size_t)z * Mslice + row) * (size_t)N + col] = bfh(x);
            }
        }
        if (stats != nullptr) {
            s += __shfl_xor(s, 16, 64); s += __shfl_xor(s, 32, 64);
            q += __shfl_xor(q, 16, 64); q += __shfl_xor(q, 32, 64);
            if (lq == 0) {
                atomicAdd(&colsum[wn + (nt << 4) + lidx], s);
                atomicAdd(&colsq [wn + (nt << 4) + lidx], q);
            }
        }
    }
    if (stats != nullptr) {
        __syncthreads();
        if (tid < 256) {
            atomicAdd(&stats[n0 + tid],       colsum[tid]);
            atomicAdd(&stats[512 + n0 + tid], colsq[tid]);
        }
    }
}

// ===== bf16 MFMA GEMM, 64x64 tile, gload_lds + 2-phase (d0,d1) =============
__global__ __launch_bounds__(256)
void k_b64g(const unsigned short* __restrict__ Abase,
            const unsigned short* __restrict__ Bt,
            unsigned short* __restrict__ Cb,
            const float* __restrict__ bias,
            float* __restrict__ stats,
            int Mslice, int K, int N, int decK)
{
    __shared__ __align__(16) unsigned short As[2][64 * 64];
    __shared__ __align__(16) unsigned short Bs[2][64 * 64];
    __shared__ float colsum[64], colsq[64];

    const int tid  = threadIdx.x;
    const int lane = tid & 63;
    const int wave = tid >> 6;
    const int wm = (wave >> 1) << 5;
    const int wn = (wave & 1) << 5;
    const int z  = blockIdx.z;
    const int n0 = blockIdx.x << 6;
    const int m0 = blockIdx.y << 6;

    if (stats != nullptr && tid < 64) { colsum[tid] = 0.f; colsq[tid] = 0.f; }

    const int a_slice = z / decK, wk = z - a_slice * decK;
    const unsigned short* Ap = Abase + (size_t)a_slice * (size_t)Mslice * (size_t)K;
    const unsigned short* Bp = Bt + (size_t)wk * (size_t)N * (size_t)K;

    const int srow  = tid >> 3;                       // 0..31
    const int selem = ((tid & 7) ^ (srow & 7)) << 3;
    const unsigned short* Asrc = Ap + (size_t)(m0 + srow) * K + selem;
    const unsigned short* Bsrc = Bp + (size_t)(n0 + srow) * K + selem;

    f32x4 acc[2][2];
#pragma unroll
    for (int i = 0; i < 2; ++i)
#pragma unroll
        for (int j = 0; j < 2; ++j) acc[i][j] = (f32x4){0.f, 0.f, 0.f, 0.f};

    const int lidx = lane & 15;
    const int lq   = lane >> 4;

    // ---- prologue: stage chunk 0 into buffer 0 ----
#pragma unroll
    for (int c = 0; c < 2; ++c) {
        gload16(Asrc + (size_t)(c << 5) * K, &As[0][tid * 8 + (c << 11)]);
        gload16(Bsrc + (size_t)(c << 5) * K, &Bs[0][tid * 8 + (c << 11)]);
    }
    __syncthreads();

    const int nsteps = K >> 6;
    int cur = 0;
    for (int t = 0; t < nsteps; ++t) {
        if (t + 1 < nsteps) {
            const int k0n = (t + 1) << 6;
#pragma unroll
            for (int c = 0; c < 2; ++c) {
                gload16(Asrc + (size_t)(c << 5) * K + k0n,
                        &As[cur ^ 1][tid * 8 + (c << 11)]);
                gload16(Bsrc + (size_t)(c << 5) * K + k0n,
                        &Bs[cur ^ 1][tid * 8 + (c << 11)]);
            }
        }
#pragma unroll
        for (int ks = 0; ks < 2; ++ks) {
            const int ub = (ks << 2) + lq;
            const int uo = (ub ^ (lidx & 7)) << 3;
            bf16x8 af[2], bfv[2];
#pragma unroll
            for (int t2 = 0; t2 < 2; ++t2)
                af[t2] = *(const bf16x8*)&As[cur][((wm + (t2 << 4) + lidx) << 6) + uo];
#pragma unroll
            for (int t2 = 0; t2 < 2; ++t2)
                bfv[t2] = *(const bf16x8*)&Bs[cur][((wn + (t2 << 4) + lidx) << 6) + uo];
#pragma unroll
            for (int mt = 0; mt < 2; ++mt)
#pragma unroll
                for (int nt = 0; nt < 2; ++nt)
                    acc[mt][nt] = __builtin_amdgcn_mfma_f32_16x16x32_bf16(
                        af[mt], bfv[nt], acc[mt][nt], 0, 0, 0);
        }
        __syncthreads();
        cur ^= 1;
    }

    const int rbase = lq << 2;
#pragma unroll
    for (int nt = 0; nt < 2; ++nt) {
        const int col = n0 + wn + (nt << 4) + lidx;
        const float badd = (bias != nullptr) ? bias[col] : 0.f;
        float s = 0.f, q = 0.f;
#pragma unroll
        for (int mt = 0; mt < 2; ++mt) {
#pragma unroll
            for (int r = 0; r < 4; ++r) {
                float x = acc[mt][nt][r];
                s += x; q += x * x;
                const int row = m0 + wm + (mt << 4) + rbase + r;
                Cb[((size_t)z * Mslice + row) * (size_t)N + col] = bfh(x + badd);
            }
        }
        if (stats != nullptr) {
            s += __shfl_xor(s, 16, 64); s += __shfl_xor(s, 32, 64);
            q += __shfl_xor(q, 16, 64); q += __shfl_xor(q, 32, 64);
            if (lq == 0) {
                atomicAdd(&colsum[wn + (nt << 4) + lidx], s);
                atomicAdd(&colsq [wn + (nt << 4) + lidx], q);
            }
        }
    }
    if (stats != nullptr) {
        __syncthreads();
        if (tid < 64) {
            atomicAdd(&stats[n0 + tid],       colsum[tid]);
            atomicAdd(&stats[512 + n0 + tid], colsq[tid]);
        }
    }
}

// ===== split-bf16 MFMA GEMM, 64x64 tile, gload_lds + 2-phase (e1,e2,e3) ====
// Linear LDS [2][64][32] bf16 per buffer; XOR-swizzle unit^(row&3).
__global__ __launch_bounds__(256)
void k_sp64g(const unsigned short* __restrict__ Ahg,
             const unsigned short* __restrict__ Alg,
             const unsigned short* __restrict__ Whi,
             const unsigned short* __restrict__ Wlo,
             float* __restrict__ Cout, float* __restrict__ stats,
             int Mslice, int Kp, int N, int n_terms)
{
    __shared__ __align__(16) unsigned short Ah[2][64 * 32];
    __shared__ __align__(16) unsigned short Al[2][64 * 32];
    __shared__ __align__(16) unsigned short Bh[2][64 * 32];
    __shared__ __align__(16) unsigned short Bl[2][64 * 32];
    __shared__ float colsum[64], colsq[64];

    const int tid  = threadIdx.x;
    const int lane = tid & 63;
    const int wave = tid >> 6;
    const int wm = (wave >> 1) << 5;
    const int wn = (wave & 1) << 5;
    const int z  = blockIdx.z;
    const int n0 = blockIdx.x << 6;
    const int m0 = blockIdx.y << 6;

    if (stats != nullptr && tid < 64) { colsum[tid] = 0.f; colsq[tid] = 0.f; }

    const int srow  = tid >> 2;                       // 0..63
    const int selem = ((tid & 3) ^ (srow & 3)) << 3;  // swizzled elem in 32-row

    f32x4 acc[2][2];
#pragma unroll
    for (int i = 0; i < 2; ++i)
#pragma unroll
        for (int j = 0; j < 2; ++j) acc[i][j] = (f32x4){0.f, 0.f, 0.f, 0.f};

    const int lidx = lane & 15;
    const int lq   = lane >> 4;
    const int uo   = (lq ^ (lidx & 3)) << 3;          // swizzled read offset

    const int cpk = Kp >> 5;
    const int tot = n_terms * cpk;

    // ---- prologue: stage chunk 0 (term 0, k 0) into buffer 0 ----
    {
        const size_t ab = ((size_t)(z * n_terms) * Mslice + m0 + srow)
                          * (size_t)Kp + selem;
        const size_t bb = ((size_t)(n0 + srow)) * (size_t)Kp + selem;
        gload16(Ahg + ab, &Ah[0][tid * 8]);
        gload16(Alg + ab, &Al[0][tid * 8]);
        gload16(Whi + bb, &Bh[0][tid * 8]);
        gload16(Wlo + bb, &Bl[0][tid * 8]);
    }
    __syncthreads();

    int cur = 0;
    int lt = 0, lk = 32;
    if (lk >= Kp) { lk = 0; lt = 1; }
    for (int c = 0; c < tot; ++c) {
        if (c + 1 < tot) {
            const size_t ab = ((size_t)(z * n_terms + lt) * Mslice + m0 + srow)
                              * (size_t)Kp + lk + selem;
            const size_t bb = ((size_t)lt * N + n0 + srow) * (size_t)Kp + lk + selem;
            gload16(Ahg + ab, &Ah[cur ^ 1][tid * 8]);
            gload16(Alg + ab, &Al[cur ^ 1][tid * 8]);
            gload16(Whi + bb, &Bh[cur ^ 1][tid * 8]);
            gload16(Wlo + bb, &Bl[cur ^ 1][tid * 8]);
            lk += 32; if (lk >= Kp) { lk = 0; ++lt; }
        }
        bf16x8 ah[2], al[2], bh[2], bl[2];
#pragma unroll
        for (int t = 0; t < 2; ++t) {
            const int ra = ((wm + (t << 4) + lidx) << 5) + uo;
            ah[t] = *(const bf16x8*)&Ah[cur][ra];
            al[t] = *(const bf16x8*)&Al[cur][ra];
        }
#pragma unroll
        for (int t = 0; t < 2; ++t) {
            const int rb = ((wn + (t << 4) + lidx) << 5) + uo;
            bh[t] = *(const bf16x8*)&Bh[cur][rb];
            bl[t] = *(const bf16x8*)&Bl[cur][rb];
        }
#pragma unroll
        for (int mt = 0; mt < 2; ++mt)
#pragma unroll
            for (int nt = 0; nt < 2; ++nt) {
                acc[mt][nt] = __builtin_amdgcn_mfma_f32_16x16x32_bf16(
                    ah[mt], bh[nt], acc[mt][nt], 0, 0, 0);
                acc[mt][nt] = __builtin_amdgcn_mfma_f32_16x16x32_bf16(
                    al[mt], bh[nt], acc[mt][nt], 0, 0, 0);
                acc[mt][nt] = __builtin_amdgcn_mfma_f32_16x16x32_bf16(
                    ah[mt], bl[nt], acc[mt][nt], 0, 0, 0);
            }
        __syncthreads();
        cur ^= 1;
    }

    const int rbase = lq << 2;
#pragma unroll
    for (int nt = 0; nt < 2; ++nt) {
        const int col = n0 + wn + (nt << 4) + lidx;
        float s = 0.f, q = 0.f;
#pragma unroll
        for (int mt = 0; mt < 2; ++mt) {
#pragma unroll
            for (int r = 0; r < 4; ++r) {
                float x = acc[mt][nt][r];
                s += x; q += x * x;
                const int row = m0 + wm + (mt << 4) + rbase + r;
                Cout[((size_t)z * Mslice + row) * (size_t)N + col] = x;
            }
        }
        if (stats != nullptr) {
            s += __shfl_xor(s, 16, 64); s += __shfl_xor(s, 32, 64);
            q += __shfl_xor(q, 16, 64); q += __shfl_xor(q, 32, 64);
            if (lq == 0) {
                atomicAdd(&colsum[wn + (nt << 4) + lidx], s);
                atomicAdd(&colsq [wn + (nt << 4) + lidx], q);
            }
        }
    }
    if (stats != nullptr) {
        __syncthreads();
        if (tid < 64) {
            atomicAdd(&stats[n0 + tid],       colsum[tid]);
            atomicAdd(&stats[512 + n0 + tid], colsq[tid]);
        }
    }
}

// ================= merged prep kernel (9 independent preps) ================
__global__ void k_prep(float* __restrict__ zbase, unsigned long long* __restrict__ amin,
                       const float* __restrict__ codebook, float* __restrict__ codeT,
                       float* __restrict__ codesq,
                       const float* __restrict__ w_e2, unsigned short* __restrict__ whi_e2,
                       unsigned short* __restrict__ wlo_e2,
                       const float* __restrict__ w_e3, unsigned short* __restrict__ whi_e3,
                       unsigned short* __restrict__ wlo_e3,
                       const float* __restrict__ W_q,  unsigned short* __restrict__ wqb,
                       const float* __restrict__ w_d1, unsigned short* __restrict__ wd1b,
                       const float* __restrict__ w_d2, unsigned short* __restrict__ wd2b,
                       const float* __restrict__ w_d3, unsigned short* __restrict__ wd3b,
                       const float* __restrict__ W_out, unsigned short* __restrict__ woutb,
                       const float* __restrict__ in_seqs,
                       unsigned short* __restrict__ in_h, unsigned short* __restrict__ in_l)
{
    __shared__ float red[4];
    const int bid = blockIdx.x;
    const int tid = threadIdx.x;

    if (bid < 32) {                                    // s0: init
        int t = bid * 256 + tid;
        if (t < 6720) zbase[t] = 0.f;
        if (t < 1024) amin[t] = ~0ULL;
        return;
    }
    if (bid < 1056) {                                  // s1: codeT repack (Kc=1)
        int idx = (bid - 32) * 256 + tid;
        int i = (idx >> 9) & 511, o = idx & 511;
        codeT[idx] = codebook[(o << 9) + i];
        return;
    }
    if (bid < 1568) {                                  // s2: codesq
        int c = bid - 1056;
        float s = 0.f;
        for (int i = tid; i < 512; i += 256) { float v = codebook[c * 512 + i]; s += v * v; }
        for (int off = 32; off; off >>= 1) s += __shfl_down(s, off, 64);
        if ((tid & 63) == 0) red[tid >> 6] = s;
        __syncthreads();
        if (tid == 0) codesq[c] = red[0] + red[1] + red[2] + red[3];
        return;
    }
    if (bid < 4640) {                                  // s3: split e2 (Kc=3)
        int idx = (bid - 1568) * 256 + tid;
        int i = idx & 511, o = (idx >> 9) & 511, k = idx >> 18;
        float v = w_e2[(((o << 9) + i) * 3) + k];
        unsigned short h = bfh(v);
        whi_e2[idx] = h; wlo_e2[idx] = bfh(v - bf2f(h));
        return;
    }
    if (bid < 6688) {                                  // s4: split e3 (Kc=2)
        int idx = (bid - 4640) * 256 + tid;
        int i = idx & 511, o = (idx >> 9) & 511, k = idx >> 18;
        float v = w_e3[(((o << 9) + i) * 2) + k];
        unsigned short h = bfh(v);
        whi_e3[idx] = h; wlo_e3[idx] = bfh(v - bf2f(h));
        return;
    }
    if (bid < 7712) {                                  // s5: W_q bf (Kc=1,I=O=512)
        int idx = (bid - 6688) * 256 + tid;
        int i = idx & 511, o = (idx >> 9) & 511;
        wqb[idx] = bfh(W_q[((size_t)i << 9) + o]);
        return;
    }
    if (bid < 9760) {                                  // s6: w_d1 bf (Kc=2)
        int idx = (bid - 7712) * 256 + tid;
        int i = idx & 511, o = (idx >> 9) & 511, k = idx >> 18;
        wd1b[idx] = bfh(w_d1[(((size_t)i << 9) + o) * 2 + k]);
        return;
    }
    if (bid < 12832) {                                 // s7: w_d2 bf (Kc=3)
        int idx = (bid - 9760) * 256 + tid;
        int i = idx & 511, o = (idx >> 9) & 511, k = idx >> 18;
        wd2b[idx] = bfh(w_d2[(((size_t)i << 9) + o) * 3 + k]);
        return;
    }
    if (bid < 17952) {                                 // s8: w_d3 bf (Kc=5)
        int idx = (bid - 12832) * 256 + tid;
        int i = idx & 511, o = (idx >> 9) & 511, k = idx >> 18;
        wd3b[idx] = bfh(w_d3[(((size_t)i << 9) + o) * 5 + k]);
        return;
    }
    if (bid < 18222) {                                 // s9: W_out bf (Kc=1,I=512,O=135)
        int idx = (bid - 17952) * 256 + tid;
        if (idx >= 69120) return;
        int i = idx % 512, o = idx / 512;              // [o][i], o<135
        woutb[idx] = bfh(W_out[((size_t)i * 135) + o]);
        return;
    }
    {                                                  // s10: split_in
        int idx = (bid - 18222) * 256 + tid;
        if (idx >= 4915200) return;
        int i = idx % 160, r = idx / 160;
        float v = (i < 135) ? in_seqs[(size_t)r * 135 + i] : 0.f;
        unsigned short h = bfh(v);
        in_h[idx] = h; in_l[idx] = bfh(v - bf2f(h));
    }
}

// ============================ small kernels ================================
__global__ void k_repack(const float* __restrict__ w, float* __restrict__ wt,
                         int Kc, int total)
{
    int idx = blockIdx.x * 256 + threadIdx.x;
    if (idx >= total) return;
    int k = idx >> 18;
    int rem = idx & 262143;
    int i = rem >> 9, o = rem & 511;
    wt[idx] = w[(((o << 9) + i) * Kc + k)];
}

__global__ void k_repack_sp_weff(const float* __restrict__ weff,
                                 unsigned short* __restrict__ whi,
                                 unsigned short* __restrict__ wlo,
                                 int total)
{
    int idx = blockIdx.x * 256 + threadIdx.x;
    if (idx >= total) return;
    int i = idx % 160;
    int o = (idx / 160) & 511;
    int t = idx / 81920;
    float v = (i < 135) ? weff[((size_t)t * 135 + i) * 512 + o] : 0.f;
    unsigned short h = bfh(v);
    whi[idx] = h;
    wlo[idx] = bfh(v - bf2f(h));
}

__global__ void k_bnsplit(const float* __restrict__ x,
                          const float* __restrict__ sc, const float* __restrict__ sh,
                          unsigned short* __restrict__ hq, unsigned short* __restrict__ lq_,
                          int total4)
{
    int idx = blockIdx.x * 256 + threadIdx.x;
    if (idx >= total4) return;
    const int base = idx << 2;
    float4 f = *(const float4*)(x + base);
    const int k = base & 511;
    float4 s = *(const float4*)(sc + k);
    float4 c = *(const float4*)(sh + k);
    float y0 = fmaxf(fmaf(f.x, s.x, c.x), 0.f);
    float y1 = fmaxf(fmaf(f.y, s.y, c.y), 0.f);
    float y2 = fmaxf(fmaf(f.z, s.z, c.z), 0.f);
    float y3 = fmaxf(fmaf(f.w, s.w, c.w), 0.f);
    unsigned short h0 = bfh(y0), h1 = bfh(y1), h2 = bfh(y2), h3 = bfh(y3);
    unsigned short l0 = bfh(y0 - bf2f(h0)), l1 = bfh(y1 - bf2f(h1));
    unsigned short l2 = bfh(y2 - bf2f(h2)), l3 = bfh(y3 - bf2f(h3));
    *(uint2*)&hq[base]  = make_uint2((unsigned)h0 | ((unsigned)h1 << 16),
                                     (unsigned)h2 | ((unsigned)h3 << 16));
    *(uint2*)&lq_[base] = make_uint2((unsigned)l0 | ((unsigned)l1 << 16),
                                     (unsigned)l2 | ((unsigned)l3 << 16));
}

__global__ void k_bnapply(const unsigned short* __restrict__ x,
                          const float* __restrict__ sc, const float* __restrict__ sh,
                          unsigned short* __restrict__ y, int total8)
{
    int idx = blockIdx.x * 256 + threadIdx.x;
    if (idx >= total8) return;
    const int base = idx << 3;
    uint4 raw = *(const uint4*)(x + base);
    const int k = base & 511;
    float4 s0 = *(const float4*)(sc + k);
    float4 c0 = *(const float4*)(sh + k);
    float4 s1 = *(const float4*)(sc + k + 4);
    float4 c1 = *(const float4*)(sh + k + 4);
    unsigned* u = (unsigned*)&raw;
    float x0 = __uint_as_float(u[0] << 16),        x1 = __uint_as_float(u[0] & 0xffff0000u);
    float x2 = __uint_as_float(u[1] << 16),        x3 = __uint_as_float(u[1] & 0xffff0000u);
    float x4 = __uint_as_float(u[2] << 16),        x5 = __uint_as_float(u[2] & 0xffff0000u);
    float x6 = __uint_as_float(u[3] << 16),        x7 = __uint_as_float(u[3] & 0xffff0000u);
    x0 = fmaxf(fmaf(x0, s0.x, c0.x), 0.f); x1 = fmaxf(fmaf(x1, s0.y, c0.y), 0.f);
    x2 = fmaxf(fmaf(x2, s0.z, c0.z), 0.f); x3 = fmaxf(fmaf(x3, s0.w, c0.w), 0.f);
    x4 = fmaxf(fmaf(x4, s1.x, c1.x), 0.f); x5 = fmaxf(fmaf(x5, s1.y, c1.y), 0.f);
    x6 = fmaxf(fmaf(x6, s1.z, c1.z), 0.f); x7 = fmaxf(fmaf(x7, s1.w, c1.w), 0.f);
    *(uint4*)&y[base] = make_uint4(pk_bf16(x0, x1), pk_bf16(x2, x3),
                                   pk_bf16(x4, x5), pk_bf16(x6, x7));
}

__global__ void k_bn_fin(const float* __restrict__ stats,
                         const float* __restrict__ g, const float* __restrict__ b,
                         float* __restrict__ sc, float* __restrict__ sh, float inv_n)
{
    int c = blockIdx.x * blockDim.x + threadIdx.x;
    if (c >= 512) return;
    float m = stats[c] * inv_n;
    float v = stats[512 + c] * inv_n - m * m;
    float a = (float)((double)g[c] / sqrt((double)v + 1e-5));
    sc[c] = a;
    sh[c] = b[c] - m * a;
}

__global__ void k_vq_gather(const unsigned long long* __restrict__ amin,
                            const float* __restrict__ codebook,
                            const float* __restrict__ e3pre,
                            const float* __restrict__ sc, const float* __restrict__ sh,
                            unsigned short* __restrict__ quant_bf,
                            float* __restrict__ loss,
                            unsigned int* __restrict__ hist)
{
    int b = blockIdx.x; int t = threadIdx.x;   // 256 threads
    unsigned int idx = (unsigned int)(amin[b] & 0xFFFFFFFFull) & 511u;
    float part = 0.f;
    for (int i = t; i < 512; i += 256) {
        float q = codebook[(size_t)idx * 512 + i];
        quant_bf[(size_t)b * 512 + i] = bfh(q);
        float x = e3pre[(size_t)b * 512 + i];
        float f = fmaxf(fmaf(x, sc[i], sh[i]), 0.f);
        float d = q - f;
        part += d * d;
    }
    for (int off = 32; off; off >>= 1) part += __shfl_down(part, off, 64);
    __shared__ float red[4];
    if ((t & 63) == 0) red[t >> 6] = part;
    __syncthreads();
    if (t == 0) {
        atomicAdd(loss, red[0] + red[1] + red[2] + red[3]);
        atomicAdd(&hist[idx], 1u);
    }
}

__global__ void k_scalars(const unsigned int* __restrict__ hist,
                          const float* __restrict__ loss, float* __restrict__ out)
{
    int t = threadIdx.x;   // 512
    float p = (float)hist[t] * (1.0f / 1024.0f);
    float e = p * logf(p + 1e-10f);
    for (int off = 32; off; off >>= 1) e += __shfl_down(e, off, 64);
    __shared__ float red[8];
    if ((t & 63) == 0) red[t >> 6] = e;
    __syncthreads();
    if (t == 0) {
        float s = 0.f;
        for (int i = 0; i < 8; ++i) s += red[i];
        out[4147200] = 1.25f * loss[0] * (1.0f / 524288.0f);
        out[4147201] = expf(-s);
    }
}

extern "C" void kernel_launch(void* const* d_in, const int* in_sizes, int n_in,
                              void* d_out, int out_size, void* d_ws, size_t ws_size,
                              hipStream_t stream)
{
    const float* in_seqs = (const float*)d_in[0];
    const float* W_in  = (const float*)d_in[1];
    const float* w_e1  = (const float*)d_in[3];
    const float* g_e1  = (const float*)d_in[4];
    const float* be1   = (const float*)d_in[5];
    const float* w_e2  = (const float*)d_in[6];
    const float* g_e2  = (const float*)d_in[7];
    const float* be2   = (const float*)d_in[8];
    const float* w_e3  = (const float*)d_in[9];
    const float* g_e3  = (const float*)d_in[10];
    const float* be3   = (const float*)d_in[11];
    const float* codebook = (const float*)d_in[12];
    const float* W_q   = (const float*)d_in[13];
    const float* b_q   = (const float*)d_in[14];
    const float* w_d1  = (const float*)d_in[15];
    const float* g_d1  = (const float*)d_in[16];
    const float* bd1   = (const float*)d_in[17];
    const float* w_d2  = (const float*)d_in[18];
    const float* g_d2  = (const float*)d_in[19];
    const float* bd2   = (const float*)d_in[20];
    const float* w_d3  = (const float*)d_in[21];
    const float* g_d3  = (const float*)d_in[22];
    const float* bd3   = (const float*)d_in[23];
    const float* W_out = (const float*)d_in[24];
    const float* b_out = (const float*)d_in[25];
    float* out = (float*)d_out;

    // ---- workspace layout (float offsets) ----
    float* W = (float*)d_ws;
    unsigned long long* amin = (unsigned long long*)W;            // 2048 f
    float* stats  = W + 2048;                                     // 6144
    float* lossp  = W + 8192;                                     // 64
    unsigned int* hist = (unsigned int*)(W + 8256);               // 512
    float* scsh   = W + 8768;                                     // 6144
    float* codesq = W + 14912;                                    // 512
    float* wt_e1  = W + 15424;                                    // 1310720 f
    float* weff   = W + 1326144;                                  // 345600 f
    float* codeT  = W + 1671744;                                  // 262144 f
    unsigned short* esw = (unsigned short*)(W + 1933888);         // 3440640 ush
    unsigned short* whi_e1 = esw;
    unsigned short* wlo_e1 = esw + 409600;
    unsigned short* whi_e2 = esw + 819200;
    unsigned short* wlo_e2 = esw + 1605632;
    unsigned short* whi_e3 = esw + 2392064;
    unsigned short* wlo_e3 = esw + 2916352;
    unsigned short* in_h  = (unsigned short*)(W + 3654208);       // 4915200 ush
    unsigned short* in_l  = in_h + 4915200;
    unsigned short* d3pre = (unsigned short*)(W + 3654208);       // 15728640 ush
    float* e1f = W + 11518528;                                    // 3145728 f
    unsigned short* e1h = (unsigned short*)(W + 14664256);        // 3145728 ush
    unsigned short* e1l = e1h + 3145728;
    float* e2f = W + 17809984;                                    // 1048576 f
    unsigned short* e2h = (unsigned short*)(W + 18858560);        // 1048576 ush
    unsigned short* e2l = e2h + 1048576;
    unsigned short* d2pre = (unsigned short*)(W + 17809984);      // 3145728 ush
    unsigned short* d2bf  = d2pre + 3145728;                      // 3145728 ush
    float* e3f = W + 20955712;                                    // 524288 f
    unsigned short* quant_bf = (unsigned short*)(W + 21480000);   // 524288 ush
    unsigned short* d0bf     = (unsigned short*)(W + 21742144);   // 524288 ush
    unsigned short* d1pre    = (unsigned short*)(W + 22004288);   // 1048576 ush
    unsigned short* d1bf     = (unsigned short*)(W + 22528640);   // 1048576 ush
    unsigned short* d3bf     = (unsigned short*)(W + 23052928);   // 15728640 ush
    // d3bf ends at f-offset 30917248 (~124 MB) < 256 MiB ws.

    unsigned short* db    = (unsigned short*)wt_e1;
    unsigned short* wqb   = db;
    unsigned short* wd1b  = db + 262144;
    unsigned short* wd2b  = db + 786432;
    unsigned short* wd3b  = db + 1572864;
    unsigned short* woutb = db + 2883584;

    float* st_e1 = stats + 0 * 1024; float* sc_e1 = scsh + 0 * 1024; float* sh_e1 = sc_e1 + 512;
    float* st_e2 = stats + 1 * 1024; float* sc_e2 = scsh + 1 * 1024; float* sh_e2 = sc_e2 + 512;
    float* st_e3 = stats + 2 * 1024; float* sc_e3 = scsh + 2 * 1024; float* sh_e3 = sc_e3 + 512;
    float* st_d1 = stats + 3 * 1024; float* sc_d1 = scsh + 3 * 1024; float* sh_d1 = sc_d1 + 512;
    float* st_d2 = stats + 4 * 1024; float* sc_d2 = scsh + 4 * 1024; float* sh_d2 = sc_d2 + 512;
    float* st_d3 = stats + 5 * 1024; float* sc_d3 = scsh + 5 * 1024; float* sh_d3 = sc_d3 + 512;

    dim3 blk(256);

    // order: wt_e1 fp32 repack -> weff gemm -> sp_weff, THEN k_prep (which
    // fills decoder bf16 weights over the then-dead wt_e1 region).
    k_repack<<<dim3(5 * 1024), blk, 0, stream>>>(w_e1, wt_e1, 5, 5 * 262144);
    k_gemm<<<dim3(16, 5, 5), blk, 0, stream>>>(W_in, wt_e1, weff,
        nullptr, nullptr, nullptr, nullptr, 135, 512, 512, 5);
    k_repack_sp_weff<<<dim3(1600), blk, 0, stream>>>(weff, whi_e1, wlo_e1, 409600);

    k_prep<<<dim3(37422), blk, 0, stream>>>(stats, amin,
        codebook, codeT, codesq,
        w_e2, whi_e2, wlo_e2, w_e3, whi_e3, wlo_e3,
        W_q, wqb, w_d1, wd1b, w_d2, wd2b, w_d3, wd3b, W_out, woutb,
        in_seqs, in_h, in_l);

    // ---- encoder: 64x64-tile split-bf16 MFMA (gload_lds, 2-phase) ----
    k_sp64g<<<dim3(8, 16, 6), blk, 0, stream>>>(in_h, in_l, whi_e1, wlo_e1,
        e1f, st_e1, 1024, 160, 512, 5);
    k_bn_fin<<<dim3(2), blk, 0, stream>>>(st_e1, g_e1, be1, sc_e1, sh_e1, 1.f / 6144.f);
    k_bnsplit<<<dim3(3072), blk, 0, stream>>>(e1f, sc_e1, sh_e1, e1h, e1l, 786432);

    k_sp64g<<<dim3(8, 16, 2), blk, 0, stream>>>(e1h, e1l, whi_e2, wlo_e2,
        e2f, st_e2, 1024, 512, 512, 3);
    k_bn_fin<<<dim3(2), blk, 0, stream>>>(st_e2, g_e2, be2, sc_e2, sh_e2, 1.f / 2048.f);
    k_bnsplit<<<dim3(1024), blk, 0, stream>>>(e2f, sc_e2, sh_e2, e2h, e2l, 262144);

    k_sp64g<<<dim3(8, 16, 1), blk, 0, stream>>>(e2h, e2l, whi_e3, wlo_e3,
        e3f, st_e3, 1024, 512, 512, 2);
    k_bn_fin<<<dim3(2), blk, 0, stream>>>(st_e3, g_e3, be3, sc_e3, sh_e3, 1.f / 1024.f);

    // ---- VQ: fp32 dist GEMM + argmin (32x32 tiles, 512 blocks) ----
    k_gemm<<<dim3(16, 32, 1), blk, 0, stream>>>(e3f, codeT, nullptr,
        sc_e3, sh_e3, amin, codesq, 1024, 512, 512, 1);
    k_vq_gather<<<dim3(1024), blk, 0, stream>>>(amin, codebook, e3f, sc_e3, sh_e3,
                                                quant_bf, lossp, hist);

    // ---- decoder: all gload_lds 2-phase; BN as separate passes ----
    k_b64g<<<dim3(8, 16, 1), blk, 0, stream>>>(quant_bf, wqb, d0bf,
        b_q, nullptr, 1024, 512, 512, 1);

    k_b64g<<<dim3(8, 16, 2), blk, 0, stream>>>(d0bf, wd1b, d1pre,
        nullptr, st_d1, 1024, 512, 512, 2);
    k_bn_fin<<<dim3(2), blk, 0, stream>>>(st_d1, g_d1, bd1, sc_d1, sh_d1, 1.f / 2048.f);
    k_bnapply<<<dim3(512), blk, 0, stream>>>(d1pre, sc_d1, sh_d1, d1bf, 131072);

    // d2: 128x128 gload_lds 2-phase (192 blocks; kept from round 20)
    k_mfma_g<<<dim3(4, 8, 6), blk, 0, stream>>>(d1bf, wd2b, d2pre,
        nullptr, nullptr, st_d2, 1024, 512, 512, 3);
    k_bn_fin<<<dim3(2), blk, 0, stream>>>(st_d2, g_d2, bd2, sc_d2, sh_d2, 1.f / 6144.f);
    k_bnapply<<<dim3(1536), blk, 0, stream>>>(d2pre, sc_d2, sh_d2, d2bf, 393216);

    // d3: 256x256 tiles, gload_lds 2-phase, 512 threads (240 blocks)
    k_m256<<<dim3(2, 4, 30), dim3(512), 0, stream>>>(d2bf, wd3b, d3pre,
        st_d3, 1024, 512, 512, 5);
    k_bn_fin<<<dim3(2), blk, 0, stream>>>(st_d3, g_d3, bd3, sc_d3, sh_d3, 1.f / 30720.f);
    k_bnapply<<<dim3(7680), blk, 0, stream>>>(d3pre, sc_d3, sh_d3, d3bf, 1966080);

    // out-proj: 128x128 gload_lds 2-phase, operm store, N=135 (B rows clamped)
    k_mfma_g<<<dim3(2, 240, 1), blk, 0, stream>>>(d3bf, woutb, nullptr,
        out, b_out, nullptr, 30720, 512, 135, 1);

    k_scalars<<<dim3(1), dim3(512), 0, stream>>>(hist, lossp, out);
}

// Round 11
// 411.714 us; speedup vs baseline: 1.0760x; 1.0294x over previous
//
#include <hip/hip_runtime.h>
#include <math.h>

// ---------------------------------------------------------------------------
// VQ-VAE forward (round 22 = exact round-18 configuration, the 415.6us best).
//  - POST-MORTEM round 21: d2 on 128^2 k_mfma_g (192 blocks < 256 CUs) lost
//    ~8us to under-occupancy -> reverted to k_b64g (768 blocks). Occupancy
//    rule: bigger tiles only pay while grid >= CU count.
//  - gload_lds 2-phase everywhere; BN as separate bit-identical passes;
//    d3 = 256x256 k_m256 (240x512t blocks); out-proj = 128^2 k_mfma_g.
// ---------------------------------------------------------------------------

typedef __attribute__((ext_vector_type(8))) short bf16x8;
typedef __attribute__((ext_vector_type(4))) float f32x4;

__device__ __forceinline__ unsigned pk_bf16(float a, float b) {
    unsigned ua = __float_as_uint(a), ub = __float_as_uint(b);
    ua += 0x7fffu + ((ua >> 16) & 1u);          // RNE
    ub += 0x7fffu + ((ub >> 16) & 1u);
    return (ua >> 16) | (ub & 0xffff0000u);
}
__device__ __forceinline__ unsigned short bfh(float x) {
    unsigned u = __float_as_uint(x);
    u += 0x7fffu + ((u >> 16) & 1u);
    return (unsigned short)(u >> 16);
}
__device__ __forceinline__ float bf2f(unsigned short h) {
    return __uint_as_float(((unsigned)h) << 16);
}

// async global->LDS DMA, 16 B per lane (global_load_lds_dwordx4)
__device__ __forceinline__ void gload16(const unsigned short* g, unsigned short* l) {
    __builtin_amdgcn_global_load_lds(
        (const __attribute__((address_space(1))) unsigned int*)g,
        (__attribute__((address_space(3))) unsigned int*)l, 16, 0, 0);
}

__device__ __forceinline__ void bn4(float4& a, const float* __restrict__ s,
                                    const float* __restrict__ c) {
    float4 sv = *(const float4*)s;
    float4 cv = *(const float4*)c;
    a.x = fmaxf(fmaf(a.x, sv.x, cv.x), 0.f);
    a.y = fmaxf(fmaf(a.y, sv.y, cv.y), 0.f);
    a.z = fmaxf(fmaf(a.z, sv.z, cv.z), 0.f);
    a.w = fmaxf(fmaf(a.w, sv.w, cv.w), 0.f);
}

// ======================= fp32 GEMM (weff + VQ dist) ========================
#define FBK  32
#define FSTR 36

__global__ __launch_bounds__(256)
void k_gemm(const float* __restrict__ Abase,
            const float* __restrict__ Wt,
            float* __restrict__ Cout,
            const float* __restrict__ bnS, const float* __restrict__ bnB,
            unsigned long long* __restrict__ amin,
            const float* __restrict__ codesq,
            int Mslice, int K, int N, int decK)
{
    __shared__ __align__(16) float As[FBK][FSTR];
    __shared__ __align__(16) float Bs[FBK][FSTR];

    const int tid = threadIdx.x;
    const int z  = blockIdx.z;
    const int n0 = blockIdx.x << 5;
    const int m0 = blockIdx.y << 5;
    const int ty = tid >> 4;          // 0..15  (m pairs)
    const int tx = tid & 15;          // 0..15  (n pairs)

    const int a_slice = z / decK, wk = z - a_slice * decK;
    const float* Ap = Abase + (size_t)a_slice * (size_t)Mslice * (size_t)K;
    const float* Wp = Wt    + (size_t)wk * (size_t)K * (size_t)N;

    const int sr  = tid >> 3;         // 0..31
    const int sc4 = (tid & 7) << 2;   // 0..28

    int mrow = m0 + sr;
    if (mrow > Mslice - 1) mrow = Mslice - 1;
    const float* Arow_p = Ap + (size_t)mrow * K;

    float acc[2][2];
    acc[0][0] = 0.f; acc[0][1] = 0.f; acc[1][0] = 0.f; acc[1][1] = 0.f;

    // ---- prefetch chunk 0 ----
    float4 pa = *(const float4*)(Arow_p + sc4);
    if (bnS != nullptr) bn4(pa, bnS + sc4, bnB + sc4);
    float4 pb = *(const float4*)(Wp + (size_t)sr * N + n0 + sc4);

    for (int k0 = 0; k0 < K; k0 += FBK) {
        __syncthreads();
        As[sc4 + 0][sr] = pa.x;
        As[sc4 + 1][sr] = pa.y;
        As[sc4 + 2][sr] = pa.z;
        As[sc4 + 3][sr] = pa.w;
        *(float4*)&Bs[sr][sc4] = pb;
        const int k0n = k0 + FBK;
        if (k0n < K) {
            pa = *(const float4*)(Arow_p + k0n + sc4);
            if (bnS != nullptr) bn4(pa, bnS + k0n + sc4, bnB + k0n + sc4);
            pb = *(const float4*)(Wp + (size_t)(k0n + sr) * N + n0 + sc4);
        }
        __syncthreads();
#pragma unroll
        for (int kk = 0; kk < FBK; ++kk) {
            float2 av = *(const float2*)&As[kk][ty << 1];
            float2 bv = *(const float2*)&Bs[kk][tx << 1];
            acc[0][0] = fmaf(av.x, bv.x, acc[0][0]);
            acc[0][1] = fmaf(av.x, bv.y, acc[0][1]);
            acc[1][0] = fmaf(av.y, bv.x, acc[1][0]);
            acc[1][1] = fmaf(av.y, bv.y, acc[1][1]);
        }
    }

    if (amin != nullptr) {
        float2 cq = *(const float2*)(codesq + n0 + (tx << 1));
#pragma unroll
        for (int i = 0; i < 2; ++i) {
            const int m = m0 + (ty << 1) + i;
            float d0 = cq.x - 2.f * acc[i][0];
            float d1 = cq.y - 2.f * acc[i][1];
            int bj = (d1 < d0) ? 1 : 0;
            float best = (d1 < d0) ? d1 : d0;
            unsigned u = __float_as_uint(best);
            u = (u & 0x80000000u) ? ~u : (u | 0x80000000u);
            unsigned long long key =
                ((unsigned long long)u << 32) | (unsigned)(n0 + (tx << 1) + bj);
#pragma unroll
            for (int off = 1; off < 16; off <<= 1) {
                unsigned long long o = __shfl_xor(key, off, 64);
                if (o < key) key = o;
            }
            if (tx == 0 && m < Mslice) atomicMin(&amin[m], key);
        }
        return;
    }

#pragma unroll
    for (int i = 0; i < 2; ++i) {
        const int m = m0 + (ty << 1) + i;
        if (m < Mslice) {
            float2 v = make_float2(acc[i][0], acc[i][1]);
            *(float2*)&Cout[((size_t)z * Mslice + m) * N + n0 + (tx << 1)] = v;
        }
    }
}

// ===== bf16 MFMA GEMM, 128x128 tile, gload_lds + 2-phase pipeline ==========
// (out-proj). Linear LDS [2][128][64] bf16; XOR-swizzle: 16B unit u at row r
// holds global unit u^(r&7). B rows clamped to N-1 for padded cols.
__global__ __launch_bounds__(256)
void k_mfma_g(const unsigned short* __restrict__ Abase,
              const unsigned short* __restrict__ Bt,
              unsigned short* __restrict__ Cb,
              float* __restrict__ operm,
              const float* __restrict__ bias,
              float* __restrict__ stats,
              int Mslice, int K, int N, int decK)
{
    __shared__ __align__(16) unsigned short As[2][128 * 64];
    __shared__ __align__(16) unsigned short Bs[2][128 * 64];
    __shared__ float colsum[128], colsq[128];

    const int tid  = threadIdx.x;
    const int lane = tid & 63;
    const int wave = tid >> 6;
    const int wm = (wave >> 1) << 6;
    const int wn = (wave & 1) << 6;
    const int z  = blockIdx.z;
    const int n0 = blockIdx.x << 7;
    const int m0 = blockIdx.y << 7;

    if (stats != nullptr && tid < 128) { colsum[tid] = 0.f; colsq[tid] = 0.f; }

    const int a_slice = z / decK, wk = z - a_slice * decK;
    const unsigned short* Ap = Abase + (size_t)a_slice * (size_t)Mslice * (size_t)K;
    const unsigned short* Bp = Bt + (size_t)wk * (size_t)N * (size_t)K;

    const int srow  = tid >> 3;                       // 0..31 (row within chunk)
    const int selem = ((tid & 7) ^ (srow & 7)) << 3;  // swizzled elem offset
    const unsigned short* Asrc = Ap + (size_t)(m0 + srow) * K + selem;

    size_t boff[4];
#pragma unroll
    for (int c = 0; c < 4; ++c) {
        int brow = n0 + srow + (c << 5);
        if (brow > N - 1) brow = N - 1;
        boff[c] = (size_t)brow * K + selem;
    }

    f32x4 acc[4][4];
#pragma unroll
    for (int i = 0; i < 4; ++i)
#pragma unroll
        for (int j = 0; j < 4; ++j) acc[i][j] = (f32x4){0.f, 0.f, 0.f, 0.f};

    const int lidx = lane & 15;
    const int lq   = lane >> 4;

    // ---- prologue: stage chunk 0 into buffer 0 ----
#pragma unroll
    for (int c = 0; c < 4; ++c) {
        gload16(Asrc + (size_t)(c << 5) * K, &As[0][tid * 8 + (c << 11)]);
        gload16(Bp + boff[c],                &Bs[0][tid * 8 + (c << 11)]);
    }
    __syncthreads();   // vmcnt(0) drain: chunk 0 visible

    const int nsteps = K >> 6;
    int cur = 0;
    for (int t = 0; t < nsteps; ++t) {
        if (t + 1 < nsteps) {
            const int k0n = (t + 1) << 6;
#pragma unroll
            for (int c = 0; c < 4; ++c) {
                gload16(Asrc + (size_t)(c << 5) * K + k0n,
                        &As[cur ^ 1][tid * 8 + (c << 11)]);
                gload16(Bp + boff[c] + k0n,
                        &Bs[cur ^ 1][tid * 8 + (c << 11)]);
            }
        }
#pragma unroll
        for (int ks = 0; ks < 2; ++ks) {
            const int ub = (ks << 2) + lq;                        // 16B unit idx
            const int uo = (ub ^ (lidx & 7)) << 3;                // swizzled elems
            bf16x8 af[4], bfv[4];
#pragma unroll
            for (int t4 = 0; t4 < 4; ++t4)
                af[t4] = *(const bf16x8*)&As[cur][((wm + (t4 << 4) + lidx) << 6) + uo];
#pragma unroll
            for (int t4 = 0; t4 < 4; ++t4)
                bfv[t4] = *(const bf16x8*)&Bs[cur][((wn + (t4 << 4) + lidx) << 6) + uo];
#pragma unroll
            for (int mt = 0; mt < 4; ++mt)
#pragma unroll
                for (int nt = 0; nt < 4; ++nt)
                    acc[mt][nt] = __builtin_amdgcn_mfma_f32_16x16x32_bf16(
                        af[mt], bfv[nt], acc[mt][nt], 0, 0, 0);
        }
        __syncthreads();   // prefetch landed + all waves done reading buf cur
        cur ^= 1;
    }

    const int rbase = lq << 2;
#pragma unroll
    for (int nt = 0; nt < 4; ++nt) {
        const int col = n0 + wn + (nt << 4) + lidx;
        const float badd = (bias != nullptr && col < N) ? bias[col] : 0.f;
        float s = 0.f, q = 0.f;
#pragma unroll
        for (int mt = 0; mt < 4; ++mt) {
#pragma unroll
            for (int r = 0; r < 4; ++r) {
                float x = acc[mt][nt][r];
                s += x; q += x * x;
                const int row = m0 + wm + (mt << 4) + rbase + r;
                if (operm != nullptr) {
                    if (col < N) {
                        const int t = row >> 10, b = row & 1023;
                        operm[(size_t)b * 4050 + t * 135 + col] = x + badd;
                    }
                } else {
                    Cb[((size_t)z * Mslice + row) * (size_t)N + col] = bfh(x + badd);
                }
            }
        }
        if (stats != nullptr) {
            s += __shfl_xor(s, 16, 64); s += __shfl_xor(s, 32, 64);
            q += __shfl_xor(q, 16, 64); q += __shfl_xor(q, 32, 64);
            if (lq == 0) {
                atomicAdd(&colsum[wn + (nt << 4) + lidx], s);
                atomicAdd(&colsq [wn + (nt << 4) + lidx], q);
            }
        }
    }
    if (stats != nullptr) {
        __syncthreads();
        if (tid < 128) {
            atomicAdd(&stats[n0 + tid],       colsum[tid]);
            atomicAdd(&stats[512 + n0 + tid], colsq[tid]);
        }
    }
}

// ===== bf16 MFMA GEMM, 256x256 tile, gload_lds + 2-phase (d3) ==============
__global__ __launch_bounds__(512)
void k_m256(const unsigned short* __restrict__ Abase,
            const unsigned short* __restrict__ Bt,
            unsigned short* __restrict__ Cb,
            float* __restrict__ stats,
            int Mslice, int K, int N, int decK)
{
    __shared__ __align__(16) unsigned short As[2][256 * 64];
    __shared__ __align__(16) unsigned short Bs[2][256 * 64];
    __shared__ float colsum[256], colsq[256];

    const int tid  = threadIdx.x;
    const int lane = tid & 63;
    const int wave = tid >> 6;          // 0..7
    const int wm = (wave >> 2) << 7;    // 0,128
    const int wn = (wave & 3) << 6;     // 0,64,128,192
    const int z  = blockIdx.z;
    const int n0 = blockIdx.x << 8;
    const int m0 = blockIdx.y << 8;

    if (stats != nullptr && tid < 256) { colsum[tid] = 0.f; colsq[tid] = 0.f; }

    const int a_slice = z / decK, wk = z - a_slice * decK;
    const unsigned short* Ap = Abase + (size_t)a_slice * (size_t)Mslice * (size_t)K;
    const unsigned short* Bp = Bt + (size_t)wk * (size_t)N * (size_t)K;

    const int srow  = tid >> 3;                       // 0..63 (row within chunk)
    const int selem = ((tid & 7) ^ (srow & 7)) << 3;  // swizzled elem offset
    const unsigned short* Asrc = Ap + (size_t)(m0 + srow) * K + selem;

    size_t boff[4];
#pragma unroll
    for (int c = 0; c < 4; ++c) {
        int brow = n0 + srow + (c << 6);
        if (brow > N - 1) brow = N - 1;
        boff[c] = (size_t)brow * K + selem;
    }

    f32x4 acc[8][4];
#pragma unroll
    for (int i = 0; i < 8; ++i)
#pragma unroll
        for (int j = 0; j < 4; ++j) acc[i][j] = (f32x4){0.f, 0.f, 0.f, 0.f};

    const int lidx = lane & 15;
    const int lq   = lane >> 4;

    // ---- prologue: stage chunk 0 into buffer 0 ----
#pragma unroll
    for (int c = 0; c < 4; ++c) {
        gload16(Asrc + (size_t)(c << 6) * K, &As[0][tid * 8 + (c << 12)]);
        gload16(Bp + boff[c],                &Bs[0][tid * 8 + (c << 12)]);
    }
    __syncthreads();

    const int nsteps = K >> 6;
    int cur = 0;
    for (int t = 0; t < nsteps; ++t) {
        if (t + 1 < nsteps) {
            const int k0n = (t + 1) << 6;
#pragma unroll
            for (int c = 0; c < 4; ++c) {
                gload16(Asrc + (size_t)(c << 6) * K + k0n,
                        &As[cur ^ 1][tid * 8 + (c << 12)]);
                gload16(Bp + boff[c] + k0n,
                        &Bs[cur ^ 1][tid * 8 + (c << 12)]);
            }
        }
#pragma unroll
        for (int ks = 0; ks < 2; ++ks) {
            const int ub = (ks << 2) + lq;                        // 16B unit idx
            const int uo = (ub ^ (lidx & 7)) << 3;                // swizzled elems
            bf16x8 af[8], bfv[4];
#pragma unroll
            for (int i = 0; i < 8; ++i)
                af[i] = *(const bf16x8*)&As[cur][((wm + (i << 4) + lidx) << 6) + uo];
#pragma unroll
            for (int j = 0; j < 4; ++j)
                bfv[j] = *(const bf16x8*)&Bs[cur][((wn + (j << 4) + lidx) << 6) + uo];
#pragma unroll
            for (int mt = 0; mt < 8; ++mt)
#pragma unroll
                for (int nt = 0; nt < 4; ++nt)
                    acc[mt][nt] = __builtin_amdgcn_mfma_f32_16x16x32_bf16(
                        af[mt], bfv[nt], acc[mt][nt], 0, 0, 0);
        }
        __syncthreads();
        cur ^= 1;
    }

    const int rbase = lq << 2;
#pragma unroll
    for (int nt = 0; nt < 4; ++nt) {
        const int col = n0 + wn + (nt << 4) + lidx;
        float s = 0.f, q = 0.f;
#pragma unroll
        for (int mt = 0; mt < 8; ++mt) {
#pragma unroll
            for (int r = 0; r < 4; ++r) {
                float x = acc[mt][nt][r];
                s += x; q += x * x;
                const int row = m0 + wm + (mt << 4) + rbase + r;
                Cb[((size_t)z * Mslice + row) * (size_t)N + col] = bfh(x);
            }
        }
        if (stats != nullptr) {
            s += __shfl_xor(s, 16, 64); s += __shfl_xor(s, 32, 64);
            q += __shfl_xor(q, 16, 64); q += __shfl_xor(q, 32, 64);
            if (lq == 0) {
                atomicAdd(&colsum[wn + (nt << 4) + lidx], s);
                atomicAdd(&colsq [wn + (nt << 4) + lidx], q);
            }
        }
    }
    if (stats != nullptr) {
        __syncthreads();
        if (tid < 256) {
            atomicAdd(&stats[n0 + tid],       colsum[tid]);
            atomicAdd(&stats[512 + n0 + tid], colsq[tid]);
        }
    }
}

// ===== bf16 MFMA GEMM, 64x64 tile, gload_lds + 2-phase (d0,d1,d2) ==========
__global__ __launch_bounds__(256)
void k_b64g(const unsigned short* __restrict__ Abase,
            const unsigned short* __restrict__ Bt,
            unsigned short* __restrict__ Cb,
            const float* __restrict__ bias,
            float* __restrict__ stats,
            int Mslice, int K, int N, int decK)
{
    __shared__ __align__(16) unsigned short As[2][64 * 64];
    __shared__ __align__(16) unsigned short Bs[2][64 * 64];
    __shared__ float colsum[64], colsq[64];

    const int tid  = threadIdx.x;
    const int lane = tid & 63;
    const int wave = tid >> 6;
    const int wm = (wave >> 1) << 5;
    const int wn = (wave & 1) << 5;
    const int z  = blockIdx.z;
    const int n0 = blockIdx.x << 6;
    const int m0 = blockIdx.y << 6;

    if (stats != nullptr && tid < 64) { colsum[tid] = 0.f; colsq[tid] = 0.f; }

    const int a_slice = z / decK, wk = z - a_slice * decK;
    const unsigned short* Ap = Abase + (size_t)a_slice * (size_t)Mslice * (size_t)K;
    const unsigned short* Bp = Bt + (size_t)wk * (size_t)N * (size_t)K;

    const int srow  = tid >> 3;                       // 0..31
    const int selem = ((tid & 7) ^ (srow & 7)) << 3;
    const unsigned short* Asrc = Ap + (size_t)(m0 + srow) * K + selem;
    const unsigned short* Bsrc = Bp + (size_t)(n0 + srow) * K + selem;

    f32x4 acc[2][2];
#pragma unroll
    for (int i = 0; i < 2; ++i)
#pragma unroll
        for (int j = 0; j < 2; ++j) acc[i][j] = (f32x4){0.f, 0.f, 0.f, 0.f};

    const int lidx = lane & 15;
    const int lq   = lane >> 4;

    // ---- prologue: stage chunk 0 into buffer 0 ----
#pragma unroll
    for (int c = 0; c < 2; ++c) {
        gload16(Asrc + (size_t)(c << 5) * K, &As[0][tid * 8 + (c << 11)]);
        gload16(Bsrc + (size_t)(c << 5) * K, &Bs[0][tid * 8 + (c << 11)]);
    }
    __syncthreads();

    const int nsteps = K >> 6;
    int cur = 0;
    for (int t = 0; t < nsteps; ++t) {
        if (t + 1 < nsteps) {
            const int k0n = (t + 1) << 6;
#pragma unroll
            for (int c = 0; c < 2; ++c) {
                gload16(Asrc + (size_t)(c << 5) * K + k0n,
                        &As[cur ^ 1][tid * 8 + (c << 11)]);
                gload16(Bsrc + (size_t)(c << 5) * K + k0n,
                        &Bs[cur ^ 1][tid * 8 + (c << 11)]);
            }
        }
#pragma unroll
        for (int ks = 0; ks < 2; ++ks) {
            const int ub = (ks << 2) + lq;
            const int uo = (ub ^ (lidx & 7)) << 3;
            bf16x8 af[2], bfv[2];
#pragma unroll
            for (int t2 = 0; t2 < 2; ++t2)
                af[t2] = *(const bf16x8*)&As[cur][((wm + (t2 << 4) + lidx) << 6) + uo];
#pragma unroll
            for (int t2 = 0; t2 < 2; ++t2)
                bfv[t2] = *(const bf16x8*)&Bs[cur][((wn + (t2 << 4) + lidx) << 6) + uo];
#pragma unroll
            for (int mt = 0; mt < 2; ++mt)
#pragma unroll
                for (int nt = 0; nt < 2; ++nt)
                    acc[mt][nt] = __builtin_amdgcn_mfma_f32_16x16x32_bf16(
                        af[mt], bfv[nt], acc[mt][nt], 0, 0, 0);
        }
        __syncthreads();
        cur ^= 1;
    }

    const int rbase = lq << 2;
#pragma unroll
    for (int nt = 0; nt < 2; ++nt) {
        const int col = n0 + wn + (nt << 4) + lidx;
        const float badd = (bias != nullptr) ? bias[col] : 0.f;
        float s = 0.f, q = 0.f;
#pragma unroll
        for (int mt = 0; mt < 2; ++mt) {
#pragma unroll
            for (int r = 0; r < 4; ++r) {
                float x = acc[mt][nt][r];
                s += x; q += x * x;
                const int row = m0 + wm + (mt << 4) + rbase + r;
                Cb[((size_t)z * Mslice + row) * (size_t)N + col] = bfh(x + badd);
            }
        }
        if (stats != nullptr) {
            s += __shfl_xor(s, 16, 64); s += __shfl_xor(s, 32, 64);
            q += __shfl_xor(q, 16, 64); q += __shfl_xor(q, 32, 64);
            if (lq == 0) {
                atomicAdd(&colsum[wn + (nt << 4) + lidx], s);
                atomicAdd(&colsq [wn + (nt << 4) + lidx], q);
            }
        }
    }
    if (stats != nullptr) {
        __syncthreads();
        if (tid < 64) {
            atomicAdd(&stats[n0 + tid],       colsum[tid]);
            atomicAdd(&stats[512 + n0 + tid], colsq[tid]);
        }
    }
}

// ===== split-bf16 MFMA GEMM, 64x64 tile, gload_lds + 2-phase (e1,e2,e3) ====
// Linear LDS [2][64][32] bf16 per buffer; XOR-swizzle unit^(row&3).
__global__ __launch_bounds__(256)
void k_sp64g(const unsigned short* __restrict__ Ahg,
             const unsigned short* __restrict__ Alg,
             const unsigned short* __restrict__ Whi,
             const unsigned short* __restrict__ Wlo,
             float* __restrict__ Cout, float* __restrict__ stats,
             int Mslice, int Kp, int N, int n_terms)
{
    __shared__ __align__(16) unsigned short Ah[2][64 * 32];
    __shared__ __align__(16) unsigned short Al[2][64 * 32];
    __shared__ __align__(16) unsigned short Bh[2][64 * 32];
    __shared__ __align__(16) unsigned short Bl[2][64 * 32];
    __shared__ float colsum[64], colsq[64];

    const int tid  = threadIdx.x;
    const int lane = tid & 63;
    const int wave = tid >> 6;
    const int wm = (wave >> 1) << 5;
    const int wn = (wave & 1) << 5;
    const int z  = blockIdx.z;
    const int n0 = blockIdx.x << 6;
    const int m0 = blockIdx.y << 6;

    if (stats != nullptr && tid < 64) { colsum[tid] = 0.f; colsq[tid] = 0.f; }

    const int srow  = tid >> 2;                       // 0..63
    const int selem = ((tid & 3) ^ (srow & 3)) << 3;  // swizzled elem in 32-row

    f32x4 acc[2][2];
#pragma unroll
    for (int i = 0; i < 2; ++i)
#pragma unroll
        for (int j = 0; j < 2; ++j) acc[i][j] = (f32x4){0.f, 0.f, 0.f, 0.f};

    const int lidx = lane & 15;
    const int lq   = lane >> 4;
    const int uo   = (lq ^ (lidx & 3)) << 3;          // swizzled read offset

    const int cpk = Kp >> 5;
    const int tot = n_terms * cpk;

    // ---- prologue: stage chunk 0 (term 0, k 0) into buffer 0 ----
    {
        const size_t ab = ((size_t)(z * n_terms) * Mslice + m0 + srow)
                          * (size_t)Kp + selem;
        const size_t bb = ((size_t)(n0 + srow)) * (size_t)Kp + selem;
        gload16(Ahg + ab, &Ah[0][tid * 8]);
        gload16(Alg + ab, &Al[0][tid * 8]);
        gload16(Whi + bb, &Bh[0][tid * 8]);
        gload16(Wlo + bb, &Bl[0][tid * 8]);
    }
    __syncthreads();

    int cur = 0;
    int lt = 0, lk = 32;
    if (lk >= Kp) { lk = 0; lt = 1; }
    for (int c = 0; c < tot; ++c) {
        if (c + 1 < tot) {
            const size_t ab = ((size_t)(z * n_terms + lt) * Mslice + m0 + srow)
                              * (size_t)Kp + lk + selem;
            const size_t bb = ((size_t)lt * N + n0 + srow) * (size_t)Kp + lk + selem;
            gload16(Ahg + ab, &Ah[cur ^ 1][tid * 8]);
            gload16(Alg + ab, &Al[cur ^ 1][tid * 8]);
            gload16(Whi + bb, &Bh[cur ^ 1][tid * 8]);
            gload16(Wlo + bb, &Bl[cur ^ 1][tid * 8]);
            lk += 32; if (lk >= Kp) { lk = 0; ++lt; }
        }
        bf16x8 ah[2], al[2], bh[2], bl[2];
#pragma unroll
        for (int t = 0; t < 2; ++t) {
            const int ra = ((wm + (t << 4) + lidx) << 5) + uo;
            ah[t] = *(const bf16x8*)&Ah[cur][ra];
            al[t] = *(const bf16x8*)&Al[cur][ra];
        }
#pragma unroll
        for (int t = 0; t < 2; ++t) {
            const int rb = ((wn + (t << 4) + lidx) << 5) + uo;
            bh[t] = *(const bf16x8*)&Bh[cur][rb];
            bl[t] = *(const bf16x8*)&Bl[cur][rb];
        }
#pragma unroll
        for (int mt = 0; mt < 2; ++mt)
#pragma unroll
            for (int nt = 0; nt < 2; ++nt) {
                acc[mt][nt] = __builtin_amdgcn_mfma_f32_16x16x32_bf16(
                    ah[mt], bh[nt], acc[mt][nt], 0, 0, 0);
                acc[mt][nt] = __builtin_amdgcn_mfma_f32_16x16x32_bf16(
                    al[mt], bh[nt], acc[mt][nt], 0, 0, 0);
                acc[mt][nt] = __builtin_amdgcn_mfma_f32_16x16x32_bf16(
                    ah[mt], bl[nt], acc[mt][nt], 0, 0, 0);
            }
        __syncthreads();
        cur ^= 1;
    }

    const int rbase = lq << 2;
#pragma unroll
    for (int nt = 0; nt < 2; ++nt) {
        const int col = n0 + wn + (nt << 4) + lidx;
        float s = 0.f, q = 0.f;
#pragma unroll
        for (int mt = 0; mt < 2; ++mt) {
#pragma unroll
            for (int r = 0; r < 4; ++r) {
                float x = acc[mt][nt][r];
                s += x; q += x * x;
                const int row = m0 + wm + (mt << 4) + rbase + r;
                Cout[((size_t)z * Mslice + row) * (size_t)N + col] = x;
            }
        }
        if (stats != nullptr) {
            s += __shfl_xor(s, 16, 64); s += __shfl_xor(s, 32, 64);
            q += __shfl_xor(q, 16, 64); q += __shfl_xor(q, 32, 64);
            if (lq == 0) {
                atomicAdd(&colsum[wn + (nt << 4) + lidx], s);
                atomicAdd(&colsq [wn + (nt << 4) + lidx], q);
            }
        }
    }
    if (stats != nullptr) {
        __syncthreads();
        if (tid < 64) {
            atomicAdd(&stats[n0 + tid],       colsum[tid]);
            atomicAdd(&stats[512 + n0 + tid], colsq[tid]);
        }
    }
}

// ================= merged prep kernel (9 independent preps) ================
__global__ void k_prep(float* __restrict__ zbase, unsigned long long* __restrict__ amin,
                       const float* __restrict__ codebook, float* __restrict__ codeT,
                       float* __restrict__ codesq,
                       const float* __restrict__ w_e2, unsigned short* __restrict__ whi_e2,
                       unsigned short* __restrict__ wlo_e2,
                       const float* __restrict__ w_e3, unsigned short* __restrict__ whi_e3,
                       unsigned short* __restrict__ wlo_e3,
                       const float* __restrict__ W_q,  unsigned short* __restrict__ wqb,
                       const float* __restrict__ w_d1, unsigned short* __restrict__ wd1b,
                       const float* __restrict__ w_d2, unsigned short* __restrict__ wd2b,
                       const float* __restrict__ w_d3, unsigned short* __restrict__ wd3b,
                       const float* __restrict__ W_out, unsigned short* __restrict__ woutb,
                       const float* __restrict__ in_seqs,
                       unsigned short* __restrict__ in_h, unsigned short* __restrict__ in_l)
{
    __shared__ float red[4];
    const int bid = blockIdx.x;
    const int tid = threadIdx.x;

    if (bid < 32) {                                    // s0: init
        int t = bid * 256 + tid;
        if (t < 6720) zbase[t] = 0.f;
        if (t < 1024) amin[t] = ~0ULL;
        return;
    }
    if (bid < 1056) {                                  // s1: codeT repack (Kc=1)
        int idx = (bid - 32) * 256 + tid;
        int i = (idx >> 9) & 511, o = idx & 511;
        codeT[idx] = codebook[(o << 9) + i];
        return;
    }
    if (bid < 1568) {                                  // s2: codesq
        int c = bid - 1056;
        float s = 0.f;
        for (int i = tid; i < 512; i += 256) { float v = codebook[c * 512 + i]; s += v * v; }
        for (int off = 32; off; off >>= 1) s += __shfl_down(s, off, 64);
        if ((tid & 63) == 0) red[tid >> 6] = s;
        __syncthreads();
        if (tid == 0) codesq[c] = red[0] + red[1] + red[2] + red[3];
        return;
    }
    if (bid < 4640) {                                  // s3: split e2 (Kc=3)
        int idx = (bid - 1568) * 256 + tid;
        int i = idx & 511, o = (idx >> 9) & 511, k = idx >> 18;
        float v = w_e2[(((o << 9) + i) * 3) + k];
        unsigned short h = bfh(v);
        whi_e2[idx] = h; wlo_e2[idx] = bfh(v - bf2f(h));
        return;
    }
    if (bid < 6688) {                                  // s4: split e3 (Kc=2)
        int idx = (bid - 4640) * 256 + tid;
        int i = idx & 511, o = (idx >> 9) & 511, k = idx >> 18;
        float v = w_e3[(((o << 9) + i) * 2) + k];
        unsigned short h = bfh(v);
        whi_e3[idx] = h; wlo_e3[idx] = bfh(v - bf2f(h));
        return;
    }
    if (bid < 7712) {                                  // s5: W_q bf (Kc=1,I=O=512)
        int idx = (bid - 6688) * 256 + tid;
        int i = idx & 511, o = (idx >> 9) & 511;
        wqb[idx] = bfh(W_q[((size_t)i << 9) + o]);
        return;
    }
    if (bid < 9760) {                                  // s6: w_d1 bf (Kc=2)
        int idx = (bid - 7712) * 256 + tid;
        int i = idx & 511, o = (idx >> 9) & 511, k = idx >> 18;
        wd1b[idx] = bfh(w_d1[(((size_t)i << 9) + o) * 2 + k]);
        return;
    }
    if (bid < 12832) {                                 // s7: w_d2 bf (Kc=3)
        int idx = (bid - 9760) * 256 + tid;
        int i = idx & 511, o = (idx >> 9) & 511, k = idx >> 18;
        wd2b[idx] = bfh(w_d2[(((size_t)i << 9) + o) * 3 + k]);
        return;
    }
    if (bid < 17952) {                                 // s8: w_d3 bf (Kc=5)
        int idx = (bid - 12832) * 256 + tid;
        int i = idx & 511, o = (idx >> 9) & 511, k = idx >> 18;
        wd3b[idx] = bfh(w_d3[(((size_t)i << 9) + o) * 5 + k]);
        return;
    }
    if (bid < 18222) {                                 // s9: W_out bf (Kc=1,I=512,O=135)
        int idx = (bid - 17952) * 256 + tid;
        if (idx >= 69120) return;
        int i = idx % 512, o = idx / 512;              // [o][i], o<135
        woutb[idx] = bfh(W_out[((size_t)i * 135) + o]);
        return;
    }
    {                                                  // s10: split_in
        int idx = (bid - 18222) * 256 + tid;
        if (idx >= 4915200) return;
        int i = idx % 160, r = idx / 160;
        float v = (i < 135) ? in_seqs[(size_t)r * 135 + i] : 0.f;
        unsigned short h = bfh(v);
        in_h[idx] = h; in_l[idx] = bfh(v - bf2f(h));
    }
}

// ============================ small kernels ================================
__global__ void k_repack(const float* __restrict__ w, float* __restrict__ wt,
                         int Kc, int total)
{
    int idx = blockIdx.x * 256 + threadIdx.x;
    if (idx >= total) return;
    int k = idx >> 18;
    int rem = idx & 262143;
    int i = rem >> 9, o = rem & 511;
    wt[idx] = w[(((o << 9) + i) * Kc + k)];
}

__global__ void k_repack_sp_weff(const float* __restrict__ weff,
                                 unsigned short* __restrict__ whi,
                                 unsigned short* __restrict__ wlo,
                                 int total)
{
    int idx = blockIdx.x * 256 + threadIdx.x;
    if (idx >= total) return;
    int i = idx % 160;
    int o = (idx / 160) & 511;
    int t = idx / 81920;
    float v = (i < 135) ? weff[((size_t)t * 135 + i) * 512 + o] : 0.f;
    unsigned short h = bfh(v);
    whi[idx] = h;
    wlo[idx] = bfh(v - bf2f(h));
}

__global__ void k_bnsplit(const float* __restrict__ x,
                          const float* __restrict__ sc, const float* __restrict__ sh,
                          unsigned short* __restrict__ hq, unsigned short* __restrict__ lq_,
                          int total4)
{
    int idx = blockIdx.x * 256 + threadIdx.x;
    if (idx >= total4) return;
    const int base = idx << 2;
    float4 f = *(const float4*)(x + base);
    const int k = base & 511;
    float4 s = *(const float4*)(sc + k);
    float4 c = *(const float4*)(sh + k);
    float y0 = fmaxf(fmaf(f.x, s.x, c.x), 0.f);
    float y1 = fmaxf(fmaf(f.y, s.y, c.y), 0.f);
    float y2 = fmaxf(fmaf(f.z, s.z, c.z), 0.f);
    float y3 = fmaxf(fmaf(f.w, s.w, c.w), 0.f);
    unsigned short h0 = bfh(y0), h1 = bfh(y1), h2 = bfh(y2), h3 = bfh(y3);
    unsigned short l0 = bfh(y0 - bf2f(h0)), l1 = bfh(y1 - bf2f(h1));
    unsigned short l2 = bfh(y2 - bf2f(h2)), l3 = bfh(y3 - bf2f(h3));
    *(uint2*)&hq[base]  = make_uint2((unsigned)h0 | ((unsigned)h1 << 16),
                                     (unsigned)h2 | ((unsigned)h3 << 16));
    *(uint2*)&lq_[base] = make_uint2((unsigned)l0 | ((unsigned)l1 << 16),
                                     (unsigned)l2 | ((unsigned)l3 << 16));
}

__global__ void k_bnapply(const unsigned short* __restrict__ x,
                          const float* __restrict__ sc, const float* __restrict__ sh,
                          unsigned short* __restrict__ y, int total8)
{
    int idx = blockIdx.x * 256 + threadIdx.x;
    if (idx >= total8) return;
    const int base = idx << 3;
    uint4 raw = *(const uint4*)(x + base);
    const int k = base & 511;
    float4 s0 = *(const float4*)(sc + k);
    float4 c0 = *(const float4*)(sh + k);
    float4 s1 = *(const float4*)(sc + k + 4);
    float4 c1 = *(const float4*)(sh + k + 4);
    unsigned* u = (unsigned*)&raw;
    float x0 = __uint_as_float(u[0] << 16),        x1 = __uint_as_float(u[0] & 0xffff0000u);
    float x2 = __uint_as_float(u[1] << 16),        x3 = __uint_as_float(u[1] & 0xffff0000u);
    float x4 = __uint_as_float(u[2] << 16),        x5 = __uint_as_float(u[2] & 0xffff0000u);
    float x6 = __uint_as_float(u[3] << 16),        x7 = __uint_as_float(u[3] & 0xffff0000u);
    x0 = fmaxf(fmaf(x0, s0.x, c0.x), 0.f); x1 = fmaxf(fmaf(x1, s0.y, c0.y), 0.f);
    x2 = fmaxf(fmaf(x2, s0.z, c0.z), 0.f); x3 = fmaxf(fmaf(x3, s0.w, c0.w), 0.f);
    x4 = fmaxf(fmaf(x4, s1.x, c1.x), 0.f); x5 = fmaxf(fmaf(x5, s1.y, c1.y), 0.f);
    x6 = fmaxf(fmaf(x6, s1.z, c1.z), 0.f); x7 = fmaxf(fmaf(x7, s1.w, c1.w), 0.f);
    *(uint4*)&y[base] = make_uint4(pk_bf16(x0, x1), pk_bf16(x2, x3),
                                   pk_bf16(x4, x5), pk_bf16(x6, x7));
}

__global__ void k_bn_fin(const float* __restrict__ stats,
                         const float* __restrict__ g, const float* __restrict__ b,
                         float* __restrict__ sc, float* __restrict__ sh, float inv_n)
{
    int c = blockIdx.x * blockDim.x + threadIdx.x;
    if (c >= 512) return;
    float m = stats[c] * inv_n;
    float v = stats[512 + c] * inv_n - m * m;
    float a = (float)((double)g[c] / sqrt((double)v + 1e-5));
    sc[c] = a;
    sh[c] = b[c] - m * a;
}

__global__ void k_vq_gather(const unsigned long long* __restrict__ amin,
                            const float* __restrict__ codebook,
                            const float* __restrict__ e3pre,
                            const float* __restrict__ sc, const float* __restrict__ sh,
                            unsigned short* __restrict__ quant_bf,
                            float* __restrict__ loss,
                            unsigned int* __restrict__ hist)
{
    int b = blockIdx.x; int t = threadIdx.x;   // 256 threads
    unsigned int idx = (unsigned int)(amin[b] & 0xFFFFFFFFull) & 511u;
    float part = 0.f;
    for (int i = t; i < 512; i += 256) {
        float q = codebook[(size_t)idx * 512 + i];
        quant_bf[(size_t)b * 512 + i] = bfh(q);
        float x = e3pre[(size_t)b * 512 + i];
        float f = fmaxf(fmaf(x, sc[i], sh[i]), 0.f);
        float d = q - f;
        part += d * d;
    }
    for (int off = 32; off; off >>= 1) part += __shfl_down(part, off, 64);
    __shared__ float red[4];
    if ((t & 63) == 0) red[t >> 6] = part;
    __syncthreads();
    if (t == 0) {
        atomicAdd(loss, red[0] + red[1] + red[2] + red[3]);
        atomicAdd(&hist[idx], 1u);
    }
}

__global__ void k_scalars(const unsigned int* __restrict__ hist,
                          const float* __restrict__ loss, float* __restrict__ out)
{
    int t = threadIdx.x;   // 512
    float p = (float)hist[t] * (1.0f / 1024.0f);
    float e = p * logf(p + 1e-10f);
    for (int off = 32; off; off >>= 1) e += __shfl_down(e, off, 64);
    __shared__ float red[8];
    if ((t & 63) == 0) red[t >> 6] = e;
    __syncthreads();
    if (t == 0) {
        float s = 0.f;
        for (int i = 0; i < 8; ++i) s += red[i];
        out[4147200] = 1.25f * loss[0] * (1.0f / 524288.0f);
        out[4147201] = expf(-s);
    }
}

extern "C" void kernel_launch(void* const* d_in, const int* in_sizes, int n_in,
                              void* d_out, int out_size, void* d_ws, size_t ws_size,
                              hipStream_t stream)
{
    const float* in_seqs = (const float*)d_in[0];
    const float* W_in  = (const float*)d_in[1];
    const float* w_e1  = (const float*)d_in[3];
    const float* g_e1  = (const float*)d_in[4];
    const float* be1   = (const float*)d_in[5];
    const float* w_e2  = (const float*)d_in[6];
    const float* g_e2  = (const float*)d_in[7];
    const float* be2   = (const float*)d_in[8];
    const float* w_e3  = (const float*)d_in[9];
    const float* g_e3  = (const float*)d_in[10];
    const float* be3   = (const float*)d_in[11];
    const float* codebook = (const float*)d_in[12];
    const float* W_q   = (const float*)d_in[13];
    const float* b_q   = (const float*)d_in[14];
    const float* w_d1  = (const float*)d_in[15];
    const float* g_d1  = (const float*)d_in[16];
    const float* bd1   = (const float*)d_in[17];
    const float* w_d2  = (const float*)d_in[18];
    const float* g_d2  = (const float*)d_in[19];
    const float* bd2   = (const float*)d_in[20];
    const float* w_d3  = (const float*)d_in[21];
    const float* g_d3  = (const float*)d_in[22];
    const float* bd3   = (const float*)d_in[23];
    const float* W_out = (const float*)d_in[24];
    const float* b_out = (const float*)d_in[25];
    float* out = (float*)d_out;

    // ---- workspace layout (float offsets) ----
    float* W = (float*)d_ws;
    unsigned long long* amin = (unsigned long long*)W;            // 2048 f
    float* stats  = W + 2048;                                     // 6144
    float* lossp  = W + 8192;                                     // 64
    unsigned int* hist = (unsigned int*)(W + 8256);               // 512
    float* scsh   = W + 8768;                                     // 6144
    float* codesq = W + 14912;                                    // 512
    float* wt_e1  = W + 15424;                                    // 1310720 f
    float* weff   = W + 1326144;                                  // 345600 f
    float* codeT  = W + 1671744;                                  // 262144 f
    unsigned short* esw = (unsigned short*)(W + 1933888);         // 3440640 ush
    unsigned short* whi_e1 = esw;
    unsigned short* wlo_e1 = esw + 409600;
    unsigned short* whi_e2 = esw + 819200;
    unsigned short* wlo_e2 = esw + 1605632;
    unsigned short* whi_e3 = esw + 2392064;
    unsigned short* wlo_e3 = esw + 2916352;
    unsigned short* in_h  = (unsigned short*)(W + 3654208);       // 4915200 ush
    unsigned short* in_l  = in_h + 4915200;
    unsigned short* d3pre = (unsigned short*)(W + 3654208);       // 15728640 ush
    float* e1f = W + 11518528;                                    // 3145728 f
    unsigned short* e1h = (unsigned short*)(W + 14664256);        // 3145728 ush
    unsigned short* e1l = e1h + 3145728;
    float* e2f = W + 17809984;                                    // 1048576 f
    unsigned short* e2h = (unsigned short*)(W + 18858560);        // 1048576 ush
    unsigned short* e2l = e2h + 1048576;
    unsigned short* d2pre = (unsigned short*)(W + 17809984);      // 3145728 ush
    unsigned short* d2bf  = d2pre + 3145728;                      // 3145728 ush
    float* e3f = W + 20955712;                                    // 524288 f
    unsigned short* quant_bf = (unsigned short*)(W + 21480000);   // 524288 ush
    unsigned short* d0bf     = (unsigned short*)(W + 21742144);   // 524288 ush
    unsigned short* d1pre    = (unsigned short*)(W + 22004288);   // 1048576 ush
    unsigned short* d1bf     = (unsigned short*)(W + 22528640);   // 1048576 ush
    unsigned short* d3bf     = (unsigned short*)(W + 23052928);   // 15728640 ush
    // d3bf ends at f-offset 30917248 (~124 MB) < 256 MiB ws.

    unsigned short* db    = (unsigned short*)wt_e1;
    unsigned short* wqb   = db;
    unsigned short* wd1b  = db + 262144;
    unsigned short* wd2b  = db + 786432;
    unsigned short* wd3b  = db + 1572864;
    unsigned short* woutb = db + 2883584;

    float* st_e1 = stats + 0 * 1024; float* sc_e1 = scsh + 0 * 1024; float* sh_e1 = sc_e1 + 512;
    float* st_e2 = stats + 1 * 1024; float* sc_e2 = scsh + 1 * 1024; float* sh_e2 = sc_e2 + 512;
    float* st_e3 = stats + 2 * 1024; float* sc_e3 = scsh + 2 * 1024; float* sh_e3 = sc_e3 + 512;
    float* st_d1 = stats + 3 * 1024; float* sc_d1 = scsh + 3 * 1024; float* sh_d1 = sc_d1 + 512;
    float* st_d2 = stats + 4 * 1024; float* sc_d2 = scsh + 4 * 1024; float* sh_d2 = sc_d2 + 512;
    float* st_d3 = stats + 5 * 1024; float* sc_d3 = scsh + 5 * 1024; float* sh_d3 = sc_d3 + 512;

    dim3 blk(256);

    // order: wt_e1 fp32 repack -> weff gemm -> sp_weff, THEN k_prep (which
    // fills decoder bf16 weights over the then-dead wt_e1 region).
    k_repack<<<dim3(5 * 1024), blk, 0, stream>>>(w_e1, wt_e1, 5, 5 * 262144);
    k_gemm<<<dim3(16, 5, 5), blk, 0, stream>>>(W_in, wt_e1, weff,
        nullptr, nullptr, nullptr, nullptr, 135, 512, 512, 5);
    k_repack_sp_weff<<<dim3(1600), blk, 0, stream>>>(weff, whi_e1, wlo_e1, 409600);

    k_prep<<<dim3(37422), blk, 0, stream>>>(stats, amin,
        codebook, codeT, codesq,
        w_e2, whi_e2, wlo_e2, w_e3, whi_e3, wlo_e3,
        W_q, wqb, w_d1, wd1b, w_d2, wd2b, w_d3, wd3b, W_out, woutb,
        in_seqs, in_h, in_l);

    // ---- encoder: 64x64-tile split-bf16 MFMA (gload_lds, 2-phase) ----
    k_sp64g<<<dim3(8, 16, 6), blk, 0, stream>>>(in_h, in_l, whi_e1, wlo_e1,
        e1f, st_e1, 1024, 160, 512, 5);
    k_bn_fin<<<dim3(2), blk, 0, stream>>>(st_e1, g_e1, be1, sc_e1, sh_e1, 1.f / 6144.f);
    k_bnsplit<<<dim3(3072), blk, 0, stream>>>(e1f, sc_e1, sh_e1, e1h, e1l, 786432);

    k_sp64g<<<dim3(8, 16, 2), blk, 0, stream>>>(e1h, e1l, whi_e2, wlo_e2,
        e2f, st_e2, 1024, 512, 512, 3);
    k_bn_fin<<<dim3(2), blk, 0, stream>>>(st_e2, g_e2, be2, sc_e2, sh_e2, 1.f / 2048.f);
    k_bnsplit<<<dim3(1024), blk, 0, stream>>>(e2f, sc_e2, sh_e2, e2h, e2l, 262144);

    k_sp64g<<<dim3(8, 16, 1), blk, 0, stream>>>(e2h, e2l, whi_e3, wlo_e3,
        e3f, st_e3, 1024, 512, 512, 2);
    k_bn_fin<<<dim3(2), blk, 0, stream>>>(st_e3, g_e3, be3, sc_e3, sh_e3, 1.f / 1024.f);

    // ---- VQ: fp32 dist GEMM + argmin (32x32 tiles, 512 blocks) ----
    k_gemm<<<dim3(16, 32, 1), blk, 0, stream>>>(e3f, codeT, nullptr,
        sc_e3, sh_e3, amin, codesq, 1024, 512, 512, 1);
    k_vq_gather<<<dim3(1024), blk, 0, stream>>>(amin, codebook, e3f, sc_e3, sh_e3,
                                                quant_bf, lossp, hist);

    // ---- decoder: all gload_lds 2-phase; BN as separate passes ----
    k_b64g<<<dim3(8, 16, 1), blk, 0, stream>>>(quant_bf, wqb, d0bf,
        b_q, nullptr, 1024, 512, 512, 1);

    k_b64g<<<dim3(8, 16, 2), blk, 0, stream>>>(d0bf, wd1b, d1pre,
        nullptr, st_d1, 1024, 512, 512, 2);
    k_bn_fin<<<dim3(2), blk, 0, stream>>>(st_d1, g_d1, bd1, sc_d1, sh_d1, 1.f / 2048.f);
    k_bnapply<<<dim3(512), blk, 0, stream>>>(d1pre, sc_d1, sh_d1, d1bf, 131072);

    // d2: 64x64 gload_lds 2-phase (768 blocks — occupancy > tile size here)
    k_b64g<<<dim3(8, 16, 6), blk, 0, stream>>>(d1bf, wd2b, d2pre,
        nullptr, st_d2, 1024, 512, 512, 3);
    k_bn_fin<<<dim3(2), blk, 0, stream>>>(st_d2, g_d2, bd2, sc_d2, sh_d2, 1.f / 6144.f);
    k_bnapply<<<dim3(1536), blk, 0, stream>>>(d2pre, sc_d2, sh_d2, d2bf, 393216);

    // d3: 256x256 tiles, gload_lds 2-phase, 512 threads (240 blocks)
    k_m256<<<dim3(2, 4, 30), dim3(512), 0, stream>>>(d2bf, wd3b, d3pre,
        st_d3, 1024, 512, 512, 5);
    k_bn_fin<<<dim3(2), blk, 0, stream>>>(st_d3, g_d3, bd3, sc_d3, sh_d3, 1.f / 30720.f);
    k_bnapply<<<dim3(7680), blk, 0, stream>>>(d3pre, sc_d3, sh_d3, d3bf, 1966080);

    // out-proj: 128x128 gload_lds 2-phase, operm store, N=135 (B rows clamped)
    k_mfma_g<<<dim3(2, 240, 1), blk, 0, stream>>>(d3bf, woutb, nullptr,
        out, b_out, nullptr, 30720, 512, 135, 1);

    k_scalars<<<dim3(1), dim3(512), 0, stream>>>(hist, lossp, out);
}

// Round 13
// 409.153 us; speedup vs baseline: 1.0827x; 1.0063x over previous
//
#include <hip/hip_runtime.h>
#include <math.h>

// ---------------------------------------------------------------------------
// VQ-VAE forward (round 24 = round 23 with the weff-aliasing race fixed).
//  - POST-MORTEM round 23: folding sp_weff into k_prep raced: wd3b/woutb
//    (k_prep s8/s9) overlay the tail of the old weff region (wd3b floats
//    786432..1441792 rel wt_e1 vs weff at 1310720 rel) and block order
//    within one kernel is undefined -> s11's weff reads saw clobbered data.
//  - FIX: weff relocated to W+30917248 (after d3bf; no aliasing). Fusions
//    kept: bn_fin folded into bnsplit/bnapply (-5 dispatches), sp_weff as
//    k_prep s11 (-1 dispatch). GEMMs byte-identical to the 411.7us config.
// ---------------------------------------------------------------------------

typedef __attribute__((ext_vector_type(8))) short bf16x8;
typedef __attribute__((ext_vector_type(4))) float f32x4;

__device__ __forceinline__ unsigned pk_bf16(float a, float b) {
    unsigned ua = __float_as_uint(a), ub = __float_as_uint(b);
    ua += 0x7fffu + ((ua >> 16) & 1u);          // RNE
    ub += 0x7fffu + ((ub >> 16) & 1u);
    return (ua >> 16) | (ub & 0xffff0000u);
}
__device__ __forceinline__ unsigned short bfh(float x) {
    unsigned u = __float_as_uint(x);
    u += 0x7fffu + ((u >> 16) & 1u);
    return (unsigned short)(u >> 16);
}
__device__ __forceinline__ float bf2f(unsigned short h) {
    return __uint_as_float(((unsigned)h) << 16);
}

// async global->LDS DMA, 16 B per lane (global_load_lds_dwordx4)
__device__ __forceinline__ void gload16(const unsigned short* g, unsigned short* l) {
    __builtin_amdgcn_global_load_lds(
        (const __attribute__((address_space(1))) unsigned int*)g,
        (__attribute__((address_space(3))) unsigned int*)l, 16, 0, 0);
}

__device__ __forceinline__ void bn4(float4& a, const float* __restrict__ s,
                                    const float* __restrict__ c) {
    float4 sv = *(const float4*)s;
    float4 cv = *(const float4*)c;
    a.x = fmaxf(fmaf(a.x, sv.x, cv.x), 0.f);
    a.y = fmaxf(fmaf(a.y, sv.y, cv.y), 0.f);
    a.z = fmaxf(fmaf(a.z, sv.z, cv.z), 0.f);
    a.w = fmaxf(fmaf(a.w, sv.w, cv.w), 0.f);
}

// shared helper: compute sc/sh for 512 channels into LDS (identical math to
// k_bn_fin; deterministic -> bit-identical wherever applied)
__device__ __forceinline__ void bn_fin_lds(const float* __restrict__ stats,
                                           const float* __restrict__ g,
                                           const float* __restrict__ b,
                                           float inv_n,
                                           float* scs, float* shs, int tid) {
    for (int c = tid; c < 512; c += 256) {
        float m = stats[c] * inv_n;
        float v = stats[512 + c] * inv_n - m * m;
        float a = (float)((double)g[c] / sqrt((double)v + 1e-5));
        scs[c] = a;
        shs[c] = b[c] - m * a;
    }
}

// ======================= fp32 GEMM (weff + VQ dist) ========================
#define FBK  32
#define FSTR 36

__global__ __launch_bounds__(256)
void k_gemm(const float* __restrict__ Abase,
            const float* __restrict__ Wt,
            float* __restrict__ Cout,
            const float* __restrict__ bnS, const float* __restrict__ bnB,
            unsigned long long* __restrict__ amin,
            const float* __restrict__ codesq,
            int Mslice, int K, int N, int decK)
{
    __shared__ __align__(16) float As[FBK][FSTR];
    __shared__ __align__(16) float Bs[FBK][FSTR];

    const int tid = threadIdx.x;
    const int z  = blockIdx.z;
    const int n0 = blockIdx.x << 5;
    const int m0 = blockIdx.y << 5;
    const int ty = tid >> 4;          // 0..15  (m pairs)
    const int tx = tid & 15;          // 0..15  (n pairs)

    const int a_slice = z / decK, wk = z - a_slice * decK;
    const float* Ap = Abase + (size_t)a_slice * (size_t)Mslice * (size_t)K;
    const float* Wp = Wt    + (size_t)wk * (size_t)K * (size_t)N;

    const int sr  = tid >> 3;         // 0..31
    const int sc4 = (tid & 7) << 2;   // 0..28

    int mrow = m0 + sr;
    if (mrow > Mslice - 1) mrow = Mslice - 1;
    const float* Arow_p = Ap + (size_t)mrow * K;

    float acc[2][2];
    acc[0][0] = 0.f; acc[0][1] = 0.f; acc[1][0] = 0.f; acc[1][1] = 0.f;

    // ---- prefetch chunk 0 ----
    float4 pa = *(const float4*)(Arow_p + sc4);
    if (bnS != nullptr) bn4(pa, bnS + sc4, bnB + sc4);
    float4 pb = *(const float4*)(Wp + (size_t)sr * N + n0 + sc4);

    for (int k0 = 0; k0 < K; k0 += FBK) {
        __syncthreads();
        As[sc4 + 0][sr] = pa.x;
        As[sc4 + 1][sr] = pa.y;
        As[sc4 + 2][sr] = pa.z;
        As[sc4 + 3][sr] = pa.w;
        *(float4*)&Bs[sr][sc4] = pb;
        const int k0n = k0 + FBK;
        if (k0n < K) {
            pa = *(const float4*)(Arow_p + k0n + sc4);
            if (bnS != nullptr) bn4(pa, bnS + k0n + sc4, bnB + k0n + sc4);
            pb = *(const float4*)(Wp + (size_t)(k0n + sr) * N + n0 + sc4);
        }
        __syncthreads();
#pragma unroll
        for (int kk = 0; kk < FBK; ++kk) {
            float2 av = *(const float2*)&As[kk][ty << 1];
            float2 bv = *(const float2*)&Bs[kk][tx << 1];
            acc[0][0] = fmaf(av.x, bv.x, acc[0][0]);
            acc[0][1] = fmaf(av.x, bv.y, acc[0][1]);
            acc[1][0] = fmaf(av.y, bv.x, acc[1][0]);
            acc[1][1] = fmaf(av.y, bv.y, acc[1][1]);
        }
    }

    if (amin != nullptr) {
        float2 cq = *(const float2*)(codesq + n0 + (tx << 1));
#pragma unroll
        for (int i = 0; i < 2; ++i) {
            const int m = m0 + (ty << 1) + i;
            float d0 = cq.x - 2.f * acc[i][0];
            float d1 = cq.y - 2.f * acc[i][1];
            int bj = (d1 < d0) ? 1 : 0;
            float best = (d1 < d0) ? d1 : d0;
            unsigned u = __float_as_uint(best);
            u = (u & 0x80000000u) ? ~u : (u | 0x80000000u);
            unsigned long long key =
                ((unsigned long long)u << 32) | (unsigned)(n0 + (tx << 1) + bj);
#pragma unroll
            for (int off = 1; off < 16; off <<= 1) {
                unsigned long long o = __shfl_xor(key, off, 64);
                if (o < key) key = o;
            }
            if (tx == 0 && m < Mslice) atomicMin(&amin[m], key);
        }
        return;
    }

#pragma unroll
    for (int i = 0; i < 2; ++i) {
        const int m = m0 + (ty << 1) + i;
        if (m < Mslice) {
            float2 v = make_float2(acc[i][0], acc[i][1]);
            *(float2*)&Cout[((size_t)z * Mslice + m) * N + n0 + (tx << 1)] = v;
        }
    }
}

// ===== bf16 MFMA GEMM, 128x128 tile, gload_lds + 2-phase pipeline ==========
// (out-proj). Linear LDS [2][128][64] bf16; XOR-swizzle: 16B unit u at row r
// holds global unit u^(r&7). B rows clamped to N-1 for padded cols.
__global__ __launch_bounds__(256)
void k_mfma_g(const unsigned short* __restrict__ Abase,
              const unsigned short* __restrict__ Bt,
              unsigned short* __restrict__ Cb,
              float* __restrict__ operm,
              const float* __restrict__ bias,
              float* __restrict__ stats,
              int Mslice, int K, int N, int decK)
{
    __shared__ __align__(16) unsigned short As[2][128 * 64];
    __shared__ __align__(16) unsigned short Bs[2][128 * 64];
    __shared__ float colsum[128], colsq[128];

    const int tid  = threadIdx.x;
    const int lane = tid & 63;
    const int wave = tid >> 6;
    const int wm = (wave >> 1) << 6;
    const int wn = (wave & 1) << 6;
    const int z  = blockIdx.z;
    const int n0 = blockIdx.x << 7;
    const int m0 = blockIdx.y << 7;

    if (stats != nullptr && tid < 128) { colsum[tid] = 0.f; colsq[tid] = 0.f; }

    const int a_slice = z / decK, wk = z - a_slice * decK;
    const unsigned short* Ap = Abase + (size_t)a_slice * (size_t)Mslice * (size_t)K;
    const unsigned short* Bp = Bt + (size_t)wk * (size_t)N * (size_t)K;

    const int srow  = tid >> 3;                       // 0..31 (row within chunk)
    const int selem = ((tid & 7) ^ (srow & 7)) << 3;  // swizzled elem offset
    const unsigned short* Asrc = Ap + (size_t)(m0 + srow) * K + selem;

    size_t boff[4];
#pragma unroll
    for (int c = 0; c < 4; ++c) {
        int brow = n0 + srow + (c << 5);
        if (brow > N - 1) brow = N - 1;
        boff[c] = (size_t)brow * K + selem;
    }

    f32x4 acc[4][4];
#pragma unroll
    for (int i = 0; i < 4; ++i)
#pragma unroll
        for (int j = 0; j < 4; ++j) acc[i][j] = (f32x4){0.f, 0.f, 0.f, 0.f};

    const int lidx = lane & 15;
    const int lq   = lane >> 4;

    // ---- prologue: stage chunk 0 into buffer 0 ----
#pragma unroll
    for (int c = 0; c < 4; ++c) {
        gload16(Asrc + (size_t)(c << 5) * K, &As[0][tid * 8 + (c << 11)]);
        gload16(Bp + boff[c],                &Bs[0][tid * 8 + (c << 11)]);
    }
    __syncthreads();   // vmcnt(0) drain: chunk 0 visible

    const int nsteps = K >> 6;
    int cur = 0;
    for (int t = 0; t < nsteps; ++t) {
        if (t + 1 < nsteps) {
            const int k0n = (t + 1) << 6;
#pragma unroll
            for (int c = 0; c < 4; ++c) {
                gload16(Asrc + (size_t)(c << 5) * K + k0n,
                        &As[cur ^ 1][tid * 8 + (c << 11)]);
                gload16(Bp + boff[c] + k0n,
                        &Bs[cur ^ 1][tid * 8 + (c << 11)]);
            }
        }
#pragma unroll
        for (int ks = 0; ks < 2; ++ks) {
            const int ub = (ks << 2) + lq;                        // 16B unit idx
            const int uo = (ub ^ (lidx & 7)) << 3;                // swizzled elems
            bf16x8 af[4], bfv[4];
#pragma unroll
            for (int t4 = 0; t4 < 4; ++t4)
                af[t4] = *(const bf16x8*)&As[cur][((wm + (t4 << 4) + lidx) << 6) + uo];
#pragma unroll
            for (int t4 = 0; t4 < 4; ++t4)
                bfv[t4] = *(const bf16x8*)&Bs[cur][((wn + (t4 << 4) + lidx) << 6) + uo];
#pragma unroll
            for (int mt = 0; mt < 4; ++mt)
#pragma unroll
                for (int nt = 0; nt < 4; ++nt)
                    acc[mt][nt] = __builtin_amdgcn_mfma_f32_16x16x32_bf16(
                        af[mt], bfv[nt], acc[mt][nt], 0, 0, 0);
        }
        __syncthreads();   // prefetch landed + all waves done reading buf cur
        cur ^= 1;
    }

    const int rbase = lq << 2;
#pragma unroll
    for (int nt = 0; nt < 4; ++nt) {
        const int col = n0 + wn + (nt << 4) + lidx;
        const float badd = (bias != nullptr && col < N) ? bias[col] : 0.f;
        float s = 0.f, q = 0.f;
#pragma unroll
        for (int mt = 0; mt < 4; ++mt) {
#pragma unroll
            for (int r = 0; r < 4; ++r) {
                float x = acc[mt][nt][r];
                s += x; q += x * x;
                const int row = m0 + wm + (mt << 4) + rbase + r;
                if (operm != nullptr) {
                    if (col < N) {
                        const int t = row >> 10, b = row & 1023;
                        operm[(size_t)b * 4050 + t * 135 + col] = x + badd;
                    }
                } else {
                    Cb[((size_t)z * Mslice + row) * (size_t)N + col] = bfh(x + badd);
                }
            }
        }
        if (stats != nullptr) {
            s += __shfl_xor(s, 16, 64); s += __shfl_xor(s, 32, 64);
            q += __shfl_xor(q, 16, 64); q += __shfl_xor(q, 32, 64);
            if (lq == 0) {
                atomicAdd(&colsum[wn + (nt << 4) + lidx], s);
                atomicAdd(&colsq [wn + (nt << 4) + lidx], q);
            }
        }
    }
    if (stats != nullptr) {
        __syncthreads();
        if (tid < 128) {
            atomicAdd(&stats[n0 + tid],       colsum[tid]);
            atomicAdd(&stats[512 + n0 + tid], colsq[tid]);
        }
    }
}

// ===== bf16 MFMA GEMM, 256x256 tile, gload_lds + 2-phase (d3) ==============
__global__ __launch_bounds__(512)
void k_m256(const unsigned short* __restrict__ Abase,
            const unsigned short* __restrict__ Bt,
            unsigned short* __restrict__ Cb,
            float* __restrict__ stats,
            int Mslice, int K, int N, int decK)
{
    __shared__ __align__(16) unsigned short As[2][256 * 64];
    __shared__ __align__(16) unsigned short Bs[2][256 * 64];
    __shared__ float colsum[256], colsq[256];

    const int tid  = threadIdx.x;
    const int lane = tid & 63;
    const int wave = tid >> 6;          // 0..7
    const int wm = (wave >> 2) << 7;    // 0,128
    const int wn = (wave & 3) << 6;     // 0,64,128,192
    const int z  = blockIdx.z;
    const int n0 = blockIdx.x << 8;
    const int m0 = blockIdx.y << 8;

    if (stats != nullptr && tid < 256) { colsum[tid] = 0.f; colsq[tid] = 0.f; }

    const int a_slice = z / decK, wk = z - a_slice * decK;
    const unsigned short* Ap = Abase + (size_t)a_slice * (size_t)Mslice * (size_t)K;
    const unsigned short* Bp = Bt + (size_t)wk * (size_t)N * (size_t)K;

    const int srow  = tid >> 3;                       // 0..63 (row within chunk)
    const int selem = ((tid & 7) ^ (srow & 7)) << 3;  // swizzled elem offset
    const unsigned short* Asrc = Ap + (size_t)(m0 + srow) * K + selem;

    size_t boff[4];
#pragma unroll
    for (int c = 0; c < 4; ++c) {
        int brow = n0 + srow + (c << 6);
        if (brow > N - 1) brow = N - 1;
        boff[c] = (size_t)brow * K + selem;
    }

    f32x4 acc[8][4];
#pragma unroll
    for (int i = 0; i < 8; ++i)
#pragma unroll
        for (int j = 0; j < 4; ++j) acc[i][j] = (f32x4){0.f, 0.f, 0.f, 0.f};

    const int lidx = lane & 15;
    const int lq   = lane >> 4;

    // ---- prologue: stage chunk 0 into buffer 0 ----
#pragma unroll
    for (int c = 0; c < 4; ++c) {
        gload16(Asrc + (size_t)(c << 6) * K, &As[0][tid * 8 + (c << 12)]);
        gload16(Bp + boff[c],                &Bs[0][tid * 8 + (c << 12)]);
    }
    __syncthreads();

    const int nsteps = K >> 6;
    int cur = 0;
    for (int t = 0; t < nsteps; ++t) {
        if (t + 1 < nsteps) {
            const int k0n = (t + 1) << 6;
#pragma unroll
            for (int c = 0; c < 4; ++c) {
                gload16(Asrc + (size_t)(c << 6) * K + k0n,
                        &As[cur ^ 1][tid * 8 + (c << 12)]);
                gload16(Bp + boff[c] + k0n,
                        &Bs[cur ^ 1][tid * 8 + (c << 12)]);
            }
        }
#pragma unroll
        for (int ks = 0; ks < 2; ++ks) {
            const int ub = (ks << 2) + lq;                        // 16B unit idx
            const int uo = (ub ^ (lidx & 7)) << 3;                // swizzled elems
            bf16x8 af[8], bfv[4];
#pragma unroll
            for (int i = 0; i < 8; ++i)
                af[i] = *(const bf16x8*)&As[cur][((wm + (i << 4) + lidx) << 6) + uo];
#pragma unroll
            for (int j = 0; j < 4; ++j)
                bfv[j] = *(const bf16x8*)&Bs[cur][((wn + (j << 4) + lidx) << 6) + uo];
#pragma unroll
            for (int mt = 0; mt < 8; ++mt)
#pragma unroll
                for (int nt = 0; nt < 4; ++nt)
                    acc[mt][nt] = __builtin_amdgcn_mfma_f32_16x16x32_bf16(
                        af[mt], bfv[nt], acc[mt][nt], 0, 0, 0);
        }
        __syncthreads();
        cur ^= 1;
    }

    const int rbase = lq << 2;
#pragma unroll
    for (int nt = 0; nt < 4; ++nt) {
        const int col = n0 + wn + (nt << 4) + lidx;
        float s = 0.f, q = 0.f;
#pragma unroll
        for (int mt = 0; mt < 8; ++mt) {
#pragma unroll
            for (int r = 0; r < 4; ++r) {
                float x = acc[mt][nt][r];
                s += x; q += x * x;
                const int row = m0 + wm + (mt << 4) + rbase + r;
                Cb[((size_t)z * Mslice + row) * (size_t)N + col] = bfh(x);
            }
        }
        if (stats != nullptr) {
            s += __shfl_xor(s, 16, 64); s += __shfl_xor(s, 32, 64);
            q += __shfl_xor(q, 16, 64); q += __shfl_xor(q, 32, 64);
            if (lq == 0) {
                atomicAdd(&colsum[wn + (nt << 4) + lidx], s);
                atomicAdd(&colsq [wn + (nt << 4) + lidx], q);
            }
        }
    }
    if (stats != nullptr) {
        __syncthreads();
        if (tid < 256) {
            atomicAdd(&stats[n0 + tid],       colsum[tid]);
            atomicAdd(&stats[512 + n0 + tid], colsq[tid]);
        }
    }
}

// ===== bf16 MFMA GEMM, 64x64 tile, gload_lds + 2-phase (d0,d1,d2) ==========
__global__ __launch_bounds__(256)
void k_b64g(const unsigned short* __restrict__ Abase,
            const unsigned short* __restrict__ Bt,
            unsigned short* __restrict__ Cb,
            const float* __restrict__ bias,
            float* __restrict__ stats,
            int Mslice, int K, int N, int decK)
{
    __shared__ __align__(16) unsigned short As[2][64 * 64];
    __shared__ __align__(16) unsigned short Bs[2][64 * 64];
    __shared__ float colsum[64], colsq[64];

    const int tid  = threadIdx.x;
    const int lane = tid & 63;
    const int wave = tid >> 6;
    const int wm = (wave >> 1) << 5;
    const int wn = (wave & 1) << 5;
    const int z  = blockIdx.z;
    const int n0 = blockIdx.x << 6;
    const int m0 = blockIdx.y << 6;

    if (stats != nullptr && tid < 64) { colsum[tid] = 0.f; colsq[tid] = 0.f; }

    const int a_slice = z / decK, wk = z - a_slice * decK;
    const unsigned short* Ap = Abase + (size_t)a_slice * (size_t)Mslice * (size_t)K;
    const unsigned short* Bp = Bt + (size_t)wk * (size_t)N * (size_t)K;

    const int srow  = tid >> 3;                       // 0..31
    const int selem = ((tid & 7) ^ (srow & 7)) << 3;
    const unsigned short* Asrc = Ap + (size_t)(m0 + srow) * K + selem;
    const unsigned short* Bsrc = Bp + (size_t)(n0 + srow) * K + selem;

    f32x4 acc[2][2];
#pragma unroll
    for (int i = 0; i < 2; ++i)
#pragma unroll
        for (int j = 0; j < 2; ++j) acc[i][j] = (f32x4){0.f, 0.f, 0.f, 0.f};

    const int lidx = lane & 15;
    const int lq   = lane >> 4;

    // ---- prologue: stage chunk 0 into buffer 0 ----
#pragma unroll
    for (int c = 0; c < 2; ++c) {
        gload16(Asrc + (size_t)(c << 5) * K, &As[0][tid * 8 + (c << 11)]);
        gload16(Bsrc + (size_t)(c << 5) * K, &Bs[0][tid * 8 + (c << 11)]);
    }
    __syncthreads();

    const int nsteps = K >> 6;
    int cur = 0;
    for (int t = 0; t < nsteps; ++t) {
        if (t + 1 < nsteps) {
            const int k0n = (t + 1) << 6;
#pragma unroll
            for (int c = 0; c < 2; ++c) {
                gload16(Asrc + (size_t)(c << 5) * K + k0n,
                        &As[cur ^ 1][tid * 8 + (c << 11)]);
                gload16(Bsrc + (size_t)(c << 5) * K + k0n,
                        &Bs[cur ^ 1][tid * 8 + (c << 11)]);
            }
        }
#pragma unroll
        for (int ks = 0; ks < 2; ++ks) {
            const int ub = (ks << 2) + lq;
            const int uo = (ub ^ (lidx & 7)) << 3;
            bf16x8 af[2], bfv[2];
#pragma unroll
            for (int t2 = 0; t2 < 2; ++t2)
                af[t2] = *(const bf16x8*)&As[cur][((wm + (t2 << 4) + lidx) << 6) + uo];
#pragma unroll
            for (int t2 = 0; t2 < 2; ++t2)
                bfv[t2] = *(const bf16x8*)&Bs[cur][((wn + (t2 << 4) + lidx) << 6) + uo];
#pragma unroll
            for (int mt = 0; mt < 2; ++mt)
#pragma unroll
                for (int nt = 0; nt < 2; ++nt)
                    acc[mt][nt] = __builtin_amdgcn_mfma_f32_16x16x32_bf16(
                        af[mt], bfv[nt], acc[mt][nt], 0, 0, 0);
        }
        __syncthreads();
        cur ^= 1;
    }

    const int rbase = lq << 2;
#pragma unroll
    for (int nt = 0; nt < 2; ++nt) {
        const int col = n0 + wn + (nt << 4) + lidx;
        const float badd = (bias != nullptr) ? bias[col] : 0.f;
        float s = 0.f, q = 0.f;
#pragma unroll
        for (int mt = 0; mt < 2; ++mt) {
#pragma unroll
            for (int r = 0; r < 4; ++r) {
                float x = acc[mt][nt][r];
                s += x; q += x * x;
                const int row = m0 + wm + (mt << 4) + rbase + r;
                Cb[((size_t)z * Mslice + row) * (size_t)N + col] = bfh(x + badd);
            }
        }
        if (stats != nullptr) {
            s += __shfl_xor(s, 16, 64); s += __shfl_xor(s, 32, 64);
            q += __shfl_xor(q, 16, 64); q += __shfl_xor(q, 32, 64);
            if (lq == 0) {
                atomicAdd(&colsum[wn + (nt << 4) + lidx], s);
                atomicAdd(&colsq [wn + (nt << 4) + lidx], q);
            }
        }
    }
    if (stats != nullptr) {
        __syncthreads();
        if (tid < 64) {
            atomicAdd(&stats[n0 + tid],       colsum[tid]);
            atomicAdd(&stats[512 + n0 + tid], colsq[tid]);
        }
    }
}

// ===== split-bf16 MFMA GEMM, 64x64 tile, gload_lds + 2-phase (e1,e2,e3) ====
// Linear LDS [2][64][32] bf16 per buffer; XOR-swizzle unit^(row&3).
__global__ __launch_bounds__(256)
void k_sp64g(const unsigned short* __restrict__ Ahg,
             const unsigned short* __restrict__ Alg,
             const unsigned short* __restrict__ Whi,
             const unsigned short* __restrict__ Wlo,
             float* __restrict__ Cout, float* __restrict__ stats,
             int Mslice, int Kp, int N, int n_terms)
{
    __shared__ __align__(16) unsigned short Ah[2][64 * 32];
    __shared__ __align__(16) unsigned short Al[2][64 * 32];
    __shared__ __align__(16) unsigned short Bh[2][64 * 32];
    __shared__ __align__(16) unsigned short Bl[2][64 * 32];
    __shared__ float colsum[64], colsq[64];

    const int tid  = threadIdx.x;
    const int lane = tid & 63;
    const int wave = tid >> 6;
    const int wm = (wave >> 1) << 5;
    const int wn = (wave & 1) << 5;
    const int z  = blockIdx.z;
    const int n0 = blockIdx.x << 6;
    const int m0 = blockIdx.y << 6;

    if (stats != nullptr && tid < 64) { colsum[tid] = 0.f; colsq[tid] = 0.f; }

    const int srow  = tid >> 2;                       // 0..63
    const int selem = ((tid & 3) ^ (srow & 3)) << 3;  // swizzled elem in 32-row

    f32x4 acc[2][2];
#pragma unroll
    for (int i = 0; i < 2; ++i)
#pragma unroll
        for (int j = 0; j < 2; ++j) acc[i][j] = (f32x4){0.f, 0.f, 0.f, 0.f};

    const int lidx = lane & 15;
    const int lq   = lane >> 4;
    const int uo   = (lq ^ (lidx & 3)) << 3;          // swizzled read offset

    const int cpk = Kp >> 5;
    const int tot = n_terms * cpk;

    // ---- prologue: stage chunk 0 (term 0, k 0) into buffer 0 ----
    {
        const size_t ab = ((size_t)(z * n_terms) * Mslice + m0 + srow)
                          * (size_t)Kp + selem;
        const size_t bb = ((size_t)(n0 + srow)) * (size_t)Kp + selem;
        gload16(Ahg + ab, &Ah[0][tid * 8]);
        gload16(Alg + ab, &Al[0][tid * 8]);
        gload16(Whi + bb, &Bh[0][tid * 8]);
        gload16(Wlo + bb, &Bl[0][tid * 8]);
    }
    __syncthreads();

    int cur = 0;
    int lt = 0, lk = 32;
    if (lk >= Kp) { lk = 0; lt = 1; }
    for (int c = 0; c < tot; ++c) {
        if (c + 1 < tot) {
            const size_t ab = ((size_t)(z * n_terms + lt) * Mslice + m0 + srow)
                              * (size_t)Kp + lk + selem;
            const size_t bb = ((size_t)lt * N + n0 + srow) * (size_t)Kp + lk + selem;
            gload16(Ahg + ab, &Ah[cur ^ 1][tid * 8]);
            gload16(Alg + ab, &Al[cur ^ 1][tid * 8]);
            gload16(Whi + bb, &Bh[cur ^ 1][tid * 8]);
            gload16(Wlo + bb, &Bl[cur ^ 1][tid * 8]);
            lk += 32; if (lk >= Kp) { lk = 0; ++lt; }
        }
        bf16x8 ah[2], al[2], bh[2], bl[2];
#pragma unroll
        for (int t = 0; t < 2; ++t) {
            const int ra = ((wm + (t << 4) + lidx) << 5) + uo;
            ah[t] = *(const bf16x8*)&Ah[cur][ra];
            al[t] = *(const bf16x8*)&Al[cur][ra];
        }
#pragma unroll
        for (int t = 0; t < 2; ++t) {
            const int rb = ((wn + (t << 4) + lidx) << 5) + uo;
            bh[t] = *(const bf16x8*)&Bh[cur][rb];
            bl[t] = *(const bf16x8*)&Bl[cur][rb];
        }
#pragma unroll
        for (int mt = 0; mt < 2; ++mt)
#pragma unroll
            for (int nt = 0; nt < 2; ++nt) {
                acc[mt][nt] = __builtin_amdgcn_mfma_f32_16x16x32_bf16(
                    ah[mt], bh[nt], acc[mt][nt], 0, 0, 0);
                acc[mt][nt] = __builtin_amdgcn_mfma_f32_16x16x32_bf16(
                    al[mt], bh[nt], acc[mt][nt], 0, 0, 0);
                acc[mt][nt] = __builtin_amdgcn_mfma_f32_16x16x32_bf16(
                    ah[mt], bl[nt], acc[mt][nt], 0, 0, 0);
            }
        __syncthreads();
        cur ^= 1;
    }

    const int rbase = lq << 2;
#pragma unroll
    for (int nt = 0; nt < 2; ++nt) {
        const int col = n0 + wn + (nt << 4) + lidx;
        float s = 0.f, q = 0.f;
#pragma unroll
        for (int mt = 0; mt < 2; ++mt) {
#pragma unroll
            for (int r = 0; r < 4; ++r) {
                float x = acc[mt][nt][r];
                s += x; q += x * x;
                const int row = m0 + wm + (mt << 4) + rbase + r;
                Cout[((size_t)z * Mslice + row) * (size_t)N + col] = x;
            }
        }
        if (stats != nullptr) {
            s += __shfl_xor(s, 16, 64); s += __shfl_xor(s, 32, 64);
            q += __shfl_xor(q, 16, 64); q += __shfl_xor(q, 32, 64);
            if (lq == 0) {
                atomicAdd(&colsum[wn + (nt << 4) + lidx], s);
                atomicAdd(&colsq [wn + (nt << 4) + lidx], q);
            }
        }
    }
    if (stats != nullptr) {
        __syncthreads();
        if (tid < 64) {
            atomicAdd(&stats[n0 + tid],       colsum[tid]);
            atomicAdd(&stats[512 + n0 + tid], colsq[tid]);
        }
    }
}

// ======== merged prep kernel (10 independent preps, incl. sp_weff) =========
// sections: s0 init:32  s1 codeT:1024  s2 codesq:512  s3 spE2:3072
//  s4 spE3:2048  s5 wq:1024  s6 wd1:2048  s7 wd2:3072  s8 wd3:5120
//  s9 wout:270  s10 split_in:19200  s11 sp_weff:1600   total 39022
// weff lives OUTSIDE the wt_e1-overlay region -> s11 has no aliasing with
// s8/s9 weight writes (round-23 race fixed).
__global__ void k_prep(float* __restrict__ zbase, unsigned long long* __restrict__ amin,
                       const float* __restrict__ codebook, float* __restrict__ codeT,
                       float* __restrict__ codesq,
                       const float* __restrict__ w_e2, unsigned short* __restrict__ whi_e2,
                       unsigned short* __restrict__ wlo_e2,
                       const float* __restrict__ w_e3, unsigned short* __restrict__ whi_e3,
                       unsigned short* __restrict__ wlo_e3,
                       const float* __restrict__ W_q,  unsigned short* __restrict__ wqb,
                       const float* __restrict__ w_d1, unsigned short* __restrict__ wd1b,
                       const float* __restrict__ w_d2, unsigned short* __restrict__ wd2b,
                       const float* __restrict__ w_d3, unsigned short* __restrict__ wd3b,
                       const float* __restrict__ W_out, unsigned short* __restrict__ woutb,
                       const float* __restrict__ in_seqs,
                       unsigned short* __restrict__ in_h, unsigned short* __restrict__ in_l,
                       const float* __restrict__ weff,
                       unsigned short* __restrict__ whi_e1,
                       unsigned short* __restrict__ wlo_e1)
{
    __shared__ float red[4];
    const int bid = blockIdx.x;
    const int tid = threadIdx.x;

    if (bid < 32) {                                    // s0: init
        int t = bid * 256 + tid;
        if (t < 6720) zbase[t] = 0.f;
        if (t < 1024) amin[t] = ~0ULL;
        return;
    }
    if (bid < 1056) {                                  // s1: codeT repack (Kc=1)
        int idx = (bid - 32) * 256 + tid;
        int i = (idx >> 9) & 511, o = idx & 511;
        codeT[idx] = codebook[(o << 9) + i];
        return;
    }
    if (bid < 1568) {                                  // s2: codesq
        int c = bid - 1056;
        float s = 0.f;
        for (int i = tid; i < 512; i += 256) { float v = codebook[c * 512 + i]; s += v * v; }
        for (int off = 32; off; off >>= 1) s += __shfl_down(s, off, 64);
        if ((tid & 63) == 0) red[tid >> 6] = s;
        __syncthreads();
        if (tid == 0) codesq[c] = red[0] + red[1] + red[2] + red[3];
        return;
    }
    if (bid < 4640) {                                  // s3: split e2 (Kc=3)
        int idx = (bid - 1568) * 256 + tid;
        int i = idx & 511, o = (idx >> 9) & 511, k = idx >> 18;
        float v = w_e2[(((o << 9) + i) * 3) + k];
        unsigned short h = bfh(v);
        whi_e2[idx] = h; wlo_e2[idx] = bfh(v - bf2f(h));
        return;
    }
    if (bid < 6688) {                                  // s4: split e3 (Kc=2)
        int idx = (bid - 4640) * 256 + tid;
        int i = idx & 511, o = (idx >> 9) & 511, k = idx >> 18;
        float v = w_e3[(((o << 9) + i) * 2) + k];
        unsigned short h = bfh(v);
        whi_e3[idx] = h; wlo_e3[idx] = bfh(v - bf2f(h));
        return;
    }
    if (bid < 7712) {                                  // s5: W_q bf (Kc=1,I=O=512)
        int idx = (bid - 6688) * 256 + tid;
        int i = idx & 511, o = (idx >> 9) & 511;
        wqb[idx] = bfh(W_q[((size_t)i << 9) + o]);
        return;
    }
    if (bid < 9760) {                                  // s6: w_d1 bf (Kc=2)
        int idx = (bid - 7712) * 256 + tid;
        int i = idx & 511, o = (idx >> 9) & 511, k = idx >> 18;
        wd1b[idx] = bfh(w_d1[(((size_t)i << 9) + o) * 2 + k]);
        return;
    }
    if (bid < 12832) {                                 // s7: w_d2 bf (Kc=3)
        int idx = (bid - 9760) * 256 + tid;
        int i = idx & 511, o = (idx >> 9) & 511, k = idx >> 18;
        wd2b[idx] = bfh(w_d2[(((size_t)i << 9) + o) * 3 + k]);
        return;
    }
    if (bid < 17952) {                                 // s8: w_d3 bf (Kc=5)
        int idx = (bid - 12832) * 256 + tid;
        int i = idx & 511, o = (idx >> 9) & 511, k = idx >> 18;
        wd3b[idx] = bfh(w_d3[(((size_t)i << 9) + o) * 5 + k]);
        return;
    }
    if (bid < 18222) {                                 // s9: W_out bf (Kc=1,I=512,O=135)
        int idx = (bid - 17952) * 256 + tid;
        if (idx >= 69120) return;
        int i = idx % 512, o = idx / 512;              // [o][i], o<135
        woutb[idx] = bfh(W_out[((size_t)i * 135) + o]);
        return;
    }
    if (bid < 37422) {                                 // s10: split_in
        int idx = (bid - 18222) * 256 + tid;
        int i = idx % 160, r = idx / 160;
        float v = (i < 135) ? in_seqs[(size_t)r * 135 + i] : 0.f;
        unsigned short h = bfh(v);
        in_h[idx] = h; in_l[idx] = bfh(v - bf2f(h));
        return;
    }
    {                                                  // s11: sp_weff
        int idx = (bid - 37422) * 256 + tid;
        if (idx >= 409600) return;
        int i = idx % 160;
        int o = (idx / 160) & 511;
        int t = idx / 81920;
        float v = (i < 135) ? weff[((size_t)t * 135 + i) * 512 + o] : 0.f;
        unsigned short h = bfh(v);
        whi_e1[idx] = h;
        wlo_e1[idx] = bfh(v - bf2f(h));
    }
}

// ============================ small kernels ================================
__global__ void k_repack(const float* __restrict__ w, float* __restrict__ wt,
                         int Kc, int total)
{
    int idx = blockIdx.x * 256 + threadIdx.x;
    if (idx >= total) return;
    int k = idx >> 18;
    int rem = idx & 262143;
    int i = rem >> 9, o = rem & 511;
    wt[idx] = w[(((o << 9) + i) * Kc + k)];
}

// BN-finalize fused: compute sc/sh in LDS (identical math), split to hi/lo
__global__ void k_bnsplit(const float* __restrict__ x,
                          const float* __restrict__ stats,
                          const float* __restrict__ g, const float* __restrict__ b,
                          float inv_n,
                          unsigned short* __restrict__ hq, unsigned short* __restrict__ lq_,
                          int total4)
{
    __shared__ __align__(16) float scs[512], shs[512];
    const int tid = threadIdx.x;
    bn_fin_lds(stats, g, b, inv_n, scs, shs, tid);
    __syncthreads();

    int idx = blockIdx.x * 256 + tid;
    if (idx >= total4) return;
    const int base = idx << 2;
    float4 f = *(const float4*)(x + base);
    const int k = base & 511;
    float4 s = *(const float4*)&scs[k];
    float4 c = *(const float4*)&shs[k];
    float y0 = fmaxf(fmaf(f.x, s.x, c.x), 0.f);
    float y1 = fmaxf(fmaf(f.y, s.y, c.y), 0.f);
    float y2 = fmaxf(fmaf(f.z, s.z, c.z), 0.f);
    float y3 = fmaxf(fmaf(f.w, s.w, c.w), 0.f);
    unsigned short h0 = bfh(y0), h1 = bfh(y1), h2 = bfh(y2), h3 = bfh(y3);
    unsigned short l0 = bfh(y0 - bf2f(h0)), l1 = bfh(y1 - bf2f(h1));
    unsigned short l2 = bfh(y2 - bf2f(h2)), l3 = bfh(y3 - bf2f(h3));
    *(uint2*)&hq[base]  = make_uint2((unsigned)h0 | ((unsigned)h1 << 16),
                                     (unsigned)h2 | ((unsigned)h3 << 16));
    *(uint2*)&lq_[base] = make_uint2((unsigned)l0 | ((unsigned)l1 << 16),
                                     (unsigned)l2 | ((unsigned)l3 << 16));
}

// BN-finalize fused: compute sc/sh in LDS, apply BN+ReLU, emit bf16
__global__ void k_bnapply(const unsigned short* __restrict__ x,
                          const float* __restrict__ stats,
                          const float* __restrict__ g, const float* __restrict__ b,
                          float inv_n,
                          unsigned short* __restrict__ y, int total8)
{
    __shared__ __align__(16) float scs[512], shs[512];
    const int tid = threadIdx.x;
    bn_fin_lds(stats, g, b, inv_n, scs, shs, tid);
    __syncthreads();

    int idx = blockIdx.x * 256 + tid;
    if (idx >= total8) return;
    const int base = idx << 3;
    uint4 raw = *(const uint4*)(x + base);
    const int k = base & 511;
    float4 s0 = *(const float4*)&scs[k];
    float4 c0 = *(const float4*)&shs[k];
    float4 s1 = *(const float4*)&scs[k + 4];
    float4 c1 = *(const float4*)&shs[k + 4];
    unsigned* u = (unsigned*)&raw;
    float x0 = __uint_as_float(u[0] << 16),        x1 = __uint_as_float(u[0] & 0xffff0000u);
    float x2 = __uint_as_float(u[1] << 16),        x3 = __uint_as_float(u[1] & 0xffff0000u);
    float x4 = __uint_as_float(u[2] << 16),        x5 = __uint_as_float(u[2] & 0xffff0000u);
    float x6 = __uint_as_float(u[3] << 16),        x7 = __uint_as_float(u[3] & 0xffff0000u);
    x0 = fmaxf(fmaf(x0, s0.x, c0.x), 0.f); x1 = fmaxf(fmaf(x1, s0.y, c0.y), 0.f);
    x2 = fmaxf(fmaf(x2, s0.z, c0.z), 0.f); x3 = fmaxf(fmaf(x3, s0.w, c0.w), 0.f);
    x4 = fmaxf(fmaf(x4, s1.x, c1.x), 0.f); x5 = fmaxf(fmaf(x5, s1.y, c1.y), 0.f);
    x6 = fmaxf(fmaf(x6, s1.z, c1.z), 0.f); x7 = fmaxf(fmaf(x7, s1.w, c1.w), 0.f);
    *(uint4*)&y[base] = make_uint4(pk_bf16(x0, x1), pk_bf16(x2, x3),
                                   pk_bf16(x4, x5), pk_bf16(x6, x7));
}

__global__ void k_bn_fin(const float* __restrict__ stats,
                         const float* __restrict__ g, const float* __restrict__ b,
                         float* __restrict__ sc, float* __restrict__ sh, float inv_n)
{
    int c = blockIdx.x * blockDim.x + threadIdx.x;
    if (c >= 512) return;
    float m = stats[c] * inv_n;
    float v = stats[512 + c] * inv_n - m * m;
    float a = (float)((double)g[c] / sqrt((double)v + 1e-5));
    sc[c] = a;
    sh[c] = b[c] - m * a;
}

__global__ void k_vq_gather(const unsigned long long* __restrict__ amin,
                            const float* __restrict__ codebook,
                            const float* __restrict__ e3pre,
                            const float* __restrict__ sc, const float* __restrict__ sh,
                            unsigned short* __restrict__ quant_bf,
                            float* __restrict__ loss,
                            unsigned int* __restrict__ hist)
{
    int b = blockIdx.x; int t = threadIdx.x;   // 256 threads
    unsigned int idx = (unsigned int)(amin[b] & 0xFFFFFFFFull) & 511u;
    float part = 0.f;
    for (int i = t; i < 512; i += 256) {
        float q = codebook[(size_t)idx * 512 + i];
        quant_bf[(size_t)b * 512 + i] = bfh(q);
        float x = e3pre[(size_t)b * 512 + i];
        float f = fmaxf(fmaf(x, sc[i], sh[i]), 0.f);
        float d = q - f;
        part += d * d;
    }
    for (int off = 32; off; off >>= 1) part += __shfl_down(part, off, 64);
    __shared__ float red[4];
    if ((t & 63) == 0) red[t >> 6] = part;
    __syncthreads();
    if (t == 0) {
        atomicAdd(loss, red[0] + red[1] + red[2] + red[3]);
        atomicAdd(&hist[idx], 1u);
    }
}

__global__ void k_scalars(const unsigned int* __restrict__ hist,
                          const float* __restrict__ loss, float* __restrict__ out)
{
    int t = threadIdx.x;   // 512
    float p = (float)hist[t] * (1.0f / 1024.0f);
    float e = p * logf(p + 1e-10f);
    for (int off = 32; off; off >>= 1) e += __shfl_down(e, off, 64);
    __shared__ float red[8];
    if ((t & 63) == 0) red[t >> 6] = e;
    __syncthreads();
    if (t == 0) {
        float s = 0.f;
        for (int i = 0; i < 8; ++i) s += red[i];
        out[4147200] = 1.25f * loss[0] * (1.0f / 524288.0f);
        out[4147201] = expf(-s);
    }
}

extern "C" void kernel_launch(void* const* d_in, const int* in_sizes, int n_in,
                              void* d_out, int out_size, void* d_ws, size_t ws_size,
                              hipStream_t stream)
{
    const float* in_seqs = (const float*)d_in[0];
    const float* W_in  = (const float*)d_in[1];
    const float* w_e1  = (const float*)d_in[3];
    const float* g_e1  = (const float*)d_in[4];
    const float* be1   = (const float*)d_in[5];
    const float* w_e2  = (const float*)d_in[6];
    const float* g_e2  = (const float*)d_in[7];
    const float* be2   = (const float*)d_in[8];
    const float* w_e3  = (const float*)d_in[9];
    const float* g_e3  = (const float*)d_in[10];
    const float* be3   = (const float*)d_in[11];
    const float* codebook = (const float*)d_in[12];
    const float* W_q   = (const float*)d_in[13];
    const float* b_q   = (const float*)d_in[14];
    const float* w_d1  = (const float*)d_in[15];
    const float* g_d1  = (const float*)d_in[16];
    const float* bd1   = (const float*)d_in[17];
    const float* w_d2  = (const float*)d_in[18];
    const float* g_d2  = (const float*)d_in[19];
    const float* bd2   = (const float*)d_in[20];
    const float* w_d3  = (const float*)d_in[21];
    const float* g_d3  = (const float*)d_in[22];
    const float* bd3   = (const float*)d_in[23];
    const float* W_out = (const float*)d_in[24];
    const float* b_out = (const float*)d_in[25];
    float* out = (float*)d_out;

    // ---- workspace layout (float offsets) ----
    float* W = (float*)d_ws;
    unsigned long long* amin = (unsigned long long*)W;            // 2048 f
    float* stats  = W + 2048;                                     // 6144
    float* lossp  = W + 8192;                                     // 64
    unsigned int* hist = (unsigned int*)(W + 8256);               // 512
    float* scsh   = W + 8768;                                     // 6144
    float* codesq = W + 14912;                                    // 512
    float* wt_e1  = W + 15424;                                    // 1310720 f
    float* codeT  = W + 1671744;                                  // 262144 f
    unsigned short* esw = (unsigned short*)(W + 1933888);         // 3440640 ush
    unsigned short* whi_e1 = esw;
    unsigned short* wlo_e1 = esw + 409600;
    unsigned short* whi_e2 = esw + 819200;
    unsigned short* wlo_e2 = esw + 1605632;
    unsigned short* whi_e3 = esw + 2392064;
    unsigned short* wlo_e3 = esw + 2916352;
    unsigned short* in_h  = (unsigned short*)(W + 3654208);       // 4915200 ush
    unsigned short* in_l  = in_h + 4915200;
    unsigned short* d3pre = (unsigned short*)(W + 3654208);       // 15728640 ush
    float* e1f = W + 11518528;                                    // 3145728 f
    unsigned short* e1h = (unsigned short*)(W + 14664256);        // 3145728 ush
    unsigned short* e1l = e1h + 3145728;
    float* e2f = W + 17809984;                                    // 1048576 f
    unsigned short* e2h = (unsigned short*)(W + 18858560);        // 1048576 ush
    unsigned short* e2l = e2h + 1048576;
    unsigned short* d2pre = (unsigned short*)(W + 17809984);      // 3145728 ush
    unsigned short* d2bf  = d2pre + 3145728;                      // 3145728 ush
    float* e3f = W + 20955712;                                    // 524288 f
    unsigned short* quant_bf = (unsigned short*)(W + 21480000);   // 524288 ush
    unsigned short* d0bf     = (unsigned short*)(W + 21742144);   // 524288 ush
    unsigned short* d1pre    = (unsigned short*)(W + 22004288);   // 1048576 ush
    unsigned short* d1bf     = (unsigned short*)(W + 22528640);   // 1048576 ush
    unsigned short* d3bf     = (unsigned short*)(W + 23052928);   // 15728640 ush
    float* weff   = W + 30917248;                                 // 345600 f
    // weff ends at 31262848 floats (~125 MB) < 256 MiB ws; no aliasing.

    unsigned short* db    = (unsigned short*)wt_e1;
    unsigned short* wqb   = db;
    unsigned short* wd1b  = db + 262144;
    unsigned short* wd2b  = db + 786432;
    unsigned short* wd3b  = db + 1572864;
    unsigned short* woutb = db + 2883584;

    float* st_e1 = stats + 0 * 1024;
    float* st_e2 = stats + 1 * 1024;
    float* st_e3 = stats + 2 * 1024; float* sc_e3 = scsh + 2 * 1024; float* sh_e3 = sc_e3 + 512;
    float* st_d1 = stats + 3 * 1024;
    float* st_d2 = stats + 4 * 1024;
    float* st_d3 = stats + 5 * 1024;

    dim3 blk(256);

    // order: wt_e1 fp32 repack -> weff gemm -> k_prep (contains sp_weff s11;
    // weff is in a non-aliased region so s11 is race-free vs s8/s9).
    k_repack<<<dim3(5 * 1024), blk, 0, stream>>>(w_e1, wt_e1, 5, 5 * 262144);
    k_gemm<<<dim3(16, 5, 5), blk, 0, stream>>>(W_in, wt_e1, weff,
        nullptr, nullptr, nullptr, nullptr, 135, 512, 512, 5);

    k_prep<<<dim3(39022), blk, 0, stream>>>(stats, amin,
        codebook, codeT, codesq,
        w_e2, whi_e2, wlo_e2, w_e3, whi_e3, wlo_e3,
        W_q, wqb, w_d1, wd1b, w_d2, wd2b, w_d3, wd3b, W_out, woutb,
        in_seqs, in_h, in_l, weff, whi_e1, wlo_e1);

    // ---- encoder: 64x64-tile split-bf16 MFMA (gload_lds, 2-phase) ----
    k_sp64g<<<dim3(8, 16, 6), blk, 0, stream>>>(in_h, in_l, whi_e1, wlo_e1,
        e1f, st_e1, 1024, 160, 512, 5);
    k_bnsplit<<<dim3(3072), blk, 0, stream>>>(e1f, st_e1, g_e1, be1,
        1.f / 6144.f, e1h, e1l, 786432);

    k_sp64g<<<dim3(8, 16, 2), blk, 0, stream>>>(e1h, e1l, whi_e2, wlo_e2,
        e2f, st_e2, 1024, 512, 512, 3);
    k_bnsplit<<<dim3(1024), blk, 0, stream>>>(e2f, st_e2, g_e2, be2,
        1.f / 2048.f, e2h, e2l, 262144);

    k_sp64g<<<dim3(8, 16, 1), blk, 0, stream>>>(e2h, e2l, whi_e3, wlo_e3,
        e3f, st_e3, 1024, 512, 512, 2);
    k_bn_fin<<<dim3(2), blk, 0, stream>>>(st_e3, g_e3, be3, sc_e3, sh_e3, 1.f / 1024.f);

    // ---- VQ: fp32 dist GEMM + argmin (32x32 tiles, 512 blocks) ----
    k_gemm<<<dim3(16, 32, 1), blk, 0, stream>>>(e3f, codeT, nullptr,
        sc_e3, sh_e3, amin, codesq, 1024, 512, 512, 1);
    k_vq_gather<<<dim3(1024), blk, 0, stream>>>(amin, codebook, e3f, sc_e3, sh_e3,
                                                quant_bf, lossp, hist);

    // ---- decoder: all gload_lds 2-phase; BN fused into bnapply ----
    k_b64g<<<dim3(8, 16, 1), blk, 0, stream>>>(quant_bf, wqb, d0bf,
        b_q, nullptr, 1024, 512, 512, 1);

    k_b64g<<<dim3(8, 16, 2), blk, 0, stream>>>(d0bf, wd1b, d1pre,
        nullptr, st_d1, 1024, 512, 512, 2);
    k_bnapply<<<dim3(512), blk, 0, stream>>>(d1pre, st_d1, g_d1, bd1,
        1.f / 2048.f, d1bf, 131072);

    k_b64g<<<dim3(8, 16, 6), blk, 0, stream>>>(d1bf, wd2b, d2pre,
        nullptr, st_d2, 1024, 512, 512, 3);
    k_bnapply<<<dim3(1536), blk, 0, stream>>>(d2pre, st_d2, g_d2, bd2,
        1.f / 6144.f, d2bf, 393216);

    // d3: 256x256 tiles, gload_lds 2-phase, 512 threads (240 blocks)
    k_m256<<<dim3(2, 4, 30), dim3(512), 0, stream>>>(d2bf, wd3b, d3pre,
        st_d3, 1024, 512, 512, 5);
    k_bnapply<<<dim3(7680), blk, 0, stream>>>(d3pre, st_d3, g_d3, bd3,
        1.f / 30720.f, d3bf, 1966080);

    // out-proj: 128x128 gload_lds 2-phase, operm store, N=135 (B rows clamped)
    k_mfma_g<<<dim3(2, 240, 1), blk, 0, stream>>>(d3bf, woutb, nullptr,
        out, b_out, nullptr, 30720, 512, 135, 1);

    k_scalars<<<dim3(1), dim3(512), 0, stream>>>(hist, lossp, out);
}

// Round 14
// 408.448 us; speedup vs baseline: 1.0846x; 1.0017x over previous
//
#include <hip/hip_runtime.h>
#include <math.h>

// ---------------------------------------------------------------------------
// VQ-VAE forward (round 25 = round 24 + e1 retiled 64x128 via k_sp64w).
//  - Round-24 base (409.2us): gload_lds 2-phase, bn_fin fused, sp_weff in
//    k_prep, weff relocated (race-free).
//  - NEW: k_sp64w (split-bf16, M=64 N=128 tile, 4 waves @32x64, acc[2][4],
//    LDS 49KB, grid (4,16,6)=384 >= 256 CUs, 3 blk/CU capacity). Halves
//    e1's A-side staged L3 traffic (157->77 MB; A redundancy 8x->4x).
//    B staged as 2x64-row sub-chunks at elem offset c<<11 in the 4096-elem
//    buffer; swizzle parity (row&3)==(srow&3) preserved on both sides ->
//    bit-identical MFMA chains.
//  - All other kernels byte-identical to round 24.
// ---------------------------------------------------------------------------

typedef __attribute__((ext_vector_type(8))) short bf16x8;
typedef __attribute__((ext_vector_type(4))) float f32x4;

__device__ __forceinline__ unsigned pk_bf16(float a, float b) {
    unsigned ua = __float_as_uint(a), ub = __float_as_uint(b);
    ua += 0x7fffu + ((ua >> 16) & 1u);          // RNE
    ub += 0x7fffu + ((ub >> 16) & 1u);
    return (ua >> 16) | (ub & 0xffff0000u);
}
__device__ __forceinline__ unsigned short bfh(float x) {
    unsigned u = __float_as_uint(x);
    u += 0x7fffu + ((u >> 16) & 1u);
    return (unsigned short)(u >> 16);
}
__device__ __forceinline__ float bf2f(unsigned short h) {
    return __uint_as_float(((unsigned)h) << 16);
}

// async global->LDS DMA, 16 B per lane (global_load_lds_dwordx4)
__device__ __forceinline__ void gload16(const unsigned short* g, unsigned short* l) {
    __builtin_amdgcn_global_load_lds(
        (const __attribute__((address_space(1))) unsigned int*)g,
        (__attribute__((address_space(3))) unsigned int*)l, 16, 0, 0);
}

__device__ __forceinline__ void bn4(float4& a, const float* __restrict__ s,
                                    const float* __restrict__ c) {
    float4 sv = *(const float4*)s;
    float4 cv = *(const float4*)c;
    a.x = fmaxf(fmaf(a.x, sv.x, cv.x), 0.f);
    a.y = fmaxf(fmaf(a.y, sv.y, cv.y), 0.f);
    a.z = fmaxf(fmaf(a.z, sv.z, cv.z), 0.f);
    a.w = fmaxf(fmaf(a.w, sv.w, cv.w), 0.f);
}

// shared helper: compute sc/sh for 512 channels into LDS (identical math to
// k_bn_fin; deterministic -> bit-identical wherever applied)
__device__ __forceinline__ void bn_fin_lds(const float* __restrict__ stats,
                                           const float* __restrict__ g,
                                           const float* __restrict__ b,
                                           float inv_n,
                                           float* scs, float* shs, int tid) {
    for (int c = tid; c < 512; c += 256) {
        float m = stats[c] * inv_n;
        float v = stats[512 + c] * inv_n - m * m;
        float a = (float)((double)g[c] / sqrt((double)v + 1e-5));
        scs[c] = a;
        shs[c] = b[c] - m * a;
    }
}

// ======================= fp32 GEMM (weff + VQ dist) ========================
#define FBK  32
#define FSTR 36

__global__ __launch_bounds__(256)
void k_gemm(const float* __restrict__ Abase,
            const float* __restrict__ Wt,
            float* __restrict__ Cout,
            const float* __restrict__ bnS, const float* __restrict__ bnB,
            unsigned long long* __restrict__ amin,
            const float* __restrict__ codesq,
            int Mslice, int K, int N, int decK)
{
    __shared__ __align__(16) float As[FBK][FSTR];
    __shared__ __align__(16) float Bs[FBK][FSTR];

    const int tid = threadIdx.x;
    const int z  = blockIdx.z;
    const int n0 = blockIdx.x << 5;
    const int m0 = blockIdx.y << 5;
    const int ty = tid >> 4;          // 0..15  (m pairs)
    const int tx = tid & 15;          // 0..15  (n pairs)

    const int a_slice = z / decK, wk = z - a_slice * decK;
    const float* Ap = Abase + (size_t)a_slice * (size_t)Mslice * (size_t)K;
    const float* Wp = Wt    + (size_t)wk * (size_t)K * (size_t)N;

    const int sr  = tid >> 3;         // 0..31
    const int sc4 = (tid & 7) << 2;   // 0..28

    int mrow = m0 + sr;
    if (mrow > Mslice - 1) mrow = Mslice - 1;
    const float* Arow_p = Ap + (size_t)mrow * K;

    float acc[2][2];
    acc[0][0] = 0.f; acc[0][1] = 0.f; acc[1][0] = 0.f; acc[1][1] = 0.f;

    // ---- prefetch chunk 0 ----
    float4 pa = *(const float4*)(Arow_p + sc4);
    if (bnS != nullptr) bn4(pa, bnS + sc4, bnB + sc4);
    float4 pb = *(const float4*)(Wp + (size_t)sr * N + n0 + sc4);

    for (int k0 = 0; k0 < K; k0 += FBK) {
        __syncthreads();
        As[sc4 + 0][sr] = pa.x;
        As[sc4 + 1][sr] = pa.y;
        As[sc4 + 2][sr] = pa.z;
        As[sc4 + 3][sr] = pa.w;
        *(float4*)&Bs[sr][sc4] = pb;
        const int k0n = k0 + FBK;
        if (k0n < K) {
            pa = *(const float4*)(Arow_p + k0n + sc4);
            if (bnS != nullptr) bn4(pa, bnS + k0n + sc4, bnB + k0n + sc4);
            pb = *(const float4*)(Wp + (size_t)(k0n + sr) * N + n0 + sc4);
        }
        __syncthreads();
#pragma unroll
        for (int kk = 0; kk < FBK; ++kk) {
            float2 av = *(const float2*)&As[kk][ty << 1];
            float2 bv = *(const float2*)&Bs[kk][tx << 1];
            acc[0][0] = fmaf(av.x, bv.x, acc[0][0]);
            acc[0][1] = fmaf(av.x, bv.y, acc[0][1]);
            acc[1][0] = fmaf(av.y, bv.x, acc[1][0]);
            acc[1][1] = fmaf(av.y, bv.y, acc[1][1]);
        }
    }

    if (amin != nullptr) {
        float2 cq = *(const float2*)(codesq + n0 + (tx << 1));
#pragma unroll
        for (int i = 0; i < 2; ++i) {
            const int m = m0 + (ty << 1) + i;
            float d0 = cq.x - 2.f * acc[i][0];
            float d1 = cq.y - 2.f * acc[i][1];
            int bj = (d1 < d0) ? 1 : 0;
            float best = (d1 < d0) ? d1 : d0;
            unsigned u = __float_as_uint(best);
            u = (u & 0x80000000u) ? ~u : (u | 0x80000000u);
            unsigned long long key =
                ((unsigned long long)u << 32) | (unsigned)(n0 + (tx << 1) + bj);
#pragma unroll
            for (int off = 1; off < 16; off <<= 1) {
                unsigned long long o = __shfl_xor(key, off, 64);
                if (o < key) key = o;
            }
            if (tx == 0 && m < Mslice) atomicMin(&amin[m], key);
        }
        return;
    }

#pragma unroll
    for (int i = 0; i < 2; ++i) {
        const int m = m0 + (ty << 1) + i;
        if (m < Mslice) {
            float2 v = make_float2(acc[i][0], acc[i][1]);
            *(float2*)&Cout[((size_t)z * Mslice + m) * N + n0 + (tx << 1)] = v;
        }
    }
}

// ===== bf16 MFMA GEMM, 128x128 tile, gload_lds + 2-phase pipeline ==========
// (out-proj). Linear LDS [2][128][64] bf16; XOR-swizzle: 16B unit u at row r
// holds global unit u^(r&7). B rows clamped to N-1 for padded cols.
__global__ __launch_bounds__(256)
void k_mfma_g(const unsigned short* __restrict__ Abase,
              const unsigned short* __restrict__ Bt,
              unsigned short* __restrict__ Cb,
              float* __restrict__ operm,
              const float* __restrict__ bias,
              float* __restrict__ stats,
              int Mslice, int K, int N, int decK)
{
    __shared__ __align__(16) unsigned short As[2][128 * 64];
    __shared__ __align__(16) unsigned short Bs[2][128 * 64];
    __shared__ float colsum[128], colsq[128];

    const int tid  = threadIdx.x;
    const int lane = tid & 63;
    const int wave = tid >> 6;
    const int wm = (wave >> 1) << 6;
    const int wn = (wave & 1) << 6;
    const int z  = blockIdx.z;
    const int n0 = blockIdx.x << 7;
    const int m0 = blockIdx.y << 7;

    if (stats != nullptr && tid < 128) { colsum[tid] = 0.f; colsq[tid] = 0.f; }

    const int a_slice = z / decK, wk = z - a_slice * decK;
    const unsigned short* Ap = Abase + (size_t)a_slice * (size_t)Mslice * (size_t)K;
    const unsigned short* Bp = Bt + (size_t)wk * (size_t)N * (size_t)K;

    const int srow  = tid >> 3;                       // 0..31 (row within chunk)
    const int selem = ((tid & 7) ^ (srow & 7)) << 3;  // swizzled elem offset
    const unsigned short* Asrc = Ap + (size_t)(m0 + srow) * K + selem;

    size_t boff[4];
#pragma unroll
    for (int c = 0; c < 4; ++c) {
        int brow = n0 + srow + (c << 5);
        if (brow > N - 1) brow = N - 1;
        boff[c] = (size_t)brow * K + selem;
    }

    f32x4 acc[4][4];
#pragma unroll
    for (int i = 0; i < 4; ++i)
#pragma unroll
        for (int j = 0; j < 4; ++j) acc[i][j] = (f32x4){0.f, 0.f, 0.f, 0.f};

    const int lidx = lane & 15;
    const int lq   = lane >> 4;

    // ---- prologue: stage chunk 0 into buffer 0 ----
#pragma unroll
    for (int c = 0; c < 4; ++c) {
        gload16(Asrc + (size_t)(c << 5) * K, &As[0][tid * 8 + (c << 11)]);
        gload16(Bp + boff[c],                &Bs[0][tid * 8 + (c << 11)]);
    }
    __syncthreads();   // vmcnt(0) drain: chunk 0 visible

    const int nsteps = K >> 6;
    int cur = 0;
    for (int t = 0; t < nsteps; ++t) {
        if (t + 1 < nsteps) {
            const int k0n = (t + 1) << 6;
#pragma unroll
            for (int c = 0; c < 4; ++c) {
                gload16(Asrc + (size_t)(c << 5) * K + k0n,
                        &As[cur ^ 1][tid * 8 + (c << 11)]);
                gload16(Bp + boff[c] + k0n,
                        &Bs[cur ^ 1][tid * 8 + (c << 11)]);
            }
        }
#pragma unroll
        for (int ks = 0; ks < 2; ++ks) {
            const int ub = (ks << 2) + lq;                        // 16B unit idx
            const int uo = (ub ^ (lidx & 7)) << 3;                // swizzled elems
            bf16x8 af[4], bfv[4];
#pragma unroll
            for (int t4 = 0; t4 < 4; ++t4)
                af[t4] = *(const bf16x8*)&As[cur][((wm + (t4 << 4) + lidx) << 6) + uo];
#pragma unroll
            for (int t4 = 0; t4 < 4; ++t4)
                bfv[t4] = *(const bf16x8*)&Bs[cur][((wn + (t4 << 4) + lidx) << 6) + uo];
#pragma unroll
            for (int mt = 0; mt < 4; ++mt)
#pragma unroll
                for (int nt = 0; nt < 4; ++nt)
                    acc[mt][nt] = __builtin_amdgcn_mfma_f32_16x16x32_bf16(
                        af[mt], bfv[nt], acc[mt][nt], 0, 0, 0);
        }
        __syncthreads();   // prefetch landed + all waves done reading buf cur
        cur ^= 1;
    }

    const int rbase = lq << 2;
#pragma unroll
    for (int nt = 0; nt < 4; ++nt) {
        const int col = n0 + wn + (nt << 4) + lidx;
        const float badd = (bias != nullptr && col < N) ? bias[col] : 0.f;
        float s = 0.f, q = 0.f;
#pragma unroll
        for (int mt = 0; mt < 4; ++mt) {
#pragma unroll
            for (int r = 0; r < 4; ++r) {
                float x = acc[mt][nt][r];
                s += x; q += x * x;
                const int row = m0 + wm + (mt << 4) + rbase + r;
                if (operm != nullptr) {
                    if (col < N) {
                        const int t = row >> 10, b = row & 1023;
                        operm[(size_t)b * 4050 + t * 135 + col] = x + badd;
                    }
                } else {
                    Cb[((size_t)z * Mslice + row) * (size_t)N + col] = bfh(x + badd);
                }
            }
        }
        if (stats != nullptr) {
            s += __shfl_xor(s, 16, 64); s += __shfl_xor(s, 32, 64);
            q += __shfl_xor(q, 16, 64); q += __shfl_xor(q, 32, 64);
            if (lq == 0) {
                atomicAdd(&colsum[wn + (nt << 4) + lidx], s);
                atomicAdd(&colsq [wn + (nt << 4) + lidx], q);
            }
        }
    }
    if (stats != nullptr) {
        __syncthreads();
        if (tid < 128) {
            atomicAdd(&stats[n0 + tid],       colsum[tid]);
            atomicAdd(&stats[512 + n0 + tid], colsq[tid]);
        }
    }
}

// ===== bf16 MFMA GEMM, 256x256 tile, gload_lds + 2-phase (d3) ==============
__global__ __launch_bounds__(512)
void k_m256(const unsigned short* __restrict__ Abase,
            const unsigned short* __restrict__ Bt,
            unsigned short* __restrict__ Cb,
            float* __restrict__ stats,
            int Mslice, int K, int N, int decK)
{
    __shared__ __align__(16) unsigned short As[2][256 * 64];
    __shared__ __align__(16) unsigned short Bs[2][256 * 64];
    __shared__ float colsum[256], colsq[256];

    const int tid  = threadIdx.x;
    const int lane = tid & 63;
    const int wave = tid >> 6;          // 0..7
    const int wm = (wave >> 2) << 7;    // 0,128
    const int wn = (wave & 3) << 6;     // 0,64,128,192
    const int z  = blockIdx.z;
    const int n0 = blockIdx.x << 8;
    const int m0 = blockIdx.y << 8;

    if (stats != nullptr && tid < 256) { colsum[tid] = 0.f; colsq[tid] = 0.f; }

    const int a_slice = z / decK, wk = z - a_slice * decK;
    const unsigned short* Ap = Abase + (size_t)a_slice * (size_t)Mslice * (size_t)K;
    const unsigned short* Bp = Bt + (size_t)wk * (size_t)N * (size_t)K;

    const int srow  = tid >> 3;                       // 0..63 (row within chunk)
    const int selem = ((tid & 7) ^ (srow & 7)) << 3;  // swizzled elem offset
    const unsigned short* Asrc = Ap + (size_t)(m0 + srow) * K + selem;

    size_t boff[4];
#pragma unroll
    for (int c = 0; c < 4; ++c) {
        int brow = n0 + srow + (c << 6);
        if (brow > N - 1) brow = N - 1;
        boff[c] = (size_t)brow * K + selem;
    }

    f32x4 acc[8][4];
#pragma unroll
    for (int i = 0; i < 8; ++i)
#pragma unroll
        for (int j = 0; j < 4; ++j) acc[i][j] = (f32x4){0.f, 0.f, 0.f, 0.f};

    const int lidx = lane & 15;
    const int lq   = lane >> 4;

    // ---- prologue: stage chunk 0 into buffer 0 ----
#pragma unroll
    for (int c = 0; c < 4; ++c) {
        gload16(Asrc + (size_t)(c << 6) * K, &As[0][tid * 8 + (c << 12)]);
        gload16(Bp + boff[c],                &Bs[0][tid * 8 + (c << 12)]);
    }
    __syncthreads();

    const int nsteps = K >> 6;
    int cur = 0;
    for (int t = 0; t < nsteps; ++t) {
        if (t + 1 < nsteps) {
            const int k0n = (t + 1) << 6;
#pragma unroll
            for (int c = 0; c < 4; ++c) {
                gload16(Asrc + (size_t)(c << 6) * K + k0n,
                        &As[cur ^ 1][tid * 8 + (c << 12)]);
                gload16(Bp + boff[c] + k0n,
                        &Bs[cur ^ 1][tid * 8 + (c << 12)]);
            }
        }
#pragma unroll
        for (int ks = 0; ks < 2; ++ks) {
            const int ub = (ks << 2) + lq;                        // 16B unit idx
            const int uo = (ub ^ (lidx & 7)) << 3;                // swizzled elems
            bf16x8 af[8], bfv[4];
#pragma unroll
            for (int i = 0; i < 8; ++i)
                af[i] = *(const bf16x8*)&As[cur][((wm + (i << 4) + lidx) << 6) + uo];
#pragma unroll
            for (int j = 0; j < 4; ++j)
                bfv[j] = *(const bf16x8*)&Bs[cur][((wn + (j << 4) + lidx) << 6) + uo];
#pragma unroll
            for (int mt = 0; mt < 8; ++mt)
#pragma unroll
                for (int nt = 0; nt < 4; ++nt)
                    acc[mt][nt] = __builtin_amdgcn_mfma_f32_16x16x32_bf16(
                        af[mt], bfv[nt], acc[mt][nt], 0, 0, 0);
        }
        __syncthreads();
        cur ^= 1;
    }

    const int rbase = lq << 2;
#pragma unroll
    for (int nt = 0; nt < 4; ++nt) {
        const int col = n0 + wn + (nt << 4) + lidx;
        float s = 0.f, q = 0.f;
#pragma unroll
        for (int mt = 0; mt < 8; ++mt) {
#pragma unroll
            for (int r = 0; r < 4; ++r) {
                float x = acc[mt][nt][r];
                s += x; q += x * x;
                const int row = m0 + wm + (mt << 4) + rbase + r;
                Cb[((size_t)z * Mslice + row) * (size_t)N + col] = bfh(x);
            }
        }
        if (stats != nullptr) {
            s += __shfl_xor(s, 16, 64); s += __shfl_xor(s, 32, 64);
            q += __shfl_xor(q, 16, 64); q += __shfl_xor(q, 32, 64);
            if (lq == 0) {
                atomicAdd(&colsum[wn + (nt << 4) + lidx], s);
                atomicAdd(&colsq [wn + (nt << 4) + lidx], q);
            }
        }
    }
    if (stats != nullptr) {
        __syncthreads();
        if (tid < 256) {
            atomicAdd(&stats[n0 + tid],       colsum[tid]);
            atomicAdd(&stats[512 + n0 + tid], colsq[tid]);
        }
    }
}

// ===== bf16 MFMA GEMM, 64x64 tile, gload_lds + 2-phase (d0,d1,d2) ==========
__global__ __launch_bounds__(256)
void k_b64g(const unsigned short* __restrict__ Abase,
            const unsigned short* __restrict__ Bt,
            unsigned short* __restrict__ Cb,
            const float* __restrict__ bias,
            float* __restrict__ stats,
            int Mslice, int K, int N, int decK)
{
    __shared__ __align__(16) unsigned short As[2][64 * 64];
    __shared__ __align__(16) unsigned short Bs[2][64 * 64];
    __shared__ float colsum[64], colsq[64];

    const int tid  = threadIdx.x;
    const int lane = tid & 63;
    const int wave = tid >> 6;
    const int wm = (wave >> 1) << 5;
    const int wn = (wave & 1) << 5;
    const int z  = blockIdx.z;
    const int n0 = blockIdx.x << 6;
    const int m0 = blockIdx.y << 6;

    if (stats != nullptr && tid < 64) { colsum[tid] = 0.f; colsq[tid] = 0.f; }

    const int a_slice = z / decK, wk = z - a_slice * decK;
    const unsigned short* Ap = Abase + (size_t)a_slice * (size_t)Mslice * (size_t)K;
    const unsigned short* Bp = Bt + (size_t)wk * (size_t)N * (size_t)K;

    const int srow  = tid >> 3;                       // 0..31
    const int selem = ((tid & 7) ^ (srow & 7)) << 3;
    const unsigned short* Asrc = Ap + (size_t)(m0 + srow) * K + selem;
    const unsigned short* Bsrc = Bp + (size_t)(n0 + srow) * K + selem;

    f32x4 acc[2][2];
#pragma unroll
    for (int i = 0; i < 2; ++i)
#pragma unroll
        for (int j = 0; j < 2; ++j) acc[i][j] = (f32x4){0.f, 0.f, 0.f, 0.f};

    const int lidx = lane & 15;
    const int lq   = lane >> 4;

    // ---- prologue: stage chunk 0 into buffer 0 ----
#pragma unroll
    for (int c = 0; c < 2; ++c) {
        gload16(Asrc + (size_t)(c << 5) * K, &As[0][tid * 8 + (c << 11)]);
        gload16(Bsrc + (size_t)(c << 5) * K, &Bs[0][tid * 8 + (c << 11)]);
    }
    __syncthreads();

    const int nsteps = K >> 6;
    int cur = 0;
    for (int t = 0; t < nsteps; ++t) {
        if (t + 1 < nsteps) {
            const int k0n = (t + 1) << 6;
#pragma unroll
            for (int c = 0; c < 2; ++c) {
                gload16(Asrc + (size_t)(c << 5) * K + k0n,
                        &As[cur ^ 1][tid * 8 + (c << 11)]);
                gload16(Bsrc + (size_t)(c << 5) * K + k0n,
                        &Bs[cur ^ 1][tid * 8 + (c << 11)]);
            }
        }
#pragma unroll
        for (int ks = 0; ks < 2; ++ks) {
            const int ub = (ks << 2) + lq;
            const int uo = (ub ^ (lidx & 7)) << 3;
            bf16x8 af[2], bfv[2];
#pragma unroll
            for (int t2 = 0; t2 < 2; ++t2)
                af[t2] = *(const bf16x8*)&As[cur][((wm + (t2 << 4) + lidx) << 6) + uo];
#pragma unroll
            for (int t2 = 0; t2 < 2; ++t2)
                bfv[t2] = *(const bf16x8*)&Bs[cur][((wn + (t2 << 4) + lidx) << 6) + uo];
#pragma unroll
            for (int mt = 0; mt < 2; ++mt)
#pragma unroll
                for (int nt = 0; nt < 2; ++nt)
                    acc[mt][nt] = __builtin_amdgcn_mfma_f32_16x16x32_bf16(
                        af[mt], bfv[nt], acc[mt][nt], 0, 0, 0);
        }
        __syncthreads();
        cur ^= 1;
    }

    const int rbase = lq << 2;
#pragma unroll
    for (int nt = 0; nt < 2; ++nt) {
        const int col = n0 + wn + (nt << 4) + lidx;
        const float badd = (bias != nullptr) ? bias[col] : 0.f;
        float s = 0.f, q = 0.f;
#pragma unroll
        for (int mt = 0; mt < 2; ++mt) {
#pragma unroll
            for (int r = 0; r < 4; ++r) {
                float x = acc[mt][nt][r];
                s += x; q += x * x;
                const int row = m0 + wm + (mt << 4) + rbase + r;
                Cb[((size_t)z * Mslice + row) * (size_t)N + col] = bfh(x + badd);
            }
        }
        if (stats != nullptr) {
            s += __shfl_xor(s, 16, 64); s += __shfl_xor(s, 32, 64);
            q += __shfl_xor(q, 16, 64); q += __shfl_xor(q, 32, 64);
            if (lq == 0) {
                atomicAdd(&colsum[wn + (nt << 4) + lidx], s);
                atomicAdd(&colsq [wn + (nt << 4) + lidx], q);
            }
        }
    }
    if (stats != nullptr) {
        __syncthreads();
        if (tid < 64) {
            atomicAdd(&stats[n0 + tid],       colsum[tid]);
            atomicAdd(&stats[512 + n0 + tid], colsq[tid]);
        }
    }
}

// ===== split-bf16 MFMA GEMM, 64x64 tile, gload_lds + 2-phase (e2,e3) =======
// Linear LDS [2][64][32] bf16 per buffer; XOR-swizzle unit^(row&3).
__global__ __launch_bounds__(256)
void k_sp64g(const unsigned short* __restrict__ Ahg,
             const unsigned short* __restrict__ Alg,
             const unsigned short* __restrict__ Whi,
             const unsigned short* __restrict__ Wlo,
             float* __restrict__ Cout, float* __restrict__ stats,
             int Mslice, int Kp, int N, int n_terms)
{
    __shared__ __align__(16) unsigned short Ah[2][64 * 32];
    __shared__ __align__(16) unsigned short Al[2][64 * 32];
    __shared__ __align__(16) unsigned short Bh[2][64 * 32];
    __shared__ __align__(16) unsigned short Bl[2][64 * 32];
    __shared__ float colsum[64], colsq[64];

    const int tid  = threadIdx.x;
    const int lane = tid & 63;
    const int wave = tid >> 6;
    const int wm = (wave >> 1) << 5;
    const int wn = (wave & 1) << 5;
    const int z  = blockIdx.z;
    const int n0 = blockIdx.x << 6;
    const int m0 = blockIdx.y << 6;

    if (stats != nullptr && tid < 64) { colsum[tid] = 0.f; colsq[tid] = 0.f; }

    const int srow  = tid >> 2;                       // 0..63
    const int selem = ((tid & 3) ^ (srow & 3)) << 3;  // swizzled elem in 32-row

    f32x4 acc[2][2];
#pragma unroll
    for (int i = 0; i < 2; ++i)
#pragma unroll
        for (int j = 0; j < 2; ++j) acc[i][j] = (f32x4){0.f, 0.f, 0.f, 0.f};

    const int lidx = lane & 15;
    const int lq   = lane >> 4;
    const int uo   = (lq ^ (lidx & 3)) << 3;          // swizzled read offset

    const int cpk = Kp >> 5;
    const int tot = n_terms * cpk;

    // ---- prologue: stage chunk 0 (term 0, k 0) into buffer 0 ----
    {
        const size_t ab = ((size_t)(z * n_terms) * Mslice + m0 + srow)
                          * (size_t)Kp + selem;
        const size_t bb = ((size_t)(n0 + srow)) * (size_t)Kp + selem;
        gload16(Ahg + ab, &Ah[0][tid * 8]);
        gload16(Alg + ab, &Al[0][tid * 8]);
        gload16(Whi + bb, &Bh[0][tid * 8]);
        gload16(Wlo + bb, &Bl[0][tid * 8]);
    }
    __syncthreads();

    int cur = 0;
    int lt = 0, lk = 32;
    if (lk >= Kp) { lk = 0; lt = 1; }
    for (int c = 0; c < tot; ++c) {
        if (c + 1 < tot) {
            const size_t ab = ((size_t)(z * n_terms + lt) * Mslice + m0 + srow)
                              * (size_t)Kp + lk + selem;
            const size_t bb = ((size_t)lt * N + n0 + srow) * (size_t)Kp + lk + selem;
            gload16(Ahg + ab, &Ah[cur ^ 1][tid * 8]);
            gload16(Alg + ab, &Al[cur ^ 1][tid * 8]);
            gload16(Whi + bb, &Bh[cur ^ 1][tid * 8]);
            gload16(Wlo + bb, &Bl[cur ^ 1][tid * 8]);
            lk += 32; if (lk >= Kp) { lk = 0; ++lt; }
        }
        bf16x8 ah[2], al[2], bh[2], bl[2];
#pragma unroll
        for (int t = 0; t < 2; ++t) {
            const int ra = ((wm + (t << 4) + lidx) << 5) + uo;
            ah[t] = *(const bf16x8*)&Ah[cur][ra];
            al[t] = *(const bf16x8*)&Al[cur][ra];
        }
#pragma unroll
        for (int t = 0; t < 2; ++t) {
            const int rb = ((wn + (t << 4) + lidx) << 5) + uo;
            bh[t] = *(const bf16x8*)&Bh[cur][rb];
            bl[t] = *(const bf16x8*)&Bl[cur][rb];
        }
#pragma unroll
        for (int mt = 0; mt < 2; ++mt)
#pragma unroll
            for (int nt = 0; nt < 2; ++nt) {
                acc[mt][nt] = __builtin_amdgcn_mfma_f32_16x16x32_bf16(
                    ah[mt], bh[nt], acc[mt][nt], 0, 0, 0);
                acc[mt][nt] = __builtin_amdgcn_mfma_f32_16x16x32_bf16(
                    al[mt], bh[nt], acc[mt][nt], 0, 0, 0);
                acc[mt][nt] = __builtin_amdgcn_mfma_f32_16x16x32_bf16(
                    ah[mt], bl[nt], acc[mt][nt], 0, 0, 0);
            }
        __syncthreads();
        cur ^= 1;
    }

    const int rbase = lq << 2;
#pragma unroll
    for (int nt = 0; nt < 2; ++nt) {
        const int col = n0 + wn + (nt << 4) + lidx;
        float s = 0.f, q = 0.f;
#pragma unroll
        for (int mt = 0; mt < 2; ++mt) {
#pragma unroll
            for (int r = 0; r < 4; ++r) {
                float x = acc[mt][nt][r];
                s += x; q += x * x;
                const int row = m0 + wm + (mt << 4) + rbase + r;
                Cout[((size_t)z * Mslice + row) * (size_t)N + col] = x;
            }
        }
        if (stats != nullptr) {
            s += __shfl_xor(s, 16, 64); s += __shfl_xor(s, 32, 64);
            q += __shfl_xor(q, 16, 64); q += __shfl_xor(q, 32, 64);
            if (lq == 0) {
                atomicAdd(&colsum[wn + (nt << 4) + lidx], s);
                atomicAdd(&colsq [wn + (nt << 4) + lidx], q);
            }
        }
    }
    if (stats != nullptr) {
        __syncthreads();
        if (tid < 64) {
            atomicAdd(&stats[n0 + tid],       colsum[tid]);
            atomicAdd(&stats[512 + n0 + tid], colsq[tid]);
        }
    }
}

// ===== split-bf16 MFMA GEMM, 64x128 tile, gload_lds + 2-phase (e1) =========
// 4 waves (2m x 2n), per-wave 32x64, acc[2][4]. LDS: Ah/Al [2][64*32],
// Bh/Bl [2][128*32] (49 KB total). B staged as 2x64-row sub-chunks at elem
// offset c<<11. Swizzle parity (row&3) preserved -> bit-identical chains.
__global__ __launch_bounds__(256)
void k_sp64w(const unsigned short* __restrict__ Ahg,
             const unsigned short* __restrict__ Alg,
             const unsigned short* __restrict__ Whi,
             const unsigned short* __restrict__ Wlo,
             float* __restrict__ Cout, float* __restrict__ stats,
             int Mslice, int Kp, int N, int n_terms)
{
    __shared__ __align__(16) unsigned short Ah[2][64 * 32];
    __shared__ __align__(16) unsigned short Al[2][64 * 32];
    __shared__ __align__(16) unsigned short Bh[2][128 * 32];
    __shared__ __align__(16) unsigned short Bl[2][128 * 32];
    __shared__ float colsum[128], colsq[128];

    const int tid  = threadIdx.x;
    const int lane = tid & 63;
    const int wave = tid >> 6;          // 0..3
    const int wm = (wave >> 1) << 5;    // 0, 32
    const int wn = (wave & 1) << 6;     // 0, 64
    const int z  = blockIdx.z;
    const int n0 = blockIdx.x << 7;     // 4 n-blocks x 128
    const int m0 = blockIdx.y << 6;     // 16 m-blocks x 64

    if (stats != nullptr && tid < 128) { colsum[tid] = 0.f; colsq[tid] = 0.f; }

    const int srow  = tid >> 2;                       // 0..63
    const int selem = ((tid & 3) ^ (srow & 3)) << 3;  // swizzled elem in 32-row

    f32x4 acc[2][4];
#pragma unroll
    for (int i = 0; i < 2; ++i)
#pragma unroll
        for (int j = 0; j < 4; ++j) acc[i][j] = (f32x4){0.f, 0.f, 0.f, 0.f};

    const int lidx = lane & 15;
    const int lq   = lane >> 4;
    const int uo   = (lq ^ (lidx & 3)) << 3;          // swizzled read offset

    const int cpk = Kp >> 5;
    const int tot = n_terms * cpk;

    // ---- prologue: stage chunk 0 (term 0, k 0) into buffer 0 ----
    {
        const size_t ab = ((size_t)(z * n_terms) * Mslice + m0 + srow)
                          * (size_t)Kp + selem;
        gload16(Ahg + ab, &Ah[0][tid * 8]);
        gload16(Alg + ab, &Al[0][tid * 8]);
#pragma unroll
        for (int c = 0; c < 2; ++c) {
            const int rowB = (c << 6) + srow;
            const size_t bb = ((size_t)(n0 + rowB)) * (size_t)Kp + selem;
            gload16(Whi + bb, &Bh[0][tid * 8 + (c << 11)]);
            gload16(Wlo + bb, &Bl[0][tid * 8 + (c << 11)]);
        }
    }
    __syncthreads();

    int cur = 0;
    int lt = 0, lk = 32;
    if (lk >= Kp) { lk = 0; lt = 1; }
    for (int c = 0; c < tot; ++c) {
        if (c + 1 < tot) {
            const size_t ab = ((size_t)(z * n_terms + lt) * Mslice + m0 + srow)
                              * (size_t)Kp + lk + selem;
            gload16(Ahg + ab, &Ah[cur ^ 1][tid * 8]);
            gload16(Alg + ab, &Al[cur ^ 1][tid * 8]);
#pragma unroll
            for (int cc = 0; cc < 2; ++cc) {
                const int rowB = (cc << 6) + srow;
                const size_t bb = ((size_t)lt * N + n0 + rowB) * (size_t)Kp
                                  + lk + selem;
                gload16(Whi + bb, &Bh[cur ^ 1][tid * 8 + (cc << 11)]);
                gload16(Wlo + bb, &Bl[cur ^ 1][tid * 8 + (cc << 11)]);
            }
            lk += 32; if (lk >= Kp) { lk = 0; ++lt; }
        }
        bf16x8 ah[2], al[2], bh[4], bl[4];
#pragma unroll
        for (int t = 0; t < 2; ++t) {
            const int ra = ((wm + (t << 4) + lidx) << 5) + uo;
            ah[t] = *(const bf16x8*)&Ah[cur][ra];
            al[t] = *(const bf16x8*)&Al[cur][ra];
        }
#pragma unroll
        for (int t = 0; t < 4; ++t) {
            const int rb = ((wn + (t << 4) + lidx) << 5) + uo;
            bh[t] = *(const bf16x8*)&Bh[cur][rb];
            bl[t] = *(const bf16x8*)&Bl[cur][rb];
        }
#pragma unroll
        for (int mt = 0; mt < 2; ++mt)
#pragma unroll
            for (int nt = 0; nt < 4; ++nt) {
                acc[mt][nt] = __builtin_amdgcn_mfma_f32_16x16x32_bf16(
                    ah[mt], bh[nt], acc[mt][nt], 0, 0, 0);
                acc[mt][nt] = __builtin_amdgcn_mfma_f32_16x16x32_bf16(
                    al[mt], bh[nt], acc[mt][nt], 0, 0, 0);
                acc[mt][nt] = __builtin_amdgcn_mfma_f32_16x16x32_bf16(
                    ah[mt], bl[nt], acc[mt][nt], 0, 0, 0);
            }
        __syncthreads();
        cur ^= 1;
    }

    const int rbase = lq << 2;
#pragma unroll
    for (int nt = 0; nt < 4; ++nt) {
        const int col = n0 + wn + (nt << 4) + lidx;
        float s = 0.f, q = 0.f;
#pragma unroll
        for (int mt = 0; mt < 2; ++mt) {
#pragma unroll
            for (int r = 0; r < 4; ++r) {
                float x = acc[mt][nt][r];
                s += x; q += x * x;
                const int row = m0 + wm + (mt << 4) + rbase + r;
                Cout[((size_t)z * Mslice + row) * (size_t)N + col] = x;
            }
        }
        if (stats != nullptr) {
            s += __shfl_xor(s, 16, 64); s += __shfl_xor(s, 32, 64);
            q += __shfl_xor(q, 16, 64); q += __shfl_xor(q, 32, 64);
            if (lq == 0) {
                atomicAdd(&colsum[wn + (nt << 4) + lidx], s);
                atomicAdd(&colsq [wn + (nt << 4) + lidx], q);
            }
        }
    }
    if (stats != nullptr) {
        __syncthreads();
        if (tid < 128) {
            atomicAdd(&stats[n0 + tid],       colsum[tid]);
            atomicAdd(&stats[512 + n0 + tid], colsq[tid]);
        }
    }
}

// ======== merged prep kernel (10 independent preps, incl. sp_weff) =========
__global__ void k_prep(float* __restrict__ zbase, unsigned long long* __restrict__ amin,
                       const float* __restrict__ codebook, float* __restrict__ codeT,
                       float* __restrict__ codesq,
                       const float* __restrict__ w_e2, unsigned short* __restrict__ whi_e2,
                       unsigned short* __restrict__ wlo_e2,
                       const float* __restrict__ w_e3, unsigned short* __restrict__ whi_e3,
                       unsigned short* __restrict__ wlo_e3,
                       const float* __restrict__ W_q,  unsigned short* __restrict__ wqb,
                       const float* __restrict__ w_d1, unsigned short* __restrict__ wd1b,
                       const float* __restrict__ w_d2, unsigned short* __restrict__ wd2b,
                       const float* __restrict__ w_d3, unsigned short* __restrict__ wd3b,
                       const float* __restrict__ W_out, unsigned short* __restrict__ woutb,
                       const float* __restrict__ in_seqs,
                       unsigned short* __restrict__ in_h, unsigned short* __restrict__ in_l,
                       const float* __restrict__ weff,
                       unsigned short* __restrict__ whi_e1,
                       unsigned short* __restrict__ wlo_e1)
{
    __shared__ float red[4];
    const int bid = blockIdx.x;
    const int tid = threadIdx.x;

    if (bid < 32) {                                    // s0: init
        int t = bid * 256 + tid;
        if (t < 6720) zbase[t] = 0.f;
        if (t < 1024) amin[t] = ~0ULL;
        return;
    }
    if (bid < 1056) {                                  // s1: codeT repack (Kc=1)
        int idx = (bid - 32) * 256 + tid;
        int i = (idx >> 9) & 511, o = idx & 511;
        codeT[idx] = codebook[(o << 9) + i];
        return;
    }
    if (bid < 1568) {                                  // s2: codesq
        int c = bid - 1056;
        float s = 0.f;
        for (int i = tid; i < 512; i += 256) { float v = codebook[c * 512 + i]; s += v * v; }
        for (int off = 32; off; off >>= 1) s += __shfl_down(s, off, 64);
        if ((tid & 63) == 0) red[tid >> 6] = s;
        __syncthreads();
        if (tid == 0) codesq[c] = red[0] + red[1] + red[2] + red[3];
        return;
    }
    if (bid < 4640) {                                  // s3: split e2 (Kc=3)
        int idx = (bid - 1568) * 256 + tid;
        int i = idx & 511, o = (idx >> 9) & 511, k = idx >> 18;
        float v = w_e2[(((o << 9) + i) * 3) + k];
        unsigned short h = bfh(v);
        whi_e2[idx] = h; wlo_e2[idx] = bfh(v - bf2f(h));
        return;
    }
    if (bid < 6688) {                                  // s4: split e3 (Kc=2)
        int idx = (bid - 4640) * 256 + tid;
        int i = idx & 511, o = (idx >> 9) & 511, k = idx >> 18;
        float v = w_e3[(((o << 9) + i) * 2) + k];
        unsigned short h = bfh(v);
        whi_e3[idx] = h; wlo_e3[idx] = bfh(v - bf2f(h));
        return;
    }
    if (bid < 7712) {                                  // s5: W_q bf (Kc=1,I=O=512)
        int idx = (bid - 6688) * 256 + tid;
        int i = idx & 511, o = (idx >> 9) & 511;
        wqb[idx] = bfh(W_q[((size_t)i << 9) + o]);
        return;
    }
    if (bid < 9760) {                                  // s6: w_d1 bf (Kc=2)
        int idx = (bid - 7712) * 256 + tid;
        int i = idx & 511, o = (idx >> 9) & 511, k = idx >> 18;
        wd1b[idx] = bfh(w_d1[(((size_t)i << 9) + o) * 2 + k]);
        return;
    }
    if (bid < 12832) {                                 // s7: w_d2 bf (Kc=3)
        int idx = (bid - 9760) * 256 + tid;
        int i = idx & 511, o = (idx >> 9) & 511, k = idx >> 18;
        wd2b[idx] = bfh(w_d2[(((size_t)i << 9) + o) * 3 + k]);
        return;
    }
    if (bid < 17952) {                                 // s8: w_d3 bf (Kc=5)
        int idx = (bid - 12832) * 256 + tid;
        int i = idx & 511, o = (idx >> 9) & 511, k = idx >> 18;
        wd3b[idx] = bfh(w_d3[(((size_t)i << 9) + o) * 5 + k]);
        return;
    }
    if (bid < 18222) {                                 // s9: W_out bf (Kc=1,I=512,O=135)
        int idx = (bid - 17952) * 256 + tid;
        if (idx >= 69120) return;
        int i = idx % 512, o = idx / 512;              // [o][i], o<135
        woutb[idx] = bfh(W_out[((size_t)i * 135) + o]);
        return;
    }
    if (bid < 37422) {                                 // s10: split_in
        int idx = (bid - 18222) * 256 + tid;
        int i = idx % 160, r = idx / 160;
        float v = (i < 135) ? in_seqs[(size_t)r * 135 + i] : 0.f;
        unsigned short h = bfh(v);
        in_h[idx] = h; in_l[idx] = bfh(v - bf2f(h));
        return;
    }
    {                                                  // s11: sp_weff
        int idx = (bid - 37422) * 256 + tid;
        if (idx >= 409600) return;
        int i = idx % 160;
        int o = (idx / 160) & 511;
        int t = idx / 81920;
        float v = (i < 135) ? weff[((size_t)t * 135 + i) * 512 + o] : 0.f;
        unsigned short h = bfh(v);
        whi_e1[idx] = h;
        wlo_e1[idx] = bfh(v - bf2f(h));
    }
}

// ============================ small kernels ================================
__global__ void k_repack(const float* __restrict__ w, float* __restrict__ wt,
                         int Kc, int total)
{
    int idx = blockIdx.x * 256 + threadIdx.x;
    if (idx >= total) return;
    int k = idx >> 18;
    int rem = idx & 262143;
    int i = rem >> 9, o = rem & 511;
    wt[idx] = w[(((o << 9) + i) * Kc + k)];
}

// BN-finalize fused: compute sc/sh in LDS (identical math), split to hi/lo
__global__ void k_bnsplit(const float* __restrict__ x,
                          const float* __restrict__ stats,
                          const float* __restrict__ g, const float* __restrict__ b,
                          float inv_n,
                          unsigned short* __restrict__ hq, unsigned short* __restrict__ lq_,
                          int total4)
{
    __shared__ __align__(16) float scs[512], shs[512];
    const int tid = threadIdx.x;
    bn_fin_lds(stats, g, b, inv_n, scs, shs, tid);
    __syncthreads();

    int idx = blockIdx.x * 256 + tid;
    if (idx >= total4) return;
    const int base = idx << 2;
    float4 f = *(const float4*)(x + base);
    const int k = base & 511;
    float4 s = *(const float4*)&scs[k];
    float4 c = *(const float4*)&shs[k];
    float y0 = fmaxf(fmaf(f.x, s.x, c.x), 0.f);
    float y1 = fmaxf(fmaf(f.y, s.y, c.y), 0.f);
    float y2 = fmaxf(fmaf(f.z, s.z, c.z), 0.f);
    float y3 = fmaxf(fmaf(f.w, s.w, c.w), 0.f);
    unsigned short h0 = bfh(y0), h1 = bfh(y1), h2 = bfh(y2), h3 = bfh(y3);
    unsigned short l0 = bfh(y0 - bf2f(h0)), l1 = bfh(y1 - bf2f(h1));
    unsigned short l2 = bfh(y2 - bf2f(h2)), l3 = bfh(y3 - bf2f(h3));
    *(uint2*)&hq[base]  = make_uint2((unsigned)h0 | ((unsigned)h1 << 16),
                                     (unsigned)h2 | ((unsigned)h3 << 16));
    *(uint2*)&lq_[base] = make_uint2((unsigned)l0 | ((unsigned)l1 << 16),
                                     (unsigned)l2 | ((unsigned)l3 << 16));
}

// BN-finalize fused: compute sc/sh in LDS, apply BN+ReLU, emit bf16
__global__ void k_bnapply(const unsigned short* __restrict__ x,
                          const float* __restrict__ stats,
                          const float* __restrict__ g, const float* __restrict__ b,
                          float inv_n,
                          unsigned short* __restrict__ y, int total8)
{
    __shared__ __align__(16) float scs[512], shs[512];
    const int tid = threadIdx.x;
    bn_fin_lds(stats, g, b, inv_n, scs, shs, tid);
    __syncthreads();

    int idx = blockIdx.x * 256 + tid;
    if (idx >= total8) return;
    const int base = idx << 3;
    uint4 raw = *(const uint4*)(x + base);
    const int k = base & 511;
    float4 s0 = *(const float4*)&scs[k];
    float4 c0 = *(const float4*)&shs[k];
    float4 s1 = *(const float4*)&scs[k + 4];
    float4 c1 = *(const float4*)&shs[k + 4];
    unsigned* u = (unsigned*)&raw;
    float x0 = __uint_as_float(u[0] << 16),        x1 = __uint_as_float(u[0] & 0xffff0000u);
    float x2 = __uint_as_float(u[1] << 16),        x3 = __uint_as_float(u[1] & 0xffff0000u);
    float x4 = __uint_as_float(u[2] << 16),        x5 = __uint_as_float(u[2] & 0xffff0000u);
    float x6 = __uint_as_float(u[3] << 16),        x7 = __uint_as_float(u[3] & 0xffff0000u);
    x0 = fmaxf(fmaf(x0, s0.x, c0.x), 0.f); x1 = fmaxf(fmaf(x1, s0.y, c0.y), 0.f);
    x2 = fmaxf(fmaf(x2, s0.z, c0.z), 0.f); x3 = fmaxf(fmaf(x3, s0.w, c0.w), 0.f);
    x4 = fmaxf(fmaf(x4, s1.x, c1.x), 0.f); x5 = fmaxf(fmaf(x5, s1.y, c1.y), 0.f);
    x6 = fmaxf(fmaf(x6, s1.z, c1.z), 0.f); x7 = fmaxf(fmaf(x7, s1.w, c1.w), 0.f);
    *(uint4*)&y[base] = make_uint4(pk_bf16(x0, x1), pk_bf16(x2, x3),
                                   pk_bf16(x4, x5), pk_bf16(x6, x7));
}

__global__ void k_bn_fin(const float* __restrict__ stats,
                         const float* __restrict__ g, const float* __restrict__ b,
                         float* __restrict__ sc, float* __restrict__ sh, float inv_n)
{
    int c = blockIdx.x * blockDim.x + threadIdx.x;
    if (c >= 512) return;
    float m = stats[c] * inv_n;
    float v = stats[512 + c] * inv_n - m * m;
    float a = (float)((double)g[c] / sqrt((double)v + 1e-5));
    sc[c] = a;
    sh[c] = b[c] - m * a;
}

__global__ void k_vq_gather(const unsigned long long* __restrict__ amin,
                            const float* __restrict__ codebook,
                            const float* __restrict__ e3pre,
                            const float* __restrict__ sc, const float* __restrict__ sh,
                            unsigned short* __restrict__ quant_bf,
                            float* __restrict__ loss,
                            unsigned int* __restrict__ hist)
{
    int b = blockIdx.x; int t = threadIdx.x;   // 256 threads
    unsigned int idx = (unsigned int)(amin[b] & 0xFFFFFFFFull) & 511u;
    float part = 0.f;
    for (int i = t; i < 512; i += 256) {
        float q = codebook[(size_t)idx * 512 + i];
        quant_bf[(size_t)b * 512 + i] = bfh(q);
        float x = e3pre[(size_t)b * 512 + i];
        float f = fmaxf(fmaf(x, sc[i], sh[i]), 0.f);
        float d = q - f;
        part += d * d;
    }
    for (int off = 32; off; off >>= 1) part += __shfl_down(part, off, 64);
    __shared__ float red[4];
    if ((t & 63) == 0) red[t >> 6] = part;
    __syncthreads();
    if (t == 0) {
        atomicAdd(loss, red[0] + red[1] + red[2] + red[3]);
        atomicAdd(&hist[idx], 1u);
    }
}

__global__ void k_scalars(const unsigned int* __restrict__ hist,
                          const float* __restrict__ loss, float* __restrict__ out)
{
    int t = threadIdx.x;   // 512
    float p = (float)hist[t] * (1.0f / 1024.0f);
    float e = p * logf(p + 1e-10f);
    for (int off = 32; off; off >>= 1) e += __shfl_down(e, off, 64);
    __shared__ float red[8];
    if ((t & 63) == 0) red[t >> 6] = e;
    __syncthreads();
    if (t == 0) {
        float s = 0.f;
        for (int i = 0; i < 8; ++i) s += red[i];
        out[4147200] = 1.25f * loss[0] * (1.0f / 524288.0f);
        out[4147201] = expf(-s);
    }
}

extern "C" void kernel_launch(void* const* d_in, const int* in_sizes, int n_in,
                              void* d_out, int out_size, void* d_ws, size_t ws_size,
                              hipStream_t stream)
{
    const float* in_seqs = (const float*)d_in[0];
    const float* W_in  = (const float*)d_in[1];
    const float* w_e1  = (const float*)d_in[3];
    const float* g_e1  = (const float*)d_in[4];
    const float* be1   = (const float*)d_in[5];
    const float* w_e2  = (const float*)d_in[6];
    const float* g_e2  = (const float*)d_in[7];
    const float* be2   = (const float*)d_in[8];
    const float* w_e3  = (const float*)d_in[9];
    const float* g_e3  = (const float*)d_in[10];
    const float* be3   = (const float*)d_in[11];
    const float* codebook = (const float*)d_in[12];
    const float* W_q   = (const float*)d_in[13];
    const float* b_q   = (const float*)d_in[14];
    const float* w_d1  = (const float*)d_in[15];
    const float* g_d1  = (const float*)d_in[16];
    const float* bd1   = (const float*)d_in[17];
    const float* w_d2  = (const float*)d_in[18];
    const float* g_d2  = (const float*)d_in[19];
    const float* bd2   = (const float*)d_in[20];
    const float* w_d3  = (const float*)d_in[21];
    const float* g_d3  = (const float*)d_in[22];
    const float* bd3   = (const float*)d_in[23];
    const float* W_out = (const float*)d_in[24];
    const float* b_out = (const float*)d_in[25];
    float* out = (float*)d_out;

    // ---- workspace layout (float offsets) ----
    float* W = (float*)d_ws;
    unsigned long long* amin = (unsigned long long*)W;            // 2048 f
    float* stats  = W + 2048;                                     // 6144
    float* lossp  = W + 8192;                                     // 64
    unsigned int* hist = (unsigned int*)(W + 8256);               // 512
    float* scsh   = W + 8768;                                     // 6144
    float* codesq = W + 14912;                                    // 512
    float* wt_e1  = W + 15424;                                    // 1310720 f
    float* codeT  = W + 1671744;                                  // 262144 f
    unsigned short* esw = (unsigned short*)(W + 1933888);         // 3440640 ush
    unsigned short* whi_e1 = esw;
    unsigned short* wlo_e1 = esw + 409600;
    unsigned short* whi_e2 = esw + 819200;
    unsigned short* wlo_e2 = esw + 1605632;
    unsigned short* whi_e3 = esw + 2392064;
    unsigned short* wlo_e3 = esw + 2916352;
    unsigned short* in_h  = (unsigned short*)(W + 3654208);       // 4915200 ush
    unsigned short* in_l  = in_h + 4915200;
    unsigned short* d3pre = (unsigned short*)(W + 3654208);       // 15728640 ush
    float* e1f = W + 11518528;                                    // 3145728 f
    unsigned short* e1h = (unsigned short*)(W + 14664256);        // 3145728 ush
    unsigned short* e1l = e1h + 3145728;
    float* e2f = W + 17809984;                                    // 1048576 f
    unsigned short* e2h = (unsigned short*)(W + 18858560);        // 1048576 ush
    unsigned short* e2l = e2h + 1048576;
    unsigned short* d2pre = (unsigned short*)(W + 17809984);      // 3145728 ush
    unsigned short* d2bf  = d2pre + 3145728;                      // 3145728 ush
    float* e3f = W + 20955712;                                    // 524288 f
    unsigned short* quant_bf = (unsigned short*)(W + 21480000);   // 524288 ush
    unsigned short* d0bf     = (unsigned short*)(W + 21742144);   // 524288 ush
    unsigned short* d1pre    = (unsigned short*)(W + 22004288);   // 1048576 ush
    unsigned short* d1bf     = (unsigned short*)(W + 22528640);   // 1048576 ush
    unsigned short* d3bf     = (unsigned short*)(W + 23052928);   // 15728640 ush
    float* weff   = W + 30917248;                                 // 345600 f
    // weff ends at 31262848 floats (~125 MB) < 256 MiB ws; no aliasing.

    unsigned short* db    = (unsigned short*)wt_e1;
    unsigned short* wqb   = db;
    unsigned short* wd1b  = db + 262144;
    unsigned short* wd2b  = db + 786432;
    unsigned short* wd3b  = db + 1572864;
    unsigned short* woutb = db + 2883584;

    float* st_e1 = stats + 0 * 1024;
    float* st_e2 = stats + 1 * 1024;
    float* st_e3 = stats + 2 * 1024; float* sc_e3 = scsh + 2 * 1024; float* sh_e3 = sc_e3 + 512;
    float* st_d1 = stats + 3 * 1024;
    float* st_d2 = stats + 4 * 1024;
    float* st_d3 = stats + 5 * 1024;

    dim3 blk(256);

    // order: wt_e1 fp32 repack -> weff gemm -> k_prep (contains sp_weff s11;
    // weff is in a non-aliased region so s11 is race-free vs s8/s9).
    k_repack<<<dim3(5 * 1024), blk, 0, stream>>>(w_e1, wt_e1, 5, 5 * 262144);
    k_gemm<<<dim3(16, 5, 5), blk, 0, stream>>>(W_in, wt_e1, weff,
        nullptr, nullptr, nullptr, nullptr, 135, 512, 512, 5);

    k_prep<<<dim3(39022), blk, 0, stream>>>(stats, amin,
        codebook, codeT, codesq,
        w_e2, whi_e2, wlo_e2, w_e3, whi_e3, wlo_e3,
        W_q, wqb, w_d1, wd1b, w_d2, wd2b, w_d3, wd3b, W_out, woutb,
        in_seqs, in_h, in_l, weff, whi_e1, wlo_e1);

    // ---- encoder: e1 = 64x128 tile (k_sp64w, 384 blk); e2/e3 = 64x64 ----
    k_sp64w<<<dim3(4, 16, 6), blk, 0, stream>>>(in_h, in_l, whi_e1, wlo_e1,
        e1f, st_e1, 1024, 160, 512, 5);
    k_bnsplit<<<dim3(3072), blk, 0, stream>>>(e1f, st_e1, g_e1, be1,
        1.f / 6144.f, e1h, e1l, 786432);

    k_sp64g<<<dim3(8, 16, 2), blk, 0, stream>>>(e1h, e1l, whi_e2, wlo_e2,
        e2f, st_e2, 1024, 512, 512, 3);
    k_bnsplit<<<dim3(1024), blk, 0, stream>>>(e2f, st_e2, g_e2, be2,
        1.f / 2048.f, e2h, e2l, 262144);

    k_sp64g<<<dim3(8, 16, 1), blk, 0, stream>>>(e2h, e2l, whi_e3, wlo_e3,
        e3f, st_e3, 1024, 512, 512, 2);
    k_bn_fin<<<dim3(2), blk, 0, stream>>>(st_e3, g_e3, be3, sc_e3, sh_e3, 1.f / 1024.f);

    // ---- VQ: fp32 dist GEMM + argmin (32x32 tiles, 512 blocks) ----
    k_gemm<<<dim3(16, 32, 1), blk, 0, stream>>>(e3f, codeT, nullptr,
        sc_e3, sh_e3, amin, codesq, 1024, 512, 512, 1);
    k_vq_gather<<<dim3(1024), blk, 0, stream>>>(amin, codebook, e3f, sc_e3, sh_e3,
                                                quant_bf, lossp, hist);

    // ---- decoder: all gload_lds 2-phase; BN fused into bnapply ----
    k_b64g<<<dim3(8, 16, 1), blk, 0, stream>>>(quant_bf, wqb, d0bf,
        b_q, nullptr, 1024, 512, 512, 1);

    k_b64g<<<dim3(8, 16, 2), blk, 0, stream>>>(d0bf, wd1b, d1pre,
        nullptr, st_d1, 1024, 512, 512, 2);
    k_bnapply<<<dim3(512), blk, 0, stream>>>(d1pre, st_d1, g_d1, bd1,
        1.f / 2048.f, d1bf, 131072);

    k_b64g<<<dim3(8, 16, 6), blk, 0, stream>>>(d1bf, wd2b, d2pre,
        nullptr, st_d2, 1024, 512, 512, 3);
    k_bnapply<<<dim3(1536), blk, 0, stream>>>(d2pre, st_d2, g_d2, bd2,
        1.f / 6144.f, d2bf, 393216);

    // d3: 256x256 tiles, gload_lds 2-phase, 512 threads (240 blocks)
    k_m256<<<dim3(2, 4, 30), dim3(512), 0, stream>>>(d2bf, wd3b, d3pre,
        st_d3, 1024, 512, 512, 5);
    k_bnapply<<<dim3(7680), blk, 0, stream>>>(d3pre, st_d3, g_d3, bd3,
        1.f / 30720.f, d3bf, 1966080);

    // out-proj: 128x128 gload_lds 2-phase, operm store, N=135 (B rows clamped)
    k_mfma_g<<<dim3(2, 240, 1), blk, 0, stream>>>(d3bf, woutb, nullptr,
        out, b_out, nullptr, 30720, 512, 135, 1);

    k_scalars<<<dim3(1), dim3(512), 0, stream>>>(hist, lossp, out);
}

// Round 15
// 407.296 us; speedup vs baseline: 1.0877x; 1.0028x over previous
//
#include <hip/hip_runtime.h>
#include <math.h>

// ---------------------------------------------------------------------------
// VQ-VAE forward (round 26 = round 25 + out-proj retiled M128xN256).
//  - Round-25 base (408.4us best): gload_lds 2-phase, bn_fin fused, sp_weff
//    in k_prep (weff relocated), e1 = k_sp64w 64x128.
//  - NEW: k_out256 replaces k_mfma_g for the out-projection. One 128x256
//    tile (512 thr, 8 waves 2m x 4n, acc[4][4], LDS 96KB -> 2 waves/SIMD,
//    grid (1,240)). A (d3bf) staged ONCE (63->31.5 MB); B rows clamped to
//    N-1; cols >=135 discarded by store guard. Staging follows the verified
//    k_m256 pattern (chunks at c<<12, same XOR swizzle) -> bit-identical
//    MFMA chains. k_mfma_g removed (dead).
// ---------------------------------------------------------------------------

typedef __attribute__((ext_vector_type(8))) short bf16x8;
typedef __attribute__((ext_vector_type(4))) float f32x4;

__device__ __forceinline__ unsigned pk_bf16(float a, float b) {
    unsigned ua = __float_as_uint(a), ub = __float_as_uint(b);
    ua += 0x7fffu + ((ua >> 16) & 1u);          // RNE
    ub += 0x7fffu + ((ub >> 16) & 1u);
    return (ua >> 16) | (ub & 0xffff0000u);
}
__device__ __forceinline__ unsigned short bfh(float x) {
    unsigned u = __float_as_uint(x);
    u += 0x7fffu + ((u >> 16) & 1u);
    return (unsigned short)(u >> 16);
}
__device__ __forceinline__ float bf2f(unsigned short h) {
    return __uint_as_float(((unsigned)h) << 16);
}

// async global->LDS DMA, 16 B per lane (global_load_lds_dwordx4)
__device__ __forceinline__ void gload16(const unsigned short* g, unsigned short* l) {
    __builtin_amdgcn_global_load_lds(
        (const __attribute__((address_space(1))) unsigned int*)g,
        (__attribute__((address_space(3))) unsigned int*)l, 16, 0, 0);
}

__device__ __forceinline__ void bn4(float4& a, const float* __restrict__ s,
                                    const float* __restrict__ c) {
    float4 sv = *(const float4*)s;
    float4 cv = *(const float4*)c;
    a.x = fmaxf(fmaf(a.x, sv.x, cv.x), 0.f);
    a.y = fmaxf(fmaf(a.y, sv.y, cv.y), 0.f);
    a.z = fmaxf(fmaf(a.z, sv.z, cv.z), 0.f);
    a.w = fmaxf(fmaf(a.w, sv.w, cv.w), 0.f);
}

// shared helper: compute sc/sh for 512 channels into LDS (identical math to
// k_bn_fin; deterministic -> bit-identical wherever applied)
__device__ __forceinline__ void bn_fin_lds(const float* __restrict__ stats,
                                           const float* __restrict__ g,
                                           const float* __restrict__ b,
                                           float inv_n,
                                           float* scs, float* shs, int tid) {
    for (int c = tid; c < 512; c += 256) {
        float m = stats[c] * inv_n;
        float v = stats[512 + c] * inv_n - m * m;
        float a = (float)((double)g[c] / sqrt((double)v + 1e-5));
        scs[c] = a;
        shs[c] = b[c] - m * a;
    }
}

// ======================= fp32 GEMM (weff + VQ dist) ========================
#define FBK  32
#define FSTR 36

__global__ __launch_bounds__(256)
void k_gemm(const float* __restrict__ Abase,
            const float* __restrict__ Wt,
            float* __restrict__ Cout,
            const float* __restrict__ bnS, const float* __restrict__ bnB,
            unsigned long long* __restrict__ amin,
            const float* __restrict__ codesq,
            int Mslice, int K, int N, int decK)
{
    __shared__ __align__(16) float As[FBK][FSTR];
    __shared__ __align__(16) float Bs[FBK][FSTR];

    const int tid = threadIdx.x;
    const int z  = blockIdx.z;
    const int n0 = blockIdx.x << 5;
    const int m0 = blockIdx.y << 5;
    const int ty = tid >> 4;          // 0..15  (m pairs)
    const int tx = tid & 15;          // 0..15  (n pairs)

    const int a_slice = z / decK, wk = z - a_slice * decK;
    const float* Ap = Abase + (size_t)a_slice * (size_t)Mslice * (size_t)K;
    const float* Wp = Wt    + (size_t)wk * (size_t)K * (size_t)N;

    const int sr  = tid >> 3;         // 0..31
    const int sc4 = (tid & 7) << 2;   // 0..28

    int mrow = m0 + sr;
    if (mrow > Mslice - 1) mrow = Mslice - 1;
    const float* Arow_p = Ap + (size_t)mrow * K;

    float acc[2][2];
    acc[0][0] = 0.f; acc[0][1] = 0.f; acc[1][0] = 0.f; acc[1][1] = 0.f;

    // ---- prefetch chunk 0 ----
    float4 pa = *(const float4*)(Arow_p + sc4);
    if (bnS != nullptr) bn4(pa, bnS + sc4, bnB + sc4);
    float4 pb = *(const float4*)(Wp + (size_t)sr * N + n0 + sc4);

    for (int k0 = 0; k0 < K; k0 += FBK) {
        __syncthreads();
        As[sc4 + 0][sr] = pa.x;
        As[sc4 + 1][sr] = pa.y;
        As[sc4 + 2][sr] = pa.z;
        As[sc4 + 3][sr] = pa.w;
        *(float4*)&Bs[sr][sc4] = pb;
        const int k0n = k0 + FBK;
        if (k0n < K) {
            pa = *(const float4*)(Arow_p + k0n + sc4);
            if (bnS != nullptr) bn4(pa, bnS + k0n + sc4, bnB + k0n + sc4);
            pb = *(const float4*)(Wp + (size_t)(k0n + sr) * N + n0 + sc4);
        }
        __syncthreads();
#pragma unroll
        for (int kk = 0; kk < FBK; ++kk) {
            float2 av = *(const float2*)&As[kk][ty << 1];
            float2 bv = *(const float2*)&Bs[kk][tx << 1];
            acc[0][0] = fmaf(av.x, bv.x, acc[0][0]);
            acc[0][1] = fmaf(av.x, bv.y, acc[0][1]);
            acc[1][0] = fmaf(av.y, bv.x, acc[1][0]);
            acc[1][1] = fmaf(av.y, bv.y, acc[1][1]);
        }
    }

    if (amin != nullptr) {
        float2 cq = *(const float2*)(codesq + n0 + (tx << 1));
#pragma unroll
        for (int i = 0; i < 2; ++i) {
            const int m = m0 + (ty << 1) + i;
            float d0 = cq.x - 2.f * acc[i][0];
            float d1 = cq.y - 2.f * acc[i][1];
            int bj = (d1 < d0) ? 1 : 0;
            float best = (d1 < d0) ? d1 : d0;
            unsigned u = __float_as_uint(best);
            u = (u & 0x80000000u) ? ~u : (u | 0x80000000u);
            unsigned long long key =
                ((unsigned long long)u << 32) | (unsigned)(n0 + (tx << 1) + bj);
#pragma unroll
            for (int off = 1; off < 16; off <<= 1) {
                unsigned long long o = __shfl_xor(key, off, 64);
                if (o < key) key = o;
            }
            if (tx == 0 && m < Mslice) atomicMin(&amin[m], key);
        }
        return;
    }

#pragma unroll
    for (int i = 0; i < 2; ++i) {
        const int m = m0 + (ty << 1) + i;
        if (m < Mslice) {
            float2 v = make_float2(acc[i][0], acc[i][1]);
            *(float2*)&Cout[((size_t)z * Mslice + m) * N + n0 + (tx << 1)] = v;
        }
    }
}

// ===== bf16 MFMA GEMM, 128x256 tile, gload_lds + 2-phase (out-proj) ========
// 512 threads, 8 waves (2m x 4n), per-wave 64x64, acc[4][4]. LDS:
// As [2][128*64] (32KB), Bs [2][256*64] (64KB). A staged once per block;
// B rows clamped to N-1 (cols >= N discarded by store guard).
__global__ __launch_bounds__(512)
void k_out256(const unsigned short* __restrict__ Ap,
              const unsigned short* __restrict__ Bp,
              float* __restrict__ operm,
              const float* __restrict__ bias,
              int K, int N)
{
    __shared__ __align__(16) unsigned short As[2][128 * 64];
    __shared__ __align__(16) unsigned short Bs[2][256 * 64];

    const int tid  = threadIdx.x;
    const int lane = tid & 63;
    const int wave = tid >> 6;          // 0..7
    const int wm = (wave >> 2) << 6;    // 0, 64
    const int wn = (wave & 3) << 6;     // 0, 64, 128, 192
    const int m0 = blockIdx.y << 7;

    const int srow  = tid >> 3;                       // 0..63 (row within chunk)
    const int selem = ((tid & 7) ^ (srow & 7)) << 3;  // swizzled elem offset
    const unsigned short* Asrc = Ap + (size_t)(m0 + srow) * K + selem;

    size_t boff[4];
#pragma unroll
    for (int c = 0; c < 4; ++c) {
        int brow = srow + (c << 6);
        if (brow > N - 1) brow = N - 1;
        boff[c] = (size_t)brow * K + selem;
    }

    f32x4 acc[4][4];
#pragma unroll
    for (int i = 0; i < 4; ++i)
#pragma unroll
        for (int j = 0; j < 4; ++j) acc[i][j] = (f32x4){0.f, 0.f, 0.f, 0.f};

    const int lidx = lane & 15;
    const int lq   = lane >> 4;

    // ---- prologue: stage chunk 0 into buffer 0 ----
#pragma unroll
    for (int c = 0; c < 2; ++c)
        gload16(Asrc + (size_t)(c << 6) * K, &As[0][tid * 8 + (c << 12)]);
#pragma unroll
    for (int c = 0; c < 4; ++c)
        gload16(Bp + boff[c],                &Bs[0][tid * 8 + (c << 12)]);
    __syncthreads();

    const int nsteps = K >> 6;
    int cur = 0;
    for (int t = 0; t < nsteps; ++t) {
        if (t + 1 < nsteps) {
            const int k0n = (t + 1) << 6;
#pragma unroll
            for (int c = 0; c < 2; ++c)
                gload16(Asrc + (size_t)(c << 6) * K + k0n,
                        &As[cur ^ 1][tid * 8 + (c << 12)]);
#pragma unroll
            for (int c = 0; c < 4; ++c)
                gload16(Bp + boff[c] + k0n,
                        &Bs[cur ^ 1][tid * 8 + (c << 12)]);
        }
#pragma unroll
        for (int ks = 0; ks < 2; ++ks) {
            const int ub = (ks << 2) + lq;                        // 16B unit idx
            const int uo = (ub ^ (lidx & 7)) << 3;                // swizzled elems
            bf16x8 af[4], bfv[4];
#pragma unroll
            for (int t4 = 0; t4 < 4; ++t4)
                af[t4] = *(const bf16x8*)&As[cur][((wm + (t4 << 4) + lidx) << 6) + uo];
#pragma unroll
            for (int t4 = 0; t4 < 4; ++t4)
                bfv[t4] = *(const bf16x8*)&Bs[cur][((wn + (t4 << 4) + lidx) << 6) + uo];
#pragma unroll
            for (int mt = 0; mt < 4; ++mt)
#pragma unroll
                for (int nt = 0; nt < 4; ++nt)
                    acc[mt][nt] = __builtin_amdgcn_mfma_f32_16x16x32_bf16(
                        af[mt], bfv[nt], acc[mt][nt], 0, 0, 0);
        }
        __syncthreads();
        cur ^= 1;
    }

    const int rbase = lq << 2;
#pragma unroll
    for (int nt = 0; nt < 4; ++nt) {
        const int col = wn + (nt << 4) + lidx;
        if (col >= N) continue;
        const float badd = (bias != nullptr) ? bias[col] : 0.f;
#pragma unroll
        for (int mt = 0; mt < 4; ++mt) {
#pragma unroll
            for (int r = 0; r < 4; ++r) {
                float x = acc[mt][nt][r];
                const int row = m0 + wm + (mt << 4) + rbase + r;
                const int t = row >> 10, b = row & 1023;
                operm[(size_t)b * 4050 + t * 135 + col] = x + badd;
            }
        }
    }
}

// ===== bf16 MFMA GEMM, 256x256 tile, gload_lds + 2-phase (d3) ==============
__global__ __launch_bounds__(512)
void k_m256(const unsigned short* __restrict__ Abase,
            const unsigned short* __restrict__ Bt,
            unsigned short* __restrict__ Cb,
            float* __restrict__ stats,
            int Mslice, int K, int N, int decK)
{
    __shared__ __align__(16) unsigned short As[2][256 * 64];
    __shared__ __align__(16) unsigned short Bs[2][256 * 64];
    __shared__ float colsum[256], colsq[256];

    const int tid  = threadIdx.x;
    const int lane = tid & 63;
    const int wave = tid >> 6;          // 0..7
    const int wm = (wave >> 2) << 7;    // 0,128
    const int wn = (wave & 3) << 6;     // 0,64,128,192
    const int z  = blockIdx.z;
    const int n0 = blockIdx.x << 8;
    const int m0 = blockIdx.y << 8;

    if (stats != nullptr && tid < 256) { colsum[tid] = 0.f; colsq[tid] = 0.f; }

    const int a_slice = z / decK, wk = z - a_slice * decK;
    const unsigned short* Ap = Abase + (size_t)a_slice * (size_t)Mslice * (size_t)K;
    const unsigned short* Bp = Bt + (size_t)wk * (size_t)N * (size_t)K;

    const int srow  = tid >> 3;                       // 0..63 (row within chunk)
    const int selem = ((tid & 7) ^ (srow & 7)) << 3;  // swizzled elem offset
    const unsigned short* Asrc = Ap + (size_t)(m0 + srow) * K + selem;

    size_t boff[4];
#pragma unroll
    for (int c = 0; c < 4; ++c) {
        int brow = n0 + srow + (c << 6);
        if (brow > N - 1) brow = N - 1;
        boff[c] = (size_t)brow * K + selem;
    }

    f32x4 acc[8][4];
#pragma unroll
    for (int i = 0; i < 8; ++i)
#pragma unroll
        for (int j = 0; j < 4; ++j) acc[i][j] = (f32x4){0.f, 0.f, 0.f, 0.f};

    const int lidx = lane & 15;
    const int lq   = lane >> 4;

    // ---- prologue: stage chunk 0 into buffer 0 ----
#pragma unroll
    for (int c = 0; c < 4; ++c) {
        gload16(Asrc + (size_t)(c << 6) * K, &As[0][tid * 8 + (c << 12)]);
        gload16(Bp + boff[c],                &Bs[0][tid * 8 + (c << 12)]);
    }
    __syncthreads();

    const int nsteps = K >> 6;
    int cur = 0;
    for (int t = 0; t < nsteps; ++t) {
        if (t + 1 < nsteps) {
            const int k0n = (t + 1) << 6;
#pragma unroll
            for (int c = 0; c < 4; ++c) {
                gload16(Asrc + (size_t)(c << 6) * K + k0n,
                        &As[cur ^ 1][tid * 8 + (c << 12)]);
                gload16(Bp + boff[c] + k0n,
                        &Bs[cur ^ 1][tid * 8 + (c << 12)]);
            }
        }
#pragma unroll
        for (int ks = 0; ks < 2; ++ks) {
            const int ub = (ks << 2) + lq;                        // 16B unit idx
            const int uo = (ub ^ (lidx & 7)) << 3;                // swizzled elems
            bf16x8 af[8], bfv[4];
#pragma unroll
            for (int i = 0; i < 8; ++i)
                af[i] = *(const bf16x8*)&As[cur][((wm + (i << 4) + lidx) << 6) + uo];
#pragma unroll
            for (int j = 0; j < 4; ++j)
                bfv[j] = *(const bf16x8*)&Bs[cur][((wn + (j << 4) + lidx) << 6) + uo];
#pragma unroll
            for (int mt = 0; mt < 8; ++mt)
#pragma unroll
                for (int nt = 0; nt < 4; ++nt)
                    acc[mt][nt] = __builtin_amdgcn_mfma_f32_16x16x32_bf16(
                        af[mt], bfv[nt], acc[mt][nt], 0, 0, 0);
        }
        __syncthreads();
        cur ^= 1;
    }

    const int rbase = lq << 2;
#pragma unroll
    for (int nt = 0; nt < 4; ++nt) {
        const int col = n0 + wn + (nt << 4) + lidx;
        float s = 0.f, q = 0.f;
#pragma unroll
        for (int mt = 0; mt < 8; ++mt) {
#pragma unroll
            for (int r = 0; r < 4; ++r) {
                float x = acc[mt][nt][r];
                s += x; q += x * x;
                const int row = m0 + wm + (mt << 4) + rbase + r;
                Cb[((size_t)z * Mslice + row) * (size_t)N + col] = bfh(x);
            }
        }
        if (stats != nullptr) {
            s += __shfl_xor(s, 16, 64); s += __shfl_xor(s, 32, 64);
            q += __shfl_xor(q, 16, 64); q += __shfl_xor(q, 32, 64);
            if (lq == 0) {
                atomicAdd(&colsum[wn + (nt << 4) + lidx], s);
                atomicAdd(&colsq [wn + (nt << 4) + lidx], q);
            }
        }
    }
    if (stats != nullptr) {
        __syncthreads();
        if (tid < 256) {
            atomicAdd(&stats[n0 + tid],       colsum[tid]);
            atomicAdd(&stats[512 + n0 + tid], colsq[tid]);
        }
    }
}

// ===== bf16 MFMA GEMM, 64x64 tile, gload_lds + 2-phase (d0,d1,d2) ==========
__global__ __launch_bounds__(256)
void k_b64g(const unsigned short* __restrict__ Abase,
            const unsigned short* __restrict__ Bt,
            unsigned short* __restrict__ Cb,
            const float* __restrict__ bias,
            float* __restrict__ stats,
            int Mslice, int K, int N, int decK)
{
    __shared__ __align__(16) unsigned short As[2][64 * 64];
    __shared__ __align__(16) unsigned short Bs[2][64 * 64];
    __shared__ float colsum[64], colsq[64];

    const int tid  = threadIdx.x;
    const int lane = tid & 63;
    const int wave = tid >> 6;
    const int wm = (wave >> 1) << 5;
    const int wn = (wave & 1) << 5;
    const int z  = blockIdx.z;
    const int n0 = blockIdx.x << 6;
    const int m0 = blockIdx.y << 6;

    if (stats != nullptr && tid < 64) { colsum[tid] = 0.f; colsq[tid] = 0.f; }

    const int a_slice = z / decK, wk = z - a_slice * decK;
    const unsigned short* Ap = Abase + (size_t)a_slice * (size_t)Mslice * (size_t)K;
    const unsigned short* Bp = Bt + (size_t)wk * (size_t)N * (size_t)K;

    const int srow  = tid >> 3;                       // 0..31
    const int selem = ((tid & 7) ^ (srow & 7)) << 3;
    const unsigned short* Asrc = Ap + (size_t)(m0 + srow) * K + selem;
    const unsigned short* Bsrc = Bp + (size_t)(n0 + srow) * K + selem;

    f32x4 acc[2][2];
#pragma unroll
    for (int i = 0; i < 2; ++i)
#pragma unroll
        for (int j = 0; j < 2; ++j) acc[i][j] = (f32x4){0.f, 0.f, 0.f, 0.f};

    const int lidx = lane & 15;
    const int lq   = lane >> 4;

    // ---- prologue: stage chunk 0 into buffer 0 ----
#pragma unroll
    for (int c = 0; c < 2; ++c) {
        gload16(Asrc + (size_t)(c << 5) * K, &As[0][tid * 8 + (c << 11)]);
        gload16(Bsrc + (size_t)(c << 5) * K, &Bs[0][tid * 8 + (c << 11)]);
    }
    __syncthreads();

    const int nsteps = K >> 6;
    int cur = 0;
    for (int t = 0; t < nsteps; ++t) {
        if (t + 1 < nsteps) {
            const int k0n = (t + 1) << 6;
#pragma unroll
            for (int c = 0; c < 2; ++c) {
                gload16(Asrc + (size_t)(c << 5) * K + k0n,
                        &As[cur ^ 1][tid * 8 + (c << 11)]);
                gload16(Bsrc + (size_t)(c << 5) * K + k0n,
                        &Bs[cur ^ 1][tid * 8 + (c << 11)]);
            }
        }
#pragma unroll
        for (int ks = 0; ks < 2; ++ks) {
            const int ub = (ks << 2) + lq;
            const int uo = (ub ^ (lidx & 7)) << 3;
            bf16x8 af[2], bfv[2];
#pragma unroll
            for (int t2 = 0; t2 < 2; ++t2)
                af[t2] = *(const bf16x8*)&As[cur][((wm + (t2 << 4) + lidx) << 6) + uo];
#pragma unroll
            for (int t2 = 0; t2 < 2; ++t2)
                bfv[t2] = *(const bf16x8*)&Bs[cur][((wn + (t2 << 4) + lidx) << 6) + uo];
#pragma unroll
            for (int mt = 0; mt < 2; ++mt)
#pragma unroll
                for (int nt = 0; nt < 2; ++nt)
                    acc[mt][nt] = __builtin_amdgcn_mfma_f32_16x16x32_bf16(
                        af[mt], bfv[nt], acc[mt][nt], 0, 0, 0);
        }
        __syncthreads();
        cur ^= 1;
    }

    const int rbase = lq << 2;
#pragma unroll
    for (int nt = 0; nt < 2; ++nt) {
        const int col = n0 + wn + (nt << 4) + lidx;
        const float badd = (bias != nullptr) ? bias[col] : 0.f;
        float s = 0.f, q = 0.f;
#pragma unroll
        for (int mt = 0; mt < 2; ++mt) {
#pragma unroll
            for (int r = 0; r < 4; ++r) {
                float x = acc[mt][nt][r];
                s += x; q += x * x;
                const int row = m0 + wm + (mt << 4) + rbase + r;
                Cb[((size_t)z * Mslice + row) * (size_t)N + col] = bfh(x + badd);
            }
        }
        if (stats != nullptr) {
            s += __shfl_xor(s, 16, 64); s += __shfl_xor(s, 32, 64);
            q += __shfl_xor(q, 16, 64); q += __shfl_xor(q, 32, 64);
            if (lq == 0) {
                atomicAdd(&colsum[wn + (nt << 4) + lidx], s);
                atomicAdd(&colsq [wn + (nt << 4) + lidx], q);
            }
        }
    }
    if (stats != nullptr) {
        __syncthreads();
        if (tid < 64) {
            atomicAdd(&stats[n0 + tid],       colsum[tid]);
            atomicAdd(&stats[512 + n0 + tid], colsq[tid]);
        }
    }
}

// ===== split-bf16 MFMA GEMM, 64x64 tile, gload_lds + 2-phase (e2,e3) =======
// Linear LDS [2][64][32] bf16 per buffer; XOR-swizzle unit^(row&3).
__global__ __launch_bounds__(256)
void k_sp64g(const unsigned short* __restrict__ Ahg,
             const unsigned short* __restrict__ Alg,
             const unsigned short* __restrict__ Whi,
             const unsigned short* __restrict__ Wlo,
             float* __restrict__ Cout, float* __restrict__ stats,
             int Mslice, int Kp, int N, int n_terms)
{
    __shared__ __align__(16) unsigned short Ah[2][64 * 32];
    __shared__ __align__(16) unsigned short Al[2][64 * 32];
    __shared__ __align__(16) unsigned short Bh[2][64 * 32];
    __shared__ __align__(16) unsigned short Bl[2][64 * 32];
    __shared__ float colsum[64], colsq[64];

    const int tid  = threadIdx.x;
    const int lane = tid & 63;
    const int wave = tid >> 6;
    const int wm = (wave >> 1) << 5;
    const int wn = (wave & 1) << 5;
    const int z  = blockIdx.z;
    const int n0 = blockIdx.x << 6;
    const int m0 = blockIdx.y << 6;

    if (stats != nullptr && tid < 64) { colsum[tid] = 0.f; colsq[tid] = 0.f; }

    const int srow  = tid >> 2;                       // 0..63
    const int selem = ((tid & 3) ^ (srow & 3)) << 3;  // swizzled elem in 32-row

    f32x4 acc[2][2];
#pragma unroll
    for (int i = 0; i < 2; ++i)
#pragma unroll
        for (int j = 0; j < 2; ++j) acc[i][j] = (f32x4){0.f, 0.f, 0.f, 0.f};

    const int lidx = lane & 15;
    const int lq   = lane >> 4;
    const int uo   = (lq ^ (lidx & 3)) << 3;          // swizzled read offset

    const int cpk = Kp >> 5;
    const int tot = n_terms * cpk;

    // ---- prologue: stage chunk 0 (term 0, k 0) into buffer 0 ----
    {
        const size_t ab = ((size_t)(z * n_terms) * Mslice + m0 + srow)
                          * (size_t)Kp + selem;
        const size_t bb = ((size_t)(n0 + srow)) * (size_t)Kp + selem;
        gload16(Ahg + ab, &Ah[0][tid * 8]);
        gload16(Alg + ab, &Al[0][tid * 8]);
        gload16(Whi + bb, &Bh[0][tid * 8]);
        gload16(Wlo + bb, &Bl[0][tid * 8]);
    }
    __syncthreads();

    int cur = 0;
    int lt = 0, lk = 32;
    if (lk >= Kp) { lk = 0; lt = 1; }
    for (int c = 0; c < tot; ++c) {
        if (c + 1 < tot) {
            const size_t ab = ((size_t)(z * n_terms + lt) * Mslice + m0 + srow)
                              * (size_t)Kp + lk + selem;
            const size_t bb = ((size_t)lt * N + n0 + srow) * (size_t)Kp + lk + selem;
            gload16(Ahg + ab, &Ah[cur ^ 1][tid * 8]);
            gload16(Alg + ab, &Al[cur ^ 1][tid * 8]);
            gload16(Whi + bb, &Bh[cur ^ 1][tid * 8]);
            gload16(Wlo + bb, &Bl[cur ^ 1][tid * 8]);
            lk += 32; if (lk >= Kp) { lk = 0; ++lt; }
        }
        bf16x8 ah[2], al[2], bh[2], bl[2];
#pragma unroll
        for (int t = 0; t < 2; ++t) {
            const int ra = ((wm + (t << 4) + lidx) << 5) + uo;
            ah[t] = *(const bf16x8*)&Ah[cur][ra];
            al[t] = *(const bf16x8*)&Al[cur][ra];
        }
#pragma unroll
        for (int t = 0; t < 2; ++t) {
            const int rb = ((wn + (t << 4) + lidx) << 5) + uo;
            bh[t] = *(const bf16x8*)&Bh[cur][rb];
            bl[t] = *(const bf16x8*)&Bl[cur][rb];
        }
#pragma unroll
        for (int mt = 0; mt < 2; ++mt)
#pragma unroll
            for (int nt = 0; nt < 2; ++nt) {
                acc[mt][nt] = __builtin_amdgcn_mfma_f32_16x16x32_bf16(
                    ah[mt], bh[nt], acc[mt][nt], 0, 0, 0);
                acc[mt][nt] = __builtin_amdgcn_mfma_f32_16x16x32_bf16(
                    al[mt], bh[nt], acc[mt][nt], 0, 0, 0);
                acc[mt][nt] = __builtin_amdgcn_mfma_f32_16x16x32_bf16(
                    ah[mt], bl[nt], acc[mt][nt], 0, 0, 0);
            }
        __syncthreads();
        cur ^= 1;
    }

    const int rbase = lq << 2;
#pragma unroll
    for (int nt = 0; nt < 2; ++nt) {
        const int col = n0 + wn + (nt << 4) + lidx;
        float s = 0.f, q = 0.f;
#pragma unroll
        for (int mt = 0; mt < 2; ++mt) {
#pragma unroll
            for (int r = 0; r < 4; ++r) {
                float x = acc[mt][nt][r];
                s += x; q += x * x;
                const int row = m0 + wm + (mt << 4) + rbase + r;
                Cout[((size_t)z * Mslice + row) * (size_t)N + col] = x;
            }
        }
        if (stats != nullptr) {
            s += __shfl_xor(s, 16, 64); s += __shfl_xor(s, 32, 64);
            q += __shfl_xor(q, 16, 64); q += __shfl_xor(q, 32, 64);
            if (lq == 0) {
                atomicAdd(&colsum[wn + (nt << 4) + lidx], s);
                atomicAdd(&colsq [wn + (nt << 4) + lidx], q);
            }
        }
    }
    if (stats != nullptr) {
        __syncthreads();
        if (tid < 64) {
            atomicAdd(&stats[n0 + tid],       colsum[tid]);
            atomicAdd(&stats[512 + n0 + tid], colsq[tid]);
        }
    }
}

// ===== split-bf16 MFMA GEMM, 64x128 tile, gload_lds + 2-phase (e1) =========
__global__ __launch_bounds__(256)
void k_sp64w(const unsigned short* __restrict__ Ahg,
             const unsigned short* __restrict__ Alg,
             const unsigned short* __restrict__ Whi,
             const unsigned short* __restrict__ Wlo,
             float* __restrict__ Cout, float* __restrict__ stats,
             int Mslice, int Kp, int N, int n_terms)
{
    __shared__ __align__(16) unsigned short Ah[2][64 * 32];
    __shared__ __align__(16) unsigned short Al[2][64 * 32];
    __shared__ __align__(16) unsigned short Bh[2][128 * 32];
    __shared__ __align__(16) unsigned short Bl[2][128 * 32];
    __shared__ float colsum[128], colsq[128];

    const int tid  = threadIdx.x;
    const int lane = tid & 63;
    const int wave = tid >> 6;          // 0..3
    const int wm = (wave >> 1) << 5;    // 0, 32
    const int wn = (wave & 1) << 6;     // 0, 64
    const int z  = blockIdx.z;
    const int n0 = blockIdx.x << 7;     // 4 n-blocks x 128
    const int m0 = blockIdx.y << 6;     // 16 m-blocks x 64

    if (stats != nullptr && tid < 128) { colsum[tid] = 0.f; colsq[tid] = 0.f; }

    const int srow  = tid >> 2;                       // 0..63
    const int selem = ((tid & 3) ^ (srow & 3)) << 3;  // swizzled elem in 32-row

    f32x4 acc[2][4];
#pragma unroll
    for (int i = 0; i < 2; ++i)
#pragma unroll
        for (int j = 0; j < 4; ++j) acc[i][j] = (f32x4){0.f, 0.f, 0.f, 0.f};

    const int lidx = lane & 15;
    const int lq   = lane >> 4;
    const int uo   = (lq ^ (lidx & 3)) << 3;          // swizzled read offset

    const int cpk = Kp >> 5;
    const int tot = n_terms * cpk;

    // ---- prologue: stage chunk 0 (term 0, k 0) into buffer 0 ----
    {
        const size_t ab = ((size_t)(z * n_terms) * Mslice + m0 + srow)
                          * (size_t)Kp + selem;
        gload16(Ahg + ab, &Ah[0][tid * 8]);
        gload16(Alg + ab, &Al[0][tid * 8]);
#pragma unroll
        for (int c = 0; c < 2; ++c) {
            const int rowB = (c << 6) + srow;
            const size_t bb = ((size_t)(n0 + rowB)) * (size_t)Kp + selem;
            gload16(Whi + bb, &Bh[0][tid * 8 + (c << 11)]);
            gload16(Wlo + bb, &Bl[0][tid * 8 + (c << 11)]);
        }
    }
    __syncthreads();

    int cur = 0;
    int lt = 0, lk = 32;
    if (lk >= Kp) { lk = 0; lt = 1; }
    for (int c = 0; c < tot; ++c) {
        if (c + 1 < tot) {
            const size_t ab = ((size_t)(z * n_terms + lt) * Mslice + m0 + srow)
                              * (size_t)Kp + lk + selem;
            gload16(Ahg + ab, &Ah[cur ^ 1][tid * 8]);
            gload16(Alg + ab, &Al[cur ^ 1][tid * 8]);
#pragma unroll
            for (int cc = 0; cc < 2; ++cc) {
                const int rowB = (cc << 6) + srow;
                const size_t bb = ((size_t)lt * N + n0 + rowB) * (size_t)Kp
                                  + lk + selem;
                gload16(Whi + bb, &Bh[cur ^ 1][tid * 8 + (cc << 11)]);
                gload16(Wlo + bb, &Bl[cur ^ 1][tid * 8 + (cc << 11)]);
            }
            lk += 32; if (lk >= Kp) { lk = 0; ++lt; }
        }
        bf16x8 ah[2], al[2], bh[4], bl[4];
#pragma unroll
        for (int t = 0; t < 2; ++t) {
            const int ra = ((wm + (t << 4) + lidx) << 5) + uo;
            ah[t] = *(const bf16x8*)&Ah[cur][ra];
            al[t] = *(const bf16x8*)&Al[cur][ra];
        }
#pragma unroll
        for (int t = 0; t < 4; ++t) {
            const int rb = ((wn + (t << 4) + lidx) << 5) + uo;
            bh[t] = *(const bf16x8*)&Bh[cur][rb];
            bl[t] = *(const bf16x8*)&Bl[cur][rb];
        }
#pragma unroll
        for (int mt = 0; mt < 2; ++mt)
#pragma unroll
            for (int nt = 0; nt < 4; ++nt) {
                acc[mt][nt] = __builtin_amdgcn_mfma_f32_16x16x32_bf16(
                    ah[mt], bh[nt], acc[mt][nt], 0, 0, 0);
                acc[mt][nt] = __builtin_amdgcn_mfma_f32_16x16x32_bf16(
                    al[mt], bh[nt], acc[mt][nt], 0, 0, 0);
                acc[mt][nt] = __builtin_amdgcn_mfma_f32_16x16x32_bf16(
                    ah[mt], bl[nt], acc[mt][nt], 0, 0, 0);
            }
        __syncthreads();
        cur ^= 1;
    }

    const int rbase = lq << 2;
#pragma unroll
    for (int nt = 0; nt < 4; ++nt) {
        const int col = n0 + wn + (nt << 4) + lidx;
        float s = 0.f, q = 0.f;
#pragma unroll
        for (int mt = 0; mt < 2; ++mt) {
#pragma unroll
            for (int r = 0; r < 4; ++r) {
                float x = acc[mt][nt][r];
                s += x; q += x * x;
                const int row = m0 + wm + (mt << 4) + rbase + r;
                Cout[((size_t)z * Mslice + row) * (size_t)N + col] = x;
            }
        }
        if (stats != nullptr) {
            s += __shfl_xor(s, 16, 64); s += __shfl_xor(s, 32, 64);
            q += __shfl_xor(q, 16, 64); q += __shfl_xor(q, 32, 64);
            if (lq == 0) {
                atomicAdd(&colsum[wn + (nt << 4) + lidx], s);
                atomicAdd(&colsq [wn + (nt << 4) + lidx], q);
            }
        }
    }
    if (stats != nullptr) {
        __syncthreads();
        if (tid < 128) {
            atomicAdd(&stats[n0 + tid],       colsum[tid]);
            atomicAdd(&stats[512 + n0 + tid], colsq[tid]);
        }
    }
}

// ======== merged prep kernel (10 independent preps, incl. sp_weff) =========
__global__ void k_prep(float* __restrict__ zbase, unsigned long long* __restrict__ amin,
                       const float* __restrict__ codebook, float* __restrict__ codeT,
                       float* __restrict__ codesq,
                       const float* __restrict__ w_e2, unsigned short* __restrict__ whi_e2,
                       unsigned short* __restrict__ wlo_e2,
                       const float* __restrict__ w_e3, unsigned short* __restrict__ whi_e3,
                       unsigned short* __restrict__ wlo_e3,
                       const float* __restrict__ W_q,  unsigned short* __restrict__ wqb,
                       const float* __restrict__ w_d1, unsigned short* __restrict__ wd1b,
                       const float* __restrict__ w_d2, unsigned short* __restrict__ wd2b,
                       const float* __restrict__ w_d3, unsigned short* __restrict__ wd3b,
                       const float* __restrict__ W_out, unsigned short* __restrict__ woutb,
                       const float* __restrict__ in_seqs,
                       unsigned short* __restrict__ in_h, unsigned short* __restrict__ in_l,
                       const float* __restrict__ weff,
                       unsigned short* __restrict__ whi_e1,
                       unsigned short* __restrict__ wlo_e1)
{
    __shared__ float red[4];
    const int bid = blockIdx.x;
    const int tid = threadIdx.x;

    if (bid < 32) {                                    // s0: init
        int t = bid * 256 + tid;
        if (t < 6720) zbase[t] = 0.f;
        if (t < 1024) amin[t] = ~0ULL;
        return;
    }
    if (bid < 1056) {                                  // s1: codeT repack (Kc=1)
        int idx = (bid - 32) * 256 + tid;
        int i = (idx >> 9) & 511, o = idx & 511;
        codeT[idx] = codebook[(o << 9) + i];
        return;
    }
    if (bid < 1568) {                                  // s2: codesq
        int c = bid - 1056;
        float s = 0.f;
        for (int i = tid; i < 512; i += 256) { float v = codebook[c * 512 + i]; s += v * v; }
        for (int off = 32; off; off >>= 1) s += __shfl_down(s, off, 64);
        if ((tid & 63) == 0) red[tid >> 6] = s;
        __syncthreads();
        if (tid == 0) codesq[c] = red[0] + red[1] + red[2] + red[3];
        return;
    }
    if (bid < 4640) {                                  // s3: split e2 (Kc=3)
        int idx = (bid - 1568) * 256 + tid;
        int i = idx & 511, o = (idx >> 9) & 511, k = idx >> 18;
        float v = w_e2[(((o << 9) + i) * 3) + k];
        unsigned short h = bfh(v);
        whi_e2[idx] = h; wlo_e2[idx] = bfh(v - bf2f(h));
        return;
    }
    if (bid < 6688) {                                  // s4: split e3 (Kc=2)
        int idx = (bid - 4640) * 256 + tid;
        int i = idx & 511, o = (idx >> 9) & 511, k = idx >> 18;
        float v = w_e3[(((o << 9) + i) * 2) + k];
        unsigned short h = bfh(v);
        whi_e3[idx] = h; wlo_e3[idx] = bfh(v - bf2f(h));
        return;
    }
    if (bid < 7712) {                                  // s5: W_q bf (Kc=1,I=O=512)
        int idx = (bid - 6688) * 256 + tid;
        int i = idx & 511, o = (idx >> 9) & 511;
        wqb[idx] = bfh(W_q[((size_t)i << 9) + o]);
        return;
    }
    if (bid < 9760) {                                  // s6: w_d1 bf (Kc=2)
        int idx = (bid - 7712) * 256 + tid;
        int i = idx & 511, o = (idx >> 9) & 511, k = idx >> 18;
        wd1b[idx] = bfh(w_d1[(((size_t)i << 9) + o) * 2 + k]);
        return;
    }
    if (bid < 12832) {                                 // s7: w_d2 bf (Kc=3)
        int idx = (bid - 9760) * 256 + tid;
        int i = idx & 511, o = (idx >> 9) & 511, k = idx >> 18;
        wd2b[idx] = bfh(w_d2[(((size_t)i << 9) + o) * 3 + k]);
        return;
    }
    if (bid < 17952) {                                 // s8: w_d3 bf (Kc=5)
        int idx = (bid - 12832) * 256 + tid;
        int i = idx & 511, o = (idx >> 9) & 511, k = idx >> 18;
        wd3b[idx] = bfh(w_d3[(((size_t)i << 9) + o) * 5 + k]);
        return;
    }
    if (bid < 18222) {                                 // s9: W_out bf (Kc=1,I=512,O=135)
        int idx = (bid - 17952) * 256 + tid;
        if (idx >= 69120) return;
        int i = idx % 512, o = idx / 512;              // [o][i], o<135
        woutb[idx] = bfh(W_out[((size_t)i * 135) + o]);
        return;
    }
    if (bid < 37422) {                                 // s10: split_in
        int idx = (bid - 18222) * 256 + tid;
        int i = idx % 160, r = idx / 160;
        float v = (i < 135) ? in_seqs[(size_t)r * 135 + i] : 0.f;
        unsigned short h = bfh(v);
        in_h[idx] = h; in_l[idx] = bfh(v - bf2f(h));
        return;
    }
    {                                                  // s11: sp_weff
        int idx = (bid - 37422) * 256 + tid;
        if (idx >= 409600) return;
        int i = idx % 160;
        int o = (idx / 160) & 511;
        int t = idx / 81920;
        float v = (i < 135) ? weff[((size_t)t * 135 + i) * 512 + o] : 0.f;
        unsigned short h = bfh(v);
        whi_e1[idx] = h;
        wlo_e1[idx] = bfh(v - bf2f(h));
    }
}

// ============================ small kernels ================================
__global__ void k_repack(const float* __restrict__ w, float* __restrict__ wt,
                         int Kc, int total)
{
    int idx = blockIdx.x * 256 + threadIdx.x;
    if (idx >= total) return;
    int k = idx >> 18;
    int rem = idx & 262143;
    int i = rem >> 9, o = rem & 511;
    wt[idx] = w[(((o << 9) + i) * Kc + k)];
}

// BN-finalize fused: compute sc/sh in LDS (identical math), split to hi/lo
__global__ void k_bnsplit(const float* __restrict__ x,
                          const float* __restrict__ stats,
                          const float* __restrict__ g, const float* __restrict__ b,
                          float inv_n,
                          unsigned short* __restrict__ hq, unsigned short* __restrict__ lq_,
                          int total4)
{
    __shared__ __align__(16) float scs[512], shs[512];
    const int tid = threadIdx.x;
    bn_fin_lds(stats, g, b, inv_n, scs, shs, tid);
    __syncthreads();

    int idx = blockIdx.x * 256 + tid;
    if (idx >= total4) return;
    const int base = idx << 2;
    float4 f = *(const float4*)(x + base);
    const int k = base & 511;
    float4 s = *(const float4*)&scs[k];
    float4 c = *(const float4*)&shs[k];
    float y0 = fmaxf(fmaf(f.x, s.x, c.x), 0.f);
    float y1 = fmaxf(fmaf(f.y, s.y, c.y), 0.f);
    float y2 = fmaxf(fmaf(f.z, s.z, c.z), 0.f);
    float y3 = fmaxf(fmaf(f.w, s.w, c.w), 0.f);
    unsigned short h0 = bfh(y0), h1 = bfh(y1), h2 = bfh(y2), h3 = bfh(y3);
    unsigned short l0 = bfh(y0 - bf2f(h0)), l1 = bfh(y1 - bf2f(h1));
    unsigned short l2 = bfh(y2 - bf2f(h2)), l3 = bfh(y3 - bf2f(h3));
    *(uint2*)&hq[base]  = make_uint2((unsigned)h0 | ((unsigned)h1 << 16),
                                     (unsigned)h2 | ((unsigned)h3 << 16));
    *(uint2*)&lq_[base] = make_uint2((unsigned)l0 | ((unsigned)l1 << 16),
                                     (unsigned)l2 | ((unsigned)l3 << 16));
}

// BN-finalize fused: compute sc/sh in LDS, apply BN+ReLU, emit bf16
__global__ void k_bnapply(const unsigned short* __restrict__ x,
                          const float* __restrict__ stats,
                          const float* __restrict__ g, const float* __restrict__ b,
                          float inv_n,
                          unsigned short* __restrict__ y, int total8)
{
    __shared__ __align__(16) float scs[512], shs[512];
    const int tid = threadIdx.x;
    bn_fin_lds(stats, g, b, inv_n, scs, shs, tid);
    __syncthreads();

    int idx = blockIdx.x * 256 + tid;
    if (idx >= total8) return;
    const int base = idx << 3;
    uint4 raw = *(const uint4*)(x + base);
    const int k = base & 511;
    float4 s0 = *(const float4*)&scs[k];
    float4 c0 = *(const float4*)&shs[k];
    float4 s1 = *(const float4*)&scs[k + 4];
    float4 c1 = *(const float4*)&shs[k + 4];
    unsigned* u = (unsigned*)&raw;
    float x0 = __uint_as_float(u[0] << 16),        x1 = __uint_as_float(u[0] & 0xffff0000u);
    float x2 = __uint_as_float(u[1] << 16),        x3 = __uint_as_float(u[1] & 0xffff0000u);
    float x4 = __uint_as_float(u[2] << 16),        x5 = __uint_as_float(u[2] & 0xffff0000u);
    float x6 = __uint_as_float(u[3] << 16),        x7 = __uint_as_float(u[3] & 0xffff0000u);
    x0 = fmaxf(fmaf(x0, s0.x, c0.x), 0.f); x1 = fmaxf(fmaf(x1, s0.y, c0.y), 0.f);
    x2 = fmaxf(fmaf(x2, s0.z, c0.z), 0.f); x3 = fmaxf(fmaf(x3, s0.w, c0.w), 0.f);
    x4 = fmaxf(fmaf(x4, s1.x, c1.x), 0.f); x5 = fmaxf(fmaf(x5, s1.y, c1.y), 0.f);
    x6 = fmaxf(fmaf(x6, s1.z, c1.z), 0.f); x7 = fmaxf(fmaf(x7, s1.w, c1.w), 0.f);
    *(uint4*)&y[base] = make_uint4(pk_bf16(x0, x1), pk_bf16(x2, x3),
                                   pk_bf16(x4, x5), pk_bf16(x6, x7));
}

__global__ void k_bn_fin(const float* __restrict__ stats,
                         const float* __restrict__ g, const float* __restrict__ b,
                         float* __restrict__ sc, float* __restrict__ sh, float inv_n)
{
    int c = blockIdx.x * blockDim.x + threadIdx.x;
    if (c >= 512) return;
    float m = stats[c] * inv_n;
    float v = stats[512 + c] * inv_n - m * m;
    float a = (float)((double)g[c] / sqrt((double)v + 1e-5));
    sc[c] = a;
    sh[c] = b[c] - m * a;
}

__global__ void k_vq_gather(const unsigned long long* __restrict__ amin,
                            const float* __restrict__ codebook,
                            const float* __restrict__ e3pre,
                            const float* __restrict__ sc, const float* __restrict__ sh,
                            unsigned short* __restrict__ quant_bf,
                            float* __restrict__ loss,
                            unsigned int* __restrict__ hist)
{
    int b = blockIdx.x; int t = threadIdx.x;   // 256 threads
    unsigned int idx = (unsigned int)(amin[b] & 0xFFFFFFFFull) & 511u;
    float part = 0.f;
    for (int i = t; i < 512; i += 256) {
        float q = codebook[(size_t)idx * 512 + i];
        quant_bf[(size_t)b * 512 + i] = bfh(q);
        float x = e3pre[(size_t)b * 512 + i];
        float f = fmaxf(fmaf(x, sc[i], sh[i]), 0.f);
        float d = q - f;
        part += d * d;
    }
    for (int off = 32; off; off >>= 1) part += __shfl_down(part, off, 64);
    __shared__ float red[4];
    if ((t & 63) == 0) red[t >> 6] = part;
    __syncthreads();
    if (t == 0) {
        atomicAdd(loss, red[0] + red[1] + red[2] + red[3]);
        atomicAdd(&hist[idx], 1u);
    }
}

__global__ void k_scalars(const unsigned int* __restrict__ hist,
                          const float* __restrict__ loss, float* __restrict__ out)
{
    int t = threadIdx.x;   // 512
    float p = (float)hist[t] * (1.0f / 1024.0f);
    float e = p * logf(p + 1e-10f);
    for (int off = 32; off; off >>= 1) e += __shfl_down(e, off, 64);
    __shared__ float red[8];
    if ((t & 63) == 0) red[t >> 6] = e;
    __syncthreads();
    if (t == 0) {
        float s = 0.f;
        for (int i = 0; i < 8; ++i) s += red[i];
        out[4147200] = 1.25f * loss[0] * (1.0f / 524288.0f);
        out[4147201] = expf(-s);
    }
}

extern "C" void kernel_launch(void* const* d_in, const int* in_sizes, int n_in,
                              void* d_out, int out_size, void* d_ws, size_t ws_size,
                              hipStream_t stream)
{
    const float* in_seqs = (const float*)d_in[0];
    const float* W_in  = (const float*)d_in[1];
    const float* w_e1  = (const float*)d_in[3];
    const float* g_e1  = (const float*)d_in[4];
    const float* be1   = (const float*)d_in[5];
    const float* w_e2  = (const float*)d_in[6];
    const float* g_e2  = (const float*)d_in[7];
    const float* be2   = (const float*)d_in[8];
    const float* w_e3  = (const float*)d_in[9];
    const float* g_e3  = (const float*)d_in[10];
    const float* be3   = (const float*)d_in[11];
    const float* codebook = (const float*)d_in[12];
    const float* W_q   = (const float*)d_in[13];
    const float* b_q   = (const float*)d_in[14];
    const float* w_d1  = (const float*)d_in[15];
    const float* g_d1  = (const float*)d_in[16];
    const float* bd1   = (const float*)d_in[17];
    const float* w_d2  = (const float*)d_in[18];
    const float* g_d2  = (const float*)d_in[19];
    const float* bd2   = (const float*)d_in[20];
    const float* w_d3  = (const float*)d_in[21];
    const float* g_d3  = (const float*)d_in[22];
    const float* bd3   = (const float*)d_in[23];
    const float* W_out = (const float*)d_in[24];
    const float* b_out = (const float*)d_in[25];
    float* out = (float*)d_out;

    // ---- workspace layout (float offsets) ----
    float* W = (float*)d_ws;
    unsigned long long* amin = (unsigned long long*)W;            // 2048 f
    float* stats  = W + 2048;                                     // 6144
    float* lossp  = W + 8192;                                     // 64
    unsigned int* hist = (unsigned int*)(W + 8256);               // 512
    float* scsh   = W + 8768;                                     // 6144
    float* codesq = W + 14912;                                    // 512
    float* wt_e1  = W + 15424;                                    // 1310720 f
    float* codeT  = W + 1671744;                                  // 262144 f
    unsigned short* esw = (unsigned short*)(W + 1933888);         // 3440640 ush
    unsigned short* whi_e1 = esw;
    unsigned short* wlo_e1 = esw + 409600;
    unsigned short* whi_e2 = esw + 819200;
    unsigned short* wlo_e2 = esw + 1605632;
    unsigned short* whi_e3 = esw + 2392064;
    unsigned short* wlo_e3 = esw + 2916352;
    unsigned short* in_h  = (unsigned short*)(W + 3654208);       // 4915200 ush
    unsigned short* in_l  = in_h + 4915200;
    unsigned short* d3pre = (unsigned short*)(W + 3654208);       // 15728640 ush
    float* e1f = W + 11518528;                                    // 3145728 f
    unsigned short* e1h = (unsigned short*)(W + 14664256);        // 3145728 ush
    unsigned short* e1l = e1h + 3145728;
    float* e2f = W + 17809984;                                    // 1048576 f
    unsigned short* e2h = (unsigned short*)(W + 18858560);        // 1048576 ush
    unsigned short* e2l = e2h + 1048576;
    unsigned short* d2pre = (unsigned short*)(W + 17809984);      // 3145728 ush
    unsigned short* d2bf  = d2pre + 3145728;                      // 3145728 ush
    float* e3f = W + 20955712;                                    // 524288 f
    unsigned short* quant_bf = (unsigned short*)(W + 21480000);   // 524288 ush
    unsigned short* d0bf     = (unsigned short*)(W + 21742144);   // 524288 ush
    unsigned short* d1pre    = (unsigned short*)(W + 22004288);   // 1048576 ush
    unsigned short* d1bf     = (unsigned short*)(W + 22528640);   // 1048576 ush
    unsigned short* d3bf     = (unsigned short*)(W + 23052928);   // 15728640 ush
    float* weff   = W + 30917248;                                 // 345600 f
    // weff ends at 31262848 floats (~125 MB) < 256 MiB ws; no aliasing.

    unsigned short* db    = (unsigned short*)wt_e1;
    unsigned short* wqb   = db;
    unsigned short* wd1b  = db + 262144;
    unsigned short* wd2b  = db + 786432;
    unsigned short* wd3b  = db + 1572864;
    unsigned short* woutb = db + 2883584;

    float* st_e1 = stats + 0 * 1024;
    float* st_e2 = stats + 1 * 1024;
    float* st_e3 = stats + 2 * 1024; float* sc_e3 = scsh + 2 * 1024; float* sh_e3 = sc_e3 + 512;
    float* st_d1 = stats + 3 * 1024;
    float* st_d2 = stats + 4 * 1024;
    float* st_d3 = stats + 5 * 1024;

    dim3 blk(256);

    // order: wt_e1 fp32 repack -> weff gemm -> k_prep (contains sp_weff s11;
    // weff is in a non-aliased region so s11 is race-free vs s8/s9).
    k_repack<<<dim3(5 * 1024), blk, 0, stream>>>(w_e1, wt_e1, 5, 5 * 262144);
    k_gemm<<<dim3(16, 5, 5), blk, 0, stream>>>(W_in, wt_e1, weff,
        nullptr, nullptr, nullptr, nullptr, 135, 512, 512, 5);

    k_prep<<<dim3(39022), blk, 0, stream>>>(stats, amin,
        codebook, codeT, codesq,
        w_e2, whi_e2, wlo_e2, w_e3, whi_e3, wlo_e3,
        W_q, wqb, w_d1, wd1b, w_d2, wd2b, w_d3, wd3b, W_out, woutb,
        in_seqs, in_h, in_l, weff, whi_e1, wlo_e1);

    // ---- encoder: e1 = 64x128 tile (k_sp64w, 384 blk); e2/e3 = 64x64 ----
    k_sp64w<<<dim3(4, 16, 6), blk, 0, stream>>>(in_h, in_l, whi_e1, wlo_e1,
        e1f, st_e1, 1024, 160, 512, 5);
    k_bnsplit<<<dim3(3072), blk, 0, stream>>>(e1f, st_e1, g_e1, be1,
        1.f / 6144.f, e1h, e1l, 786432);

    k_sp64g<<<dim3(8, 16, 2), blk, 0, stream>>>(e1h, e1l, whi_e2, wlo_e2,
        e2f, st_e2, 1024, 512, 512, 3);
    k_bnsplit<<<dim3(1024), blk, 0, stream>>>(e2f, st_e2, g_e2, be2,
        1.f / 2048.f, e2h, e2l, 262144);

    k_sp64g<<<dim3(8, 16, 1), blk, 0, stream>>>(e2h, e2l, whi_e3, wlo_e3,
        e3f, st_e3, 1024, 512, 512, 2);
    k_bn_fin<<<dim3(2), blk, 0, stream>>>(st_e3, g_e3, be3, sc_e3, sh_e3, 1.f / 1024.f);

    // ---- VQ: fp32 dist GEMM + argmin (32x32 tiles, 512 blocks) ----
    k_gemm<<<dim3(16, 32, 1), blk, 0, stream>>>(e3f, codeT, nullptr,
        sc_e3, sh_e3, amin, codesq, 1024, 512, 512, 1);
    k_vq_gather<<<dim3(1024), blk, 0, stream>>>(amin, codebook, e3f, sc_e3, sh_e3,
                                                quant_bf, lossp, hist);

    // ---- decoder: all gload_lds 2-phase; BN fused into bnapply ----
    k_b64g<<<dim3(8, 16, 1), blk, 0, stream>>>(quant_bf, wqb, d0bf,
        b_q, nullptr, 1024, 512, 512, 1);

    k_b64g<<<dim3(8, 16, 2), blk, 0, stream>>>(d0bf, wd1b, d1pre,
        nullptr, st_d1, 1024, 512, 512, 2);
    k_bnapply<<<dim3(512), blk, 0, stream>>>(d1pre, st_d1, g_d1, bd1,
        1.f / 2048.f, d1bf, 131072);

    k_b64g<<<dim3(8, 16, 6), blk, 0, stream>>>(d1bf, wd2b, d2pre,
        nullptr, st_d2, 1024, 512, 512, 3);
    k_bnapply<<<dim3(1536), blk, 0, stream>>>(d2pre, st_d2, g_d2, bd2,
        1.f / 6144.f, d2bf, 393216);

    // d3: 256x256 tiles, gload_lds 2-phase, 512 threads (240 blocks)
    k_m256<<<dim3(2, 4, 30), dim3(512), 0, stream>>>(d2bf, wd3b, d3pre,
        st_d3, 1024, 512, 512, 5);
    k_bnapply<<<dim3(7680), blk, 0, stream>>>(d3pre, st_d3, g_d3, bd3,
        1.f / 30720.f, d3bf, 1966080);

    // out-proj: 128x256 single-n-block tile (A staged once), grid (1,240)
    k_out256<<<dim3(1, 240, 1), dim3(512), 0, stream>>>(d3bf, woutb,
        out, b_out, 512, 135);

    k_scalars<<<dim3(1), dim3(512), 0, stream>>>(hist, lossp, out);
}

// Round 16
// 399.518 us; speedup vs baseline: 1.1088x; 1.0195x over previous
//
#include <hip/hip_runtime.h>
#include <math.h>

// ---------------------------------------------------------------------------
// VQ-VAE forward (round 27 = round 26 + d3-BN fused into k_out256).
//  - Round-26 base (407.3us best).
//  - NEW: k_bnapply(d3pre->d3bf) eliminated. k_out256 stages RAW d3pre
//    (pure-copy gload_lds unchanged) and applies BN+ReLU+bf16-pack on each
//    A-fragment after ds_read via bn_on_raw with sc/sh from bn_fin_lds
//    (identical expressions) -> bit-identical MFMA operands. Fragment
//    k-range = t*64 + ub*8 (swizzle cancels). Saves 63 MB traffic + 1
//    dispatch; d3bf dead.
// ---------------------------------------------------------------------------

typedef __attribute__((ext_vector_type(8))) short bf16x8;
typedef __attribute__((ext_vector_type(4))) float f32x4;

__device__ __forceinline__ unsigned pk_bf16(float a, float b) {
    unsigned ua = __float_as_uint(a), ub = __float_as_uint(b);
    ua += 0x7fffu + ((ua >> 16) & 1u);          // RNE
    ub += 0x7fffu + ((ub >> 16) & 1u);
    return (ua >> 16) | (ub & 0xffff0000u);
}
__device__ __forceinline__ unsigned short bfh(float x) {
    unsigned u = __float_as_uint(x);
    u += 0x7fffu + ((u >> 16) & 1u);
    return (unsigned short)(u >> 16);
}
__device__ __forceinline__ float bf2f(unsigned short h) {
    return __uint_as_float(((unsigned)h) << 16);
}

// async global->LDS DMA, 16 B per lane (global_load_lds_dwordx4)
__device__ __forceinline__ void gload16(const unsigned short* g, unsigned short* l) {
    __builtin_amdgcn_global_load_lds(
        (const __attribute__((address_space(1))) unsigned int*)g,
        (__attribute__((address_space(3))) unsigned int*)l, 16, 0, 0);
}

__device__ __forceinline__ void bn4(float4& a, const float* __restrict__ s,
                                    const float* __restrict__ c) {
    float4 sv = *(const float4*)s;
    float4 cv = *(const float4*)c;
    a.x = fmaxf(fmaf(a.x, sv.x, cv.x), 0.f);
    a.y = fmaxf(fmaf(a.y, sv.y, cv.y), 0.f);
    a.z = fmaxf(fmaf(a.z, sv.z, cv.z), 0.f);
    a.w = fmaxf(fmaf(a.w, sv.w, cv.w), 0.f);
}

// BN+ReLU on packed bf16 pairs; kbase = absolute k of raw[0] low half.
// bnS/bnB may be LDS pointers. Identical expression chain to k_bnapply.
template <int NV>
__device__ __forceinline__ void bn_on_raw(uint4* raw, int kbase,
                                          const float* bnS,
                                          const float* bnB) {
#pragma unroll
    for (int i = 0; i < NV; ++i) {
        unsigned* u4 = (unsigned*)&raw[i];
#pragma unroll
        for (int j = 0; j < 4; ++j) {
            const int k = kbase + (i << 3) + (j << 1);
            unsigned u = u4[j];
            float x0 = __uint_as_float(u << 16);
            float x1 = __uint_as_float(u & 0xffff0000u);
            x0 = fmaxf(fmaf(x0, bnS[k],     bnB[k]),     0.f);
            x1 = fmaxf(fmaf(x1, bnS[k + 1], bnB[k + 1]), 0.f);
            u4[j] = pk_bf16(x0, x1);
        }
    }
}

// shared helper: compute sc/sh for 512 channels into LDS (identical math to
// k_bn_fin; deterministic -> bit-identical wherever applied; duplicate
// writes with >256 threads store identical bits)
__device__ __forceinline__ void bn_fin_lds(const float* __restrict__ stats,
                                           const float* __restrict__ g,
                                           const float* __restrict__ b,
                                           float inv_n,
                                           float* scs, float* shs, int tid) {
    for (int c = tid; c < 512; c += 256) {
        float m = stats[c] * inv_n;
        float v = stats[512 + c] * inv_n - m * m;
        float a = (float)((double)g[c] / sqrt((double)v + 1e-5));
        scs[c] = a;
        shs[c] = b[c] - m * a;
    }
}

// ======================= fp32 GEMM (weff + VQ dist) ========================
#define FBK  32
#define FSTR 36

__global__ __launch_bounds__(256)
void k_gemm(const float* __restrict__ Abase,
            const float* __restrict__ Wt,
            float* __restrict__ Cout,
            const float* __restrict__ bnS, const float* __restrict__ bnB,
            unsigned long long* __restrict__ amin,
            const float* __restrict__ codesq,
            int Mslice, int K, int N, int decK)
{
    __shared__ __align__(16) float As[FBK][FSTR];
    __shared__ __align__(16) float Bs[FBK][FSTR];

    const int tid = threadIdx.x;
    const int z  = blockIdx.z;
    const int n0 = blockIdx.x << 5;
    const int m0 = blockIdx.y << 5;
    const int ty = tid >> 4;          // 0..15  (m pairs)
    const int tx = tid & 15;          // 0..15  (n pairs)

    const int a_slice = z / decK, wk = z - a_slice * decK;
    const float* Ap = Abase + (size_t)a_slice * (size_t)Mslice * (size_t)K;
    const float* Wp = Wt    + (size_t)wk * (size_t)K * (size_t)N;

    const int sr  = tid >> 3;         // 0..31
    const int sc4 = (tid & 7) << 2;   // 0..28

    int mrow = m0 + sr;
    if (mrow > Mslice - 1) mrow = Mslice - 1;
    const float* Arow_p = Ap + (size_t)mrow * K;

    float acc[2][2];
    acc[0][0] = 0.f; acc[0][1] = 0.f; acc[1][0] = 0.f; acc[1][1] = 0.f;

    // ---- prefetch chunk 0 ----
    float4 pa = *(const float4*)(Arow_p + sc4);
    if (bnS != nullptr) bn4(pa, bnS + sc4, bnB + sc4);
    float4 pb = *(const float4*)(Wp + (size_t)sr * N + n0 + sc4);

    for (int k0 = 0; k0 < K; k0 += FBK) {
        __syncthreads();
        As[sc4 + 0][sr] = pa.x;
        As[sc4 + 1][sr] = pa.y;
        As[sc4 + 2][sr] = pa.z;
        As[sc4 + 3][sr] = pa.w;
        *(float4*)&Bs[sr][sc4] = pb;
        const int k0n = k0 + FBK;
        if (k0n < K) {
            pa = *(const float4*)(Arow_p + k0n + sc4);
            if (bnS != nullptr) bn4(pa, bnS + k0n + sc4, bnB + k0n + sc4);
            pb = *(const float4*)(Wp + (size_t)(k0n + sr) * N + n0 + sc4);
        }
        __syncthreads();
#pragma unroll
        for (int kk = 0; kk < FBK; ++kk) {
            float2 av = *(const float2*)&As[kk][ty << 1];
            float2 bv = *(const float2*)&Bs[kk][tx << 1];
            acc[0][0] = fmaf(av.x, bv.x, acc[0][0]);
            acc[0][1] = fmaf(av.x, bv.y, acc[0][1]);
            acc[1][0] = fmaf(av.y, bv.x, acc[1][0]);
            acc[1][1] = fmaf(av.y, bv.y, acc[1][1]);
        }
    }

    if (amin != nullptr) {
        float2 cq = *(const float2*)(codesq + n0 + (tx << 1));
#pragma unroll
        for (int i = 0; i < 2; ++i) {
            const int m = m0 + (ty << 1) + i;
            float d0 = cq.x - 2.f * acc[i][0];
            float d1 = cq.y - 2.f * acc[i][1];
            int bj = (d1 < d0) ? 1 : 0;
            float best = (d1 < d0) ? d1 : d0;
            unsigned u = __float_as_uint(best);
            u = (u & 0x80000000u) ? ~u : (u | 0x80000000u);
            unsigned long long key =
                ((unsigned long long)u << 32) | (unsigned)(n0 + (tx << 1) + bj);
#pragma unroll
            for (int off = 1; off < 16; off <<= 1) {
                unsigned long long o = __shfl_xor(key, off, 64);
                if (o < key) key = o;
            }
            if (tx == 0 && m < Mslice) atomicMin(&amin[m], key);
        }
        return;
    }

#pragma unroll
    for (int i = 0; i < 2; ++i) {
        const int m = m0 + (ty << 1) + i;
        if (m < Mslice) {
            float2 v = make_float2(acc[i][0], acc[i][1]);
            *(float2*)&Cout[((size_t)z * Mslice + m) * N + n0 + (tx << 1)] = v;
        }
    }
}

// ===== bf16 MFMA GEMM, 128x256 tile, gload_lds + 2-phase (out-proj) ========
// 512 threads, 8 waves (2m x 4n), per-wave 64x64, acc[4][4]. LDS:
// As [2][128*64] (32KB), Bs [2][256*64] (64KB) + sc/sh (4KB). A = RAW d3pre
// staged pure-copy; BN+ReLU+bf16 applied per fragment after ds_read
// (bn_on_raw, kbase = t*64 + ub*8; swizzle cancels). B rows clamped to N-1.
__global__ __launch_bounds__(512)
void k_out256(const unsigned short* __restrict__ Ap,
              const unsigned short* __restrict__ Bp,
              float* __restrict__ operm,
              const float* __restrict__ bias,
              const float* __restrict__ stats,
              const float* __restrict__ g, const float* __restrict__ b,
              float inv_n,
              int K, int N)
{
    __shared__ __align__(16) unsigned short As[2][128 * 64];
    __shared__ __align__(16) unsigned short Bs[2][256 * 64];
    __shared__ __align__(16) float scs[512], shs[512];

    const int tid  = threadIdx.x;
    const int lane = tid & 63;
    const int wave = tid >> 6;          // 0..7
    const int wm = (wave >> 2) << 6;    // 0, 64
    const int wn = (wave & 3) << 6;     // 0, 64, 128, 192
    const int m0 = blockIdx.y << 7;

    bn_fin_lds(stats, g, b, inv_n, scs, shs, tid);

    const int srow  = tid >> 3;                       // 0..63 (row within chunk)
    const int selem = ((tid & 7) ^ (srow & 7)) << 3;  // swizzled elem offset
    const unsigned short* Asrc = Ap + (size_t)(m0 + srow) * K + selem;

    size_t boff[4];
#pragma unroll
    for (int c = 0; c < 4; ++c) {
        int brow = srow + (c << 6);
        if (brow > N - 1) brow = N - 1;
        boff[c] = (size_t)brow * K + selem;
    }

    f32x4 acc[4][4];
#pragma unroll
    for (int i = 0; i < 4; ++i)
#pragma unroll
        for (int j = 0; j < 4; ++j) acc[i][j] = (f32x4){0.f, 0.f, 0.f, 0.f};

    const int lidx = lane & 15;
    const int lq   = lane >> 4;

    // ---- prologue: stage chunk 0 into buffer 0 ----
#pragma unroll
    for (int c = 0; c < 2; ++c)
        gload16(Asrc + (size_t)(c << 6) * K, &As[0][tid * 8 + (c << 12)]);
#pragma unroll
    for (int c = 0; c < 4; ++c)
        gload16(Bp + boff[c],                &Bs[0][tid * 8 + (c << 12)]);
    __syncthreads();   // drains staging + makes scs/shs visible

    const int nsteps = K >> 6;
    int cur = 0;
    for (int t = 0; t < nsteps; ++t) {
        if (t + 1 < nsteps) {
            const int k0n = (t + 1) << 6;
#pragma unroll
            for (int c = 0; c < 2; ++c)
                gload16(Asrc + (size_t)(c << 6) * K + k0n,
                        &As[cur ^ 1][tid * 8 + (c << 12)]);
#pragma unroll
            for (int c = 0; c < 4; ++c)
                gload16(Bp + boff[c] + k0n,
                        &Bs[cur ^ 1][tid * 8 + (c << 12)]);
        }
#pragma unroll
        for (int ks = 0; ks < 2; ++ks) {
            const int ub = (ks << 2) + lq;                        // 16B unit idx
            const int uo = (ub ^ (lidx & 7)) << 3;                // swizzled elems
            const int kbase = (t << 6) + (ub << 3);               // global k of af[0]
            bf16x8 af[4], bfv[4];
#pragma unroll
            for (int t4 = 0; t4 < 4; ++t4) {
                af[t4] = *(const bf16x8*)&As[cur][((wm + (t4 << 4) + lidx) << 6) + uo];
                bn_on_raw<1>((uint4*)&af[t4], kbase, scs, shs);
            }
#pragma unroll
            for (int t4 = 0; t4 < 4; ++t4)
                bfv[t4] = *(const bf16x8*)&Bs[cur][((wn + (t4 << 4) + lidx) << 6) + uo];
#pragma unroll
            for (int mt = 0; mt < 4; ++mt)
#pragma unroll
                for (int nt = 0; nt < 4; ++nt)
                    acc[mt][nt] = __builtin_amdgcn_mfma_f32_16x16x32_bf16(
                        af[mt], bfv[nt], acc[mt][nt], 0, 0, 0);
        }
        __syncthreads();
        cur ^= 1;
    }

    const int rbase = lq << 2;
#pragma unroll
    for (int nt = 0; nt < 4; ++nt) {
        const int col = wn + (nt << 4) + lidx;
        if (col >= N) continue;
        const float badd = (bias != nullptr) ? bias[col] : 0.f;
#pragma unroll
        for (int mt = 0; mt < 4; ++mt) {
#pragma unroll
            for (int r = 0; r < 4; ++r) {
                float x = acc[mt][nt][r];
                const int row = m0 + wm + (mt << 4) + rbase + r;
                const int t = row >> 10, bb = row & 1023;
                operm[(size_t)bb * 4050 + t * 135 + col] = x + badd;
            }
        }
    }
}

// ===== bf16 MFMA GEMM, 256x256 tile, gload_lds + 2-phase (d3) ==============
__global__ __launch_bounds__(512)
void k_m256(const unsigned short* __restrict__ Abase,
            const unsigned short* __restrict__ Bt,
            unsigned short* __restrict__ Cb,
            float* __restrict__ stats,
            int Mslice, int K, int N, int decK)
{
    __shared__ __align__(16) unsigned short As[2][256 * 64];
    __shared__ __align__(16) unsigned short Bs[2][256 * 64];
    __shared__ float colsum[256], colsq[256];

    const int tid  = threadIdx.x;
    const int lane = tid & 63;
    const int wave = tid >> 6;          // 0..7
    const int wm = (wave >> 2) << 7;    // 0,128
    const int wn = (wave & 3) << 6;     // 0,64,128,192
    const int z  = blockIdx.z;
    const int n0 = blockIdx.x << 8;
    const int m0 = blockIdx.y << 8;

    if (stats != nullptr && tid < 256) { colsum[tid] = 0.f; colsq[tid] = 0.f; }

    const int a_slice = z / decK, wk = z - a_slice * decK;
    const unsigned short* Ap = Abase + (size_t)a_slice * (size_t)Mslice * (size_t)K;
    const unsigned short* Bp = Bt + (size_t)wk * (size_t)N * (size_t)K;

    const int srow  = tid >> 3;                       // 0..63 (row within chunk)
    const int selem = ((tid & 7) ^ (srow & 7)) << 3;  // swizzled elem offset
    const unsigned short* Asrc = Ap + (size_t)(m0 + srow) * K + selem;

    size_t boff[4];
#pragma unroll
    for (int c = 0; c < 4; ++c) {
        int brow = n0 + srow + (c << 6);
        if (brow > N - 1) brow = N - 1;
        boff[c] = (size_t)brow * K + selem;
    }

    f32x4 acc[8][4];
#pragma unroll
    for (int i = 0; i < 8; ++i)
#pragma unroll
        for (int j = 0; j < 4; ++j) acc[i][j] = (f32x4){0.f, 0.f, 0.f, 0.f};

    const int lidx = lane & 15;
    const int lq   = lane >> 4;

    // ---- prologue: stage chunk 0 into buffer 0 ----
#pragma unroll
    for (int c = 0; c < 4; ++c) {
        gload16(Asrc + (size_t)(c << 6) * K, &As[0][tid * 8 + (c << 12)]);
        gload16(Bp + boff[c],                &Bs[0][tid * 8 + (c << 12)]);
    }
    __syncthreads();

    const int nsteps = K >> 6;
    int cur = 0;
    for (int t = 0; t < nsteps; ++t) {
        if (t + 1 < nsteps) {
            const int k0n = (t + 1) << 6;
#pragma unroll
            for (int c = 0; c < 4; ++c) {
                gload16(Asrc + (size_t)(c << 6) * K + k0n,
                        &As[cur ^ 1][tid * 8 + (c << 12)]);
                gload16(Bp + boff[c] + k0n,
                        &Bs[cur ^ 1][tid * 8 + (c << 12)]);
            }
        }
#pragma unroll
        for (int ks = 0; ks < 2; ++ks) {
            const int ub = (ks << 2) + lq;                        // 16B unit idx
            const int uo = (ub ^ (lidx & 7)) << 3;                // swizzled elems
            bf16x8 af[8], bfv[4];
#pragma unroll
            for (int i = 0; i < 8; ++i)
                af[i] = *(const bf16x8*)&As[cur][((wm + (i << 4) + lidx) << 6) + uo];
#pragma unroll
            for (int j = 0; j < 4; ++j)
                bfv[j] = *(const bf16x8*)&Bs[cur][((wn + (j << 4) + lidx) << 6) + uo];
#pragma unroll
            for (int mt = 0; mt < 8; ++mt)
#pragma unroll
                for (int nt = 0; nt < 4; ++nt)
                    acc[mt][nt] = __builtin_amdgcn_mfma_f32_16x16x32_bf16(
                        af[mt], bfv[nt], acc[mt][nt], 0, 0, 0);
        }
        __syncthreads();
        cur ^= 1;
    }

    const int rbase = lq << 2;
#pragma unroll
    for (int nt = 0; nt < 4; ++nt) {
        const int col = n0 + wn + (nt << 4) + lidx;
        float s = 0.f, q = 0.f;
#pragma unroll
        for (int mt = 0; mt < 8; ++mt) {
#pragma unroll
            for (int r = 0; r < 4; ++r) {
                float x = acc[mt][nt][r];
                s += x; q += x * x;
                const int row = m0 + wm + (mt << 4) + rbase + r;
                Cb[((size_t)z * Mslice + row) * (size_t)N + col] = bfh(x);
            }
        }
        if (stats != nullptr) {
            s += __shfl_xor(s, 16, 64); s += __shfl_xor(s, 32, 64);
            q += __shfl_xor(q, 16, 64); q += __shfl_xor(q, 32, 64);
            if (lq == 0) {
                atomicAdd(&colsum[wn + (nt << 4) + lidx], s);
                atomicAdd(&colsq [wn + (nt << 4) + lidx], q);
            }
        }
    }
    if (stats != nullptr) {
        __syncthreads();
        if (tid < 256) {
            atomicAdd(&stats[n0 + tid],       colsum[tid]);
            atomicAdd(&stats[512 + n0 + tid], colsq[tid]);
        }
    }
}

// ===== bf16 MFMA GEMM, 64x64 tile, gload_lds + 2-phase (d0,d1,d2) ==========
__global__ __launch_bounds__(256)
void k_b64g(const unsigned short* __restrict__ Abase,
            const unsigned short* __restrict__ Bt,
            unsigned short* __restrict__ Cb,
            const float* __restrict__ bias,
            float* __restrict__ stats,
            int Mslice, int K, int N, int decK)
{
    __shared__ __align__(16) unsigned short As[2][64 * 64];
    __shared__ __align__(16) unsigned short Bs[2][64 * 64];
    __shared__ float colsum[64], colsq[64];

    const int tid  = threadIdx.x;
    const int lane = tid & 63;
    const int wave = tid >> 6;
    const int wm = (wave >> 1) << 5;
    const int wn = (wave & 1) << 5;
    const int z  = blockIdx.z;
    const int n0 = blockIdx.x << 6;
    const int m0 = blockIdx.y << 6;

    if (stats != nullptr && tid < 64) { colsum[tid] = 0.f; colsq[tid] = 0.f; }

    const int a_slice = z / decK, wk = z - a_slice * decK;
    const unsigned short* Ap = Abase + (size_t)a_slice * (size_t)Mslice * (size_t)K;
    const unsigned short* Bp = Bt + (size_t)wk * (size_t)N * (size_t)K;

    const int srow  = tid >> 3;                       // 0..31
    const int selem = ((tid & 7) ^ (srow & 7)) << 3;
    const unsigned short* Asrc = Ap + (size_t)(m0 + srow) * K + selem;
    const unsigned short* Bsrc = Bp + (size_t)(n0 + srow) * K + selem;

    f32x4 acc[2][2];
#pragma unroll
    for (int i = 0; i < 2; ++i)
#pragma unroll
        for (int j = 0; j < 2; ++j) acc[i][j] = (f32x4){0.f, 0.f, 0.f, 0.f};

    const int lidx = lane & 15;
    const int lq   = lane >> 4;

    // ---- prologue: stage chunk 0 into buffer 0 ----
#pragma unroll
    for (int c = 0; c < 2; ++c) {
        gload16(Asrc + (size_t)(c << 5) * K, &As[0][tid * 8 + (c << 11)]);
        gload16(Bsrc + (size_t)(c << 5) * K, &Bs[0][tid * 8 + (c << 11)]);
    }
    __syncthreads();

    const int nsteps = K >> 6;
    int cur = 0;
    for (int t = 0; t < nsteps; ++t) {
        if (t + 1 < nsteps) {
            const int k0n = (t + 1) << 6;
#pragma unroll
            for (int c = 0; c < 2; ++c) {
                gload16(Asrc + (size_t)(c << 5) * K + k0n,
                        &As[cur ^ 1][tid * 8 + (c << 11)]);
                gload16(Bsrc + (size_t)(c << 5) * K + k0n,
                        &Bs[cur ^ 1][tid * 8 + (c << 11)]);
            }
        }
#pragma unroll
        for (int ks = 0; ks < 2; ++ks) {
            const int ub = (ks << 2) + lq;
            const int uo = (ub ^ (lidx & 7)) << 3;
            bf16x8 af[2], bfv[2];
#pragma unroll
            for (int t2 = 0; t2 < 2; ++t2)
                af[t2] = *(const bf16x8*)&As[cur][((wm + (t2 << 4) + lidx) << 6) + uo];
#pragma unroll
            for (int t2 = 0; t2 < 2; ++t2)
                bfv[t2] = *(const bf16x8*)&Bs[cur][((wn + (t2 << 4) + lidx) << 6) + uo];
#pragma unroll
            for (int mt = 0; mt < 2; ++mt)
#pragma unroll
                for (int nt = 0; nt < 2; ++nt)
                    acc[mt][nt] = __builtin_amdgcn_mfma_f32_16x16x32_bf16(
                        af[mt], bfv[nt], acc[mt][nt], 0, 0, 0);
        }
        __syncthreads();
        cur ^= 1;
    }

    const int rbase = lq << 2;
#pragma unroll
    for (int nt = 0; nt < 2; ++nt) {
        const int col = n0 + wn + (nt << 4) + lidx;
        const float badd = (bias != nullptr) ? bias[col] : 0.f;
        float s = 0.f, q = 0.f;
#pragma unroll
        for (int mt = 0; mt < 2; ++mt) {
#pragma unroll
            for (int r = 0; r < 4; ++r) {
                float x = acc[mt][nt][r];
                s += x; q += x * x;
                const int row = m0 + wm + (mt << 4) + rbase + r;
                Cb[((size_t)z * Mslice + row) * (size_t)N + col] = bfh(x + badd);
            }
        }
        if (stats != nullptr) {
            s += __shfl_xor(s, 16, 64); s += __shfl_xor(s, 32, 64);
            q += __shfl_xor(q, 16, 64); q += __shfl_xor(q, 32, 64);
            if (lq == 0) {
                atomicAdd(&colsum[wn + (nt << 4) + lidx], s);
                atomicAdd(&colsq [wn + (nt << 4) + lidx], q);
            }
        }
    }
    if (stats != nullptr) {
        __syncthreads();
        if (tid < 64) {
            atomicAdd(&stats[n0 + tid],       colsum[tid]);
            atomicAdd(&stats[512 + n0 + tid], colsq[tid]);
        }
    }
}

// ===== split-bf16 MFMA GEMM, 64x64 tile, gload_lds + 2-phase (e2,e3) =======
// Linear LDS [2][64][32] bf16 per buffer; XOR-swizzle unit^(row&3).
__global__ __launch_bounds__(256)
void k_sp64g(const unsigned short* __restrict__ Ahg,
             const unsigned short* __restrict__ Alg,
             const unsigned short* __restrict__ Whi,
             const unsigned short* __restrict__ Wlo,
             float* __restrict__ Cout, float* __restrict__ stats,
             int Mslice, int Kp, int N, int n_terms)
{
    __shared__ __align__(16) unsigned short Ah[2][64 * 32];
    __shared__ __align__(16) unsigned short Al[2][64 * 32];
    __shared__ __align__(16) unsigned short Bh[2][64 * 32];
    __shared__ __align__(16) unsigned short Bl[2][64 * 32];
    __shared__ float colsum[64], colsq[64];

    const int tid  = threadIdx.x;
    const int lane = tid & 63;
    const int wave = tid >> 6;
    const int wm = (wave >> 1) << 5;
    const int wn = (wave & 1) << 5;
    const int z  = blockIdx.z;
    const int n0 = blockIdx.x << 6;
    const int m0 = blockIdx.y << 6;

    if (stats != nullptr && tid < 64) { colsum[tid] = 0.f; colsq[tid] = 0.f; }

    const int srow  = tid >> 2;                       // 0..63
    const int selem = ((tid & 3) ^ (srow & 3)) << 3;  // swizzled elem in 32-row

    f32x4 acc[2][2];
#pragma unroll
    for (int i = 0; i < 2; ++i)
#pragma unroll
        for (int j = 0; j < 2; ++j) acc[i][j] = (f32x4){0.f, 0.f, 0.f, 0.f};

    const int lidx = lane & 15;
    const int lq   = lane >> 4;
    const int uo   = (lq ^ (lidx & 3)) << 3;          // swizzled read offset

    const int cpk = Kp >> 5;
    const int tot = n_terms * cpk;

    // ---- prologue: stage chunk 0 (term 0, k 0) into buffer 0 ----
    {
        const size_t ab = ((size_t)(z * n_terms) * Mslice + m0 + srow)
                          * (size_t)Kp + selem;
        const size_t bb = ((size_t)(n0 + srow)) * (size_t)Kp + selem;
        gload16(Ahg + ab, &Ah[0][tid * 8]);
        gload16(Alg + ab, &Al[0][tid * 8]);
        gload16(Whi + bb, &Bh[0][tid * 8]);
        gload16(Wlo + bb, &Bl[0][tid * 8]);
    }
    __syncthreads();

    int cur = 0;
    int lt = 0, lk = 32;
    if (lk >= Kp) { lk = 0; lt = 1; }
    for (int c = 0; c < tot; ++c) {
        if (c + 1 < tot) {
            const size_t ab = ((size_t)(z * n_terms + lt) * Mslice + m0 + srow)
                              * (size_t)Kp + lk + selem;
            const size_t bb = ((size_t)lt * N + n0 + srow) * (size_t)Kp + lk + selem;
            gload16(Ahg + ab, &Ah[cur ^ 1][tid * 8]);
            gload16(Alg + ab, &Al[cur ^ 1][tid * 8]);
            gload16(Whi + bb, &Bh[cur ^ 1][tid * 8]);
            gload16(Wlo + bb, &Bl[cur ^ 1][tid * 8]);
            lk += 32; if (lk >= Kp) { lk = 0; ++lt; }
        }
        bf16x8 ah[2], al[2], bh[2], bl[2];
#pragma unroll
        for (int t = 0; t < 2; ++t) {
            const int ra = ((wm + (t << 4) + lidx) << 5) + uo;
            ah[t] = *(const bf16x8*)&Ah[cur][ra];
            al[t] = *(const bf16x8*)&Al[cur][ra];
        }
#pragma unroll
        for (int t = 0; t < 2; ++t) {
            const int rb = ((wn + (t << 4) + lidx) << 5) + uo;
            bh[t] = *(const bf16x8*)&Bh[cur][rb];
            bl[t] = *(const bf16x8*)&Bl[cur][rb];
        }
#pragma unroll
        for (int mt = 0; mt < 2; ++mt)
#pragma unroll
            for (int nt = 0; nt < 2; ++nt) {
                acc[mt][nt] = __builtin_amdgcn_mfma_f32_16x16x32_bf16(
                    ah[mt], bh[nt], acc[mt][nt], 0, 0, 0);
                acc[mt][nt] = __builtin_amdgcn_mfma_f32_16x16x32_bf16(
                    al[mt], bh[nt], acc[mt][nt], 0, 0, 0);
                acc[mt][nt] = __builtin_amdgcn_mfma_f32_16x16x32_bf16(
                    ah[mt], bl[nt], acc[mt][nt], 0, 0, 0);
            }
        __syncthreads();
        cur ^= 1;
    }

    const int rbase = lq << 2;
#pragma unroll
    for (int nt = 0; nt < 2; ++nt) {
        const int col = n0 + wn + (nt << 4) + lidx;
        float s = 0.f, q = 0.f;
#pragma unroll
        for (int mt = 0; mt < 2; ++mt) {
#pragma unroll
            for (int r = 0; r < 4; ++r) {
                float x = acc[mt][nt][r];
                s += x; q += x * x;
                const int row = m0 + wm + (mt << 4) + rbase + r;
                Cout[((size_t)z * Mslice + row) * (size_t)N + col] = x;
            }
        }
        if (stats != nullptr) {
            s += __shfl_xor(s, 16, 64); s += __shfl_xor(s, 32, 64);
            q += __shfl_xor(q, 16, 64); q += __shfl_xor(q, 32, 64);
            if (lq == 0) {
                atomicAdd(&colsum[wn + (nt << 4) + lidx], s);
                atomicAdd(&colsq [wn + (nt << 4) + lidx], q);
            }
        }
    }
    if (stats != nullptr) {
        __syncthreads();
        if (tid < 64) {
            atomicAdd(&stats[n0 + tid],       colsum[tid]);
            atomicAdd(&stats[512 + n0 + tid], colsq[tid]);
        }
    }
}

// ===== split-bf16 MFMA GEMM, 64x128 tile, gload_lds + 2-phase (e1) =========
__global__ __launch_bounds__(256)
void k_sp64w(const unsigned short* __restrict__ Ahg,
             const unsigned short* __restrict__ Alg,
             const unsigned short* __restrict__ Whi,
             const unsigned short* __restrict__ Wlo,
             float* __restrict__ Cout, float* __restrict__ stats,
             int Mslice, int Kp, int N, int n_terms)
{
    __shared__ __align__(16) unsigned short Ah[2][64 * 32];
    __shared__ __align__(16) unsigned short Al[2][64 * 32];
    __shared__ __align__(16) unsigned short Bh[2][128 * 32];
    __shared__ __align__(16) unsigned short Bl[2][128 * 32];
    __shared__ float colsum[128], colsq[128];

    const int tid  = threadIdx.x;
    const int lane = tid & 63;
    const int wave = tid >> 6;          // 0..3
    const int wm = (wave >> 1) << 5;    // 0, 32
    const int wn = (wave & 1) << 6;     // 0, 64
    const int z  = blockIdx.z;
    const int n0 = blockIdx.x << 7;     // 4 n-blocks x 128
    const int m0 = blockIdx.y << 6;     // 16 m-blocks x 64

    if (stats != nullptr && tid < 128) { colsum[tid] = 0.f; colsq[tid] = 0.f; }

    const int srow  = tid >> 2;                       // 0..63
    const int selem = ((tid & 3) ^ (srow & 3)) << 3;  // swizzled elem in 32-row

    f32x4 acc[2][4];
#pragma unroll
    for (int i = 0; i < 2; ++i)
#pragma unroll
        for (int j = 0; j < 4; ++j) acc[i][j] = (f32x4){0.f, 0.f, 0.f, 0.f};

    const int lidx = lane & 15;
    const int lq   = lane >> 4;
    const int uo   = (lq ^ (lidx & 3)) << 3;          // swizzled read offset

    const int cpk = Kp >> 5;
    const int tot = n_terms * cpk;

    // ---- prologue: stage chunk 0 (term 0, k 0) into buffer 0 ----
    {
        const size_t ab = ((size_t)(z * n_terms) * Mslice + m0 + srow)
                          * (size_t)Kp + selem;
        gload16(Ahg + ab, &Ah[0][tid * 8]);
        gload16(Alg + ab, &Al[0][tid * 8]);
#pragma unroll
        for (int c = 0; c < 2; ++c) {
            const int rowB = (c << 6) + srow;
            const size_t bb = ((size_t)(n0 + rowB)) * (size_t)Kp + selem;
            gload16(Whi + bb, &Bh[0][tid * 8 + (c << 11)]);
            gload16(Wlo + bb, &Bl[0][tid * 8 + (c << 11)]);
        }
    }
    __syncthreads();

    int cur = 0;
    int lt = 0, lk = 32;
    if (lk >= Kp) { lk = 0; lt = 1; }
    for (int c = 0; c < tot; ++c) {
        if (c + 1 < tot) {
            const size_t ab = ((size_t)(z * n_terms + lt) * Mslice + m0 + srow)
                              * (size_t)Kp + lk + selem;
            gload16(Ahg + ab, &Ah[cur ^ 1][tid * 8]);
            gload16(Alg + ab, &Al[cur ^ 1][tid * 8]);
#pragma unroll
            for (int cc = 0; cc < 2; ++cc) {
                const int rowB = (cc << 6) + srow;
                const size_t bb = ((size_t)lt * N + n0 + rowB) * (size_t)Kp
                                  + lk + selem;
                gload16(Whi + bb, &Bh[cur ^ 1][tid * 8 + (cc << 11)]);
                gload16(Wlo + bb, &Bl[cur ^ 1][tid * 8 + (cc << 11)]);
            }
            lk += 32; if (lk >= Kp) { lk = 0; ++lt; }
        }
        bf16x8 ah[2], al[2], bh[4], bl[4];
#pragma unroll
        for (int t = 0; t < 2; ++t) {
            const int ra = ((wm + (t << 4) + lidx) << 5) + uo;
            ah[t] = *(const bf16x8*)&Ah[cur][ra];
            al[t] = *(const bf16x8*)&Al[cur][ra];
        }
#pragma unroll
        for (int t = 0; t < 4; ++t) {
            const int rb = ((wn + (t << 4) + lidx) << 5) + uo;
            bh[t] = *(const bf16x8*)&Bh[cur][rb];
            bl[t] = *(const bf16x8*)&Bl[cur][rb];
        }
#pragma unroll
        for (int mt = 0; mt < 2; ++mt)
#pragma unroll
            for (int nt = 0; nt < 4; ++nt) {
                acc[mt][nt] = __builtin_amdgcn_mfma_f32_16x16x32_bf16(
                    ah[mt], bh[nt], acc[mt][nt], 0, 0, 0);
                acc[mt][nt] = __builtin_amdgcn_mfma_f32_16x16x32_bf16(
                    al[mt], bh[nt], acc[mt][nt], 0, 0, 0);
                acc[mt][nt] = __builtin_amdgcn_mfma_f32_16x16x32_bf16(
                    ah[mt], bl[nt], acc[mt][nt], 0, 0, 0);
            }
        __syncthreads();
        cur ^= 1;
    }

    const int rbase = lq << 2;
#pragma unroll
    for (int nt = 0; nt < 4; ++nt) {
        const int col = n0 + wn + (nt << 4) + lidx;
        float s = 0.f, q = 0.f;
#pragma unroll
        for (int mt = 0; mt < 2; ++mt) {
#pragma unroll
            for (int r = 0; r < 4; ++r) {
                float x = acc[mt][nt][r];
                s += x; q += x * x;
                const int row = m0 + wm + (mt << 4) + rbase + r;
                Cout[((size_t)z * Mslice + row) * (size_t)N + col] = x;
            }
        }
        if (stats != nullptr) {
            s += __shfl_xor(s, 16, 64); s += __shfl_xor(s, 32, 64);
            q += __shfl_xor(q, 16, 64); q += __shfl_xor(q, 32, 64);
            if (lq == 0) {
                atomicAdd(&colsum[wn + (nt << 4) + lidx], s);
                atomicAdd(&colsq [wn + (nt << 4) + lidx], q);
            }
        }
    }
    if (stats != nullptr) {
        __syncthreads();
        if (tid < 128) {
            atomicAdd(&stats[n0 + tid],       colsum[tid]);
            atomicAdd(&stats[512 + n0 + tid], colsq[tid]);
        }
    }
}

// ======== merged prep kernel (10 independent preps, incl. sp_weff) =========
__global__ void k_prep(float* __restrict__ zbase, unsigned long long* __restrict__ amin,
                       const float* __restrict__ codebook, float* __restrict__ codeT,
                       float* __restrict__ codesq,
                       const float* __restrict__ w_e2, unsigned short* __restrict__ whi_e2,
                       unsigned short* __restrict__ wlo_e2,
                       const float* __restrict__ w_e3, unsigned short* __restrict__ whi_e3,
                       unsigned short* __restrict__ wlo_e3,
                       const float* __restrict__ W_q,  unsigned short* __restrict__ wqb,
                       const float* __restrict__ w_d1, unsigned short* __restrict__ wd1b,
                       const float* __restrict__ w_d2, unsigned short* __restrict__ wd2b,
                       const float* __restrict__ w_d3, unsigned short* __restrict__ wd3b,
                       const float* __restrict__ W_out, unsigned short* __restrict__ woutb,
                       const float* __restrict__ in_seqs,
                       unsigned short* __restrict__ in_h, unsigned short* __restrict__ in_l,
                       const float* __restrict__ weff,
                       unsigned short* __restrict__ whi_e1,
                       unsigned short* __restrict__ wlo_e1)
{
    __shared__ float red[4];
    const int bid = blockIdx.x;
    const int tid = threadIdx.x;

    if (bid < 32) {                                    // s0: init
        int t = bid * 256 + tid;
        if (t < 6720) zbase[t] = 0.f;
        if (t < 1024) amin[t] = ~0ULL;
        return;
    }
    if (bid < 1056) {                                  // s1: codeT repack (Kc=1)
        int idx = (bid - 32) * 256 + tid;
        int i = (idx >> 9) & 511, o = idx & 511;
        codeT[idx] = codebook[(o << 9) + i];
        return;
    }
    if (bid < 1568) {                                  // s2: codesq
        int c = bid - 1056;
        float s = 0.f;
        for (int i = tid; i < 512; i += 256) { float v = codebook[c * 512 + i]; s += v * v; }
        for (int off = 32; off; off >>= 1) s += __shfl_down(s, off, 64);
        if ((tid & 63) == 0) red[tid >> 6] = s;
        __syncthreads();
        if (tid == 0) codesq[c] = red[0] + red[1] + red[2] + red[3];
        return;
    }
    if (bid < 4640) {                                  // s3: split e2 (Kc=3)
        int idx = (bid - 1568) * 256 + tid;
        int i = idx & 511, o = (idx >> 9) & 511, k = idx >> 18;
        float v = w_e2[(((o << 9) + i) * 3) + k];
        unsigned short h = bfh(v);
        whi_e2[idx] = h; wlo_e2[idx] = bfh(v - bf2f(h));
        return;
    }
    if (bid < 6688) {                                  // s4: split e3 (Kc=2)
        int idx = (bid - 4640) * 256 + tid;
        int i = idx & 511, o = (idx >> 9) & 511, k = idx >> 18;
        float v = w_e3[(((o << 9) + i) * 2) + k];
        unsigned short h = bfh(v);
        whi_e3[idx] = h; wlo_e3[idx] = bfh(v - bf2f(h));
        return;
    }
    if (bid < 7712) {                                  // s5: W_q bf (Kc=1,I=O=512)
        int idx = (bid - 6688) * 256 + tid;
        int i = idx & 511, o = (idx >> 9) & 511;
        wqb[idx] = bfh(W_q[((size_t)i << 9) + o]);
        return;
    }
    if (bid < 9760) {                                  // s6: w_d1 bf (Kc=2)
        int idx = (bid - 7712) * 256 + tid;
        int i = idx & 511, o = (idx >> 9) & 511, k = idx >> 18;
        wd1b[idx] = bfh(w_d1[(((size_t)i << 9) + o) * 2 + k]);
        return;
    }
    if (bid < 12832) {                                 // s7: w_d2 bf (Kc=3)
        int idx = (bid - 9760) * 256 + tid;
        int i = idx & 511, o = (idx >> 9) & 511, k = idx >> 18;
        wd2b[idx] = bfh(w_d2[(((size_t)i << 9) + o) * 3 + k]);
        return;
    }
    if (bid < 17952) {                                 // s8: w_d3 bf (Kc=5)
        int idx = (bid - 12832) * 256 + tid;
        int i = idx & 511, o = (idx >> 9) & 511, k = idx >> 18;
        wd3b[idx] = bfh(w_d3[(((size_t)i << 9) + o) * 5 + k]);
        return;
    }
    if (bid < 18222) {                                 // s9: W_out bf (Kc=1,I=512,O=135)
        int idx = (bid - 17952) * 256 + tid;
        if (idx >= 69120) return;
        int i = idx % 512, o = idx / 512;              // [o][i], o<135
        woutb[idx] = bfh(W_out[((size_t)i * 135) + o]);
        return;
    }
    if (bid < 37422) {                                 // s10: split_in
        int idx = (bid - 18222) * 256 + tid;
        int i = idx % 160, r = idx / 160;
        float v = (i < 135) ? in_seqs[(size_t)r * 135 + i] : 0.f;
        unsigned short h = bfh(v);
        in_h[idx] = h; in_l[idx] = bfh(v - bf2f(h));
        return;
    }
    {                                                  // s11: sp_weff
        int idx = (bid - 37422) * 256 + tid;
        if (idx >= 409600) return;
        int i = idx % 160;
        int o = (idx / 160) & 511;
        int t = idx / 81920;
        float v = (i < 135) ? weff[((size_t)t * 135 + i) * 512 + o] : 0.f;
        unsigned short h = bfh(v);
        whi_e1[idx] = h;
        wlo_e1[idx] = bfh(v - bf2f(h));
    }
}

// ============================ small kernels ================================
__global__ void k_repack(const float* __restrict__ w, float* __restrict__ wt,
                         int Kc, int total)
{
    int idx = blockIdx.x * 256 + threadIdx.x;
    if (idx >= total) return;
    int k = idx >> 18;
    int rem = idx & 262143;
    int i = rem >> 9, o = rem & 511;
    wt[idx] = w[(((o << 9) + i) * Kc + k)];
}

// BN-finalize fused: compute sc/sh in LDS (identical math), split to hi/lo
__global__ void k_bnsplit(const float* __restrict__ x,
                          const float* __restrict__ stats,
                          const float* __restrict__ g, const float* __restrict__ b,
                          float inv_n,
                          unsigned short* __restrict__ hq, unsigned short* __restrict__ lq_,
                          int total4)
{
    __shared__ __align__(16) float scs[512], shs[512];
    const int tid = threadIdx.x;
    bn_fin_lds(stats, g, b, inv_n, scs, shs, tid);
    __syncthreads();

    int idx = blockIdx.x * 256 + tid;
    if (idx >= total4) return;
    const int base = idx << 2;
    float4 f = *(const float4*)(x + base);
    const int k = base & 511;
    float4 s = *(const float4*)&scs[k];
    float4 c = *(const float4*)&shs[k];
    float y0 = fmaxf(fmaf(f.x, s.x, c.x), 0.f);
    float y1 = fmaxf(fmaf(f.y, s.y, c.y), 0.f);
    float y2 = fmaxf(fmaf(f.z, s.z, c.z), 0.f);
    float y3 = fmaxf(fmaf(f.w, s.w, c.w), 0.f);
    unsigned short h0 = bfh(y0), h1 = bfh(y1), h2 = bfh(y2), h3 = bfh(y3);
    unsigned short l0 = bfh(y0 - bf2f(h0)), l1 = bfh(y1 - bf2f(h1));
    unsigned short l2 = bfh(y2 - bf2f(h2)), l3 = bfh(y3 - bf2f(h3));
    *(uint2*)&hq[base]  = make_uint2((unsigned)h0 | ((unsigned)h1 << 16),
                                     (unsigned)h2 | ((unsigned)h3 << 16));
    *(uint2*)&lq_[base] = make_uint2((unsigned)l0 | ((unsigned)l1 << 16),
                                     (unsigned)l2 | ((unsigned)l3 << 16));
}

// BN-finalize fused: compute sc/sh in LDS, apply BN+ReLU, emit bf16
__global__ void k_bnapply(const unsigned short* __restrict__ x,
                          const float* __restrict__ stats,
                          const float* __restrict__ g, const float* __restrict__ b,
                          float inv_n,
                          unsigned short* __restrict__ y, int total8)
{
    __shared__ __align__(16) float scs[512], shs[512];
    const int tid = threadIdx.x;
    bn_fin_lds(stats, g, b, inv_n, scs, shs, tid);
    __syncthreads();

    int idx = blockIdx.x * 256 + tid;
    if (idx >= total8) return;
    const int base = idx << 3;
    uint4 raw = *(const uint4*)(x + base);
    const int k = base & 511;
    float4 s0 = *(const float4*)&scs[k];
    float4 c0 = *(const float4*)&shs[k];
    float4 s1 = *(const float4*)&scs[k + 4];
    float4 c1 = *(const float4*)&shs[k + 4];
    unsigned* u = (unsigned*)&raw;
    float x0 = __uint_as_float(u[0] << 16),        x1 = __uint_as_float(u[0] & 0xffff0000u);
    float x2 = __uint_as_float(u[1] << 16),        x3 = __uint_as_float(u[1] & 0xffff0000u);
    float x4 = __uint_as_float(u[2] << 16),        x5 = __uint_as_float(u[2] & 0xffff0000u);
    float x6 = __uint_as_float(u[3] << 16),        x7 = __uint_as_float(u[3] & 0xffff0000u);
    x0 = fmaxf(fmaf(x0, s0.x, c0.x), 0.f); x1 = fmaxf(fmaf(x1, s0.y, c0.y), 0.f);
    x2 = fmaxf(fmaf(x2, s0.z, c0.z), 0.f); x3 = fmaxf(fmaf(x3, s0.w, c0.w), 0.f);
    x4 = fmaxf(fmaf(x4, s1.x, c1.x), 0.f); x5 = fmaxf(fmaf(x5, s1.y, c1.y), 0.f);
    x6 = fmaxf(fmaf(x6, s1.z, c1.z), 0.f); x7 = fmaxf(fmaf(x7, s1.w, c1.w), 0.f);
    *(uint4*)&y[base] = make_uint4(pk_bf16(x0, x1), pk_bf16(x2, x3),
                                   pk_bf16(x4, x5), pk_bf16(x6, x7));
}

__global__ void k_bn_fin(const float* __restrict__ stats,
                         const float* __restrict__ g, const float* __restrict__ b,
                         float* __restrict__ sc, float* __restrict__ sh, float inv_n)
{
    int c = blockIdx.x * blockDim.x + threadIdx.x;
    if (c >= 512) return;
    float m = stats[c] * inv_n;
    float v = stats[512 + c] * inv_n - m * m;
    float a = (float)((double)g[c] / sqrt((double)v + 1e-5));
    sc[c] = a;
    sh[c] = b[c] - m * a;
}

__global__ void k_vq_gather(const unsigned long long* __restrict__ amin,
                            const float* __restrict__ codebook,
                            const float* __restrict__ e3pre,
                            const float* __restrict__ sc, const float* __restrict__ sh,
                            unsigned short* __restrict__ quant_bf,
                            float* __restrict__ loss,
                            unsigned int* __restrict__ hist)
{
    int b = blockIdx.x; int t = threadIdx.x;   // 256 threads
    unsigned int idx = (unsigned int)(amin[b] & 0xFFFFFFFFull) & 511u;
    float part = 0.f;
    for (int i = t; i < 512; i += 256) {
        float q = codebook[(size_t)idx * 512 + i];
        quant_bf[(size_t)b * 512 + i] = bfh(q);
        float x = e3pre[(size_t)b * 512 + i];
        float f = fmaxf(fmaf(x, sc[i], sh[i]), 0.f);
        float d = q - f;
        part += d * d;
    }
    for (int off = 32; off; off >>= 1) part += __shfl_down(part, off, 64);
    __shared__ float red[4];
    if ((t & 63) == 0) red[t >> 6] = part;
    __syncthreads();
    if (t == 0) {
        atomicAdd(loss, red[0] + red[1] + red[2] + red[3]);
        atomicAdd(&hist[idx], 1u);
    }
}

__global__ void k_scalars(const unsigned int* __restrict__ hist,
                          const float* __restrict__ loss, float* __restrict__ out)
{
    int t = threadIdx.x;   // 512
    float p = (float)hist[t] * (1.0f / 1024.0f);
    float e = p * logf(p + 1e-10f);
    for (int off = 32; off; off >>= 1) e += __shfl_down(e, off, 64);
    __shared__ float red[8];
    if ((t & 63) == 0) red[t >> 6] = e;
    __syncthreads();
    if (t == 0) {
        float s = 0.f;
        for (int i = 0; i < 8; ++i) s += red[i];
        out[4147200] = 1.25f * loss[0] * (1.0f / 524288.0f);
        out[4147201] = expf(-s);
    }
}

extern "C" void kernel_launch(void* const* d_in, const int* in_sizes, int n_in,
                              void* d_out, int out_size, void* d_ws, size_t ws_size,
                              hipStream_t stream)
{
    const float* in_seqs = (const float*)d_in[0];
    const float* W_in  = (const float*)d_in[1];
    const float* w_e1  = (const float*)d_in[3];
    const float* g_e1  = (const float*)d_in[4];
    const float* be1   = (const float*)d_in[5];
    const float* w_e2  = (const float*)d_in[6];
    const float* g_e2  = (const float*)d_in[7];
    const float* be2   = (const float*)d_in[8];
    const float* w_e3  = (const float*)d_in[9];
    const float* g_e3  = (const float*)d_in[10];
    const float* be3   = (const float*)d_in[11];
    const float* codebook = (const float*)d_in[12];
    const float* W_q   = (const float*)d_in[13];
    const float* b_q   = (const float*)d_in[14];
    const float* w_d1  = (const float*)d_in[15];
    const float* g_d1  = (const float*)d_in[16];
    const float* bd1   = (const float*)d_in[17];
    const float* w_d2  = (const float*)d_in[18];
    const float* g_d2  = (const float*)d_in[19];
    const float* bd2   = (const float*)d_in[20];
    const float* w_d3  = (const float*)d_in[21];
    const float* g_d3  = (const float*)d_in[22];
    const float* bd3   = (const float*)d_in[23];
    const float* W_out = (const float*)d_in[24];
    const float* b_out = (const float*)d_in[25];
    float* out = (float*)d_out;

    // ---- workspace layout (float offsets) ----
    float* W = (float*)d_ws;
    unsigned long long* amin = (unsigned long long*)W;            // 2048 f
    float* stats  = W + 2048;                                     // 6144
    float* lossp  = W + 8192;                                     // 64
    unsigned int* hist = (unsigned int*)(W + 8256);               // 512
    float* scsh   = W + 8768;                                     // 6144
    float* codesq = W + 14912;                                    // 512
    float* wt_e1  = W + 15424;                                    // 1310720 f
    float* codeT  = W + 1671744;                                  // 262144 f
    unsigned short* esw = (unsigned short*)(W + 1933888);         // 3440640 ush
    unsigned short* whi_e1 = esw;
    unsigned short* wlo_e1 = esw + 409600;
    unsigned short* whi_e2 = esw + 819200;
    unsigned short* wlo_e2 = esw + 1605632;
    unsigned short* whi_e3 = esw + 2392064;
    unsigned short* wlo_e3 = esw + 2916352;
    unsigned short* in_h  = (unsigned short*)(W + 3654208);       // 4915200 ush
    unsigned short* in_l  = in_h + 4915200;
    unsigned short* d3pre = (unsigned short*)(W + 3654208);       // 15728640 ush
    float* e1f = W + 11518528;                                    // 3145728 f
    unsigned short* e1h = (unsigned short*)(W + 14664256);        // 3145728 ush
    unsigned short* e1l = e1h + 3145728;
    float* e2f = W + 17809984;                                    // 1048576 f
    unsigned short* e2h = (unsigned short*)(W + 18858560);        // 1048576 ush
    unsigned short* e2l = e2h + 1048576;
    unsigned short* d2pre = (unsigned short*)(W + 17809984);      // 3145728 ush
    unsigned short* d2bf  = d2pre + 3145728;                      // 3145728 ush
    float* e3f = W + 20955712;                                    // 524288 f
    unsigned short* quant_bf = (unsigned short*)(W + 21480000);   // 524288 ush
    unsigned short* d0bf     = (unsigned short*)(W + 21742144);   // 524288 ush
    unsigned short* d1pre    = (unsigned short*)(W + 22004288);   // 1048576 ush
    unsigned short* d1bf     = (unsigned short*)(W + 22528640);   // 1048576 ush
    float* weff   = W + 30917248;                                 // 345600 f
    // weff ends at 31262848 floats (~125 MB) < 256 MiB ws; no aliasing.

    unsigned short* db    = (unsigned short*)wt_e1;
    unsigned short* wqb   = db;
    unsigned short* wd1b  = db + 262144;
    unsigned short* wd2b  = db + 786432;
    unsigned short* wd3b  = db + 1572864;
    unsigned short* woutb = db + 2883584;

    float* st_e1 = stats + 0 * 1024;
    float* st_e2 = stats + 1 * 1024;
    float* st_e3 = stats + 2 * 1024; float* sc_e3 = scsh + 2 * 1024; float* sh_e3 = sc_e3 + 512;
    float* st_d1 = stats + 3 * 1024;
    float* st_d2 = stats + 4 * 1024;
    float* st_d3 = stats + 5 * 1024;

    dim3 blk(256);

    // order: wt_e1 fp32 repack -> weff gemm -> k_prep (contains sp_weff s11;
    // weff is in a non-aliased region so s11 is race-free vs s8/s9).
    k_repack<<<dim3(5 * 1024), blk, 0, stream>>>(w_e1, wt_e1, 5, 5 * 262144);
    k_gemm<<<dim3(16, 5, 5), blk, 0, stream>>>(W_in, wt_e1, weff,
        nullptr, nullptr, nullptr, nullptr, 135, 512, 512, 5);

    k_prep<<<dim3(39022), blk, 0, stream>>>(stats, amin,
        codebook, codeT, codesq,
        w_e2, whi_e2, wlo_e2, w_e3, whi_e3, wlo_e3,
        W_q, wqb, w_d1, wd1b, w_d2, wd2b, w_d3, wd3b, W_out, woutb,
        in_seqs, in_h, in_l, weff, whi_e1, wlo_e1);

    // ---- encoder: e1 = 64x128 tile (k_sp64w, 384 blk); e2/e3 = 64x64 ----
    k_sp64w<<<dim3(4, 16, 6), blk, 0, stream>>>(in_h, in_l, whi_e1, wlo_e1,
        e1f, st_e1, 1024, 160, 512, 5);
    k_bnsplit<<<dim3(3072), blk, 0, stream>>>(e1f, st_e1, g_e1, be1,
        1.f / 6144.f, e1h, e1l, 786432);

    k_sp64g<<<dim3(8, 16, 2), blk, 0, stream>>>(e1h, e1l, whi_e2, wlo_e2,
        e2f, st_e2, 1024, 512, 512, 3);
    k_bnsplit<<<dim3(1024), blk, 0, stream>>>(e2f, st_e2, g_e2, be2,
        1.f / 2048.f, e2h, e2l, 262144);

    k_sp64g<<<dim3(8, 16, 1), blk, 0, stream>>>(e2h, e2l, whi_e3, wlo_e3,
        e3f, st_e3, 1024, 512, 512, 2);
    k_bn_fin<<<dim3(2), blk, 0, stream>>>(st_e3, g_e3, be3, sc_e3, sh_e3, 1.f / 1024.f);

    // ---- VQ: fp32 dist GEMM + argmin (32x32 tiles, 512 blocks) ----
    k_gemm<<<dim3(16, 32, 1), blk, 0, stream>>>(e3f, codeT, nullptr,
        sc_e3, sh_e3, amin, codesq, 1024, 512, 512, 1);
    k_vq_gather<<<dim3(1024), blk, 0, stream>>>(amin, codebook, e3f, sc_e3, sh_e3,
                                                quant_bf, lossp, hist);

    // ---- decoder: all gload_lds 2-phase; BN fused into bnapply ----
    k_b64g<<<dim3(8, 16, 1), blk, 0, stream>>>(quant_bf, wqb, d0bf,
        b_q, nullptr, 1024, 512, 512, 1);

    k_b64g<<<dim3(8, 16, 2), blk, 0, stream>>>(d0bf, wd1b, d1pre,
        nullptr, st_d1, 1024, 512, 512, 2);
    k_bnapply<<<dim3(512), blk, 0, stream>>>(d1pre, st_d1, g_d1, bd1,
        1.f / 2048.f, d1bf, 131072);

    k_b64g<<<dim3(8, 16, 6), blk, 0, stream>>>(d1bf, wd2b, d2pre,
        nullptr, st_d2, 1024, 512, 512, 3);
    k_bnapply<<<dim3(1536), blk, 0, stream>>>(d2pre, st_d2, g_d2, bd2,
        1.f / 6144.f, d2bf, 393216);

    // d3: 256x256 tiles, gload_lds 2-phase, 512 threads (240 blocks)
    k_m256<<<dim3(2, 4, 30), dim3(512), 0, stream>>>(d2bf, wd3b, d3pre,
        st_d3, 1024, 512, 512, 5);

    // out-proj: BN(d3) fused in-kernel; reads RAW d3pre (no bnapply pass)
    k_out256<<<dim3(1, 240, 1), dim3(512), 0, stream>>>(d3pre, woutb,
        out, b_out, st_d3, g_d3, bd3, 1.f / 30720.f, 512, 135);

    k_scalars<<<dim3(1), dim3(512), 0, stream>>>(hist, lossp, out);
}